// Round 2
// baseline (2504.170 us; speedup 1.0000x reference)
//
#include <hip/hip_runtime.h>

#define NN     131072
#define NEDGE  1048576
#define BG     1024
#define LAYERS 3

// ------------------------------------------------------------------
// Segment offsets: off[g] = lower_bound(graph_idx, g); graph_idx sorted.
// ------------------------------------------------------------------
__global__ __launch_bounds__(256) void k_offsets(const int* __restrict__ gi,
                                                 int* __restrict__ off)
{
    int g = blockIdx.x*256 + threadIdx.x;
    if (g > BG) return;
    int lo = 0, hi = NN;
    while (lo < hi) { int mid = (lo + hi) >> 1; if (gi[mid] < g) lo = mid + 1; else hi = mid; }
    off[g] = lo;
}

// ------------------------------------------------------------------
// Init: agg = (1+eps)*x ; zero BN stats
// ------------------------------------------------------------------
__global__ __launch_bounds__(256) void k_init(const float* __restrict__ xsrc,
    const float* __restrict__ epsp, float* __restrict__ agg,
    float* __restrict__ stats)
{
    int i = blockIdx.x*256 + threadIdx.x;
    float ep = 1.0f + *epsp;
    agg[i] = ep * xsrc[i];
    if (blockIdx.x == 0 && threadIdx.x < 128) stats[threadIdx.x] = 0.f;
}

// ------------------------------------------------------------------
// Edge scatter: agg[dst] += x[src]  (64 consecutive threads = 1 edge row)
// ------------------------------------------------------------------
__global__ __launch_bounds__(256) void k_scatter(const float* __restrict__ xf,
    const int* __restrict__ ei, float* __restrict__ agg)
{
    int g = blockIdx.x*256 + threadIdx.x;
    int e = g >> 6, c = g & 63;
    int s = ei[e];
    int d = ei[NEDGE + e];
    unsafeAtomicAdd(agg + (((size_t)d) << 6) + c, xf[(((size_t)s) << 6) + c]);
}

// ------------------------------------------------------------------
// Fused GIN MLP: h = relu(h0 @ w1 + b1) @ w2 + b2  (in-place over agg)
// + BN statistics (sum, sumsq per column), one atomic per col per block.
// 2 waves/block; per-wave LDS tile [feat][node] padded x65 (conflict-free).
// ------------------------------------------------------------------
__global__ __launch_bounds__(128, 2) void k_gin(
    float* __restrict__ big,
    const float* __restrict__ w1, const float* __restrict__ b1,
    const float* __restrict__ w2, const float* __restrict__ b2,
    float* __restrict__ stats)
{
    __shared__ float lh[2][64*65];
    __shared__ float red[2][2][64];
    int tid = threadIdx.x;
    int wv = tid >> 6, lane = tid & 63;
    float* L = lh[wv];
    size_t base = ((size_t)blockIdx.x*128 + (size_t)wv*64) << 6;

    // stage: lane = feature, r = node  (coalesced global, conflict-free LDS)
    #pragma unroll 8
    for (int r = 0; r < 64; r++)
        L[lane*65 + r] = big[base + (size_t)r*64 + lane];
    __syncthreads();

    // layer 1: lane = node, acc over the 64 outputs
    float acc[64];
    #pragma unroll
    for (int j = 0; j < 64; j++) acc[j] = b1[j];
    for (int k = 0; k < 64; k++) {
        float hk = L[k*65 + lane];
        const float* wr = w1 + k*64;
        #pragma unroll
        for (int j = 0; j < 64; j++) acc[j] = fmaf(hk, wr[j], acc[j]);
    }
    #pragma unroll
    for (int j = 0; j < 64; j++) L[j*65 + lane] = fmaxf(acc[j], 0.f);

    // layer 2
    #pragma unroll
    for (int j = 0; j < 64; j++) acc[j] = b2[j];
    for (int k = 0; k < 64; k++) {
        float tk = L[k*65 + lane];
        const float* wr = w2 + k*64;
        #pragma unroll
        for (int j = 0; j < 64; j++) acc[j] = fmaf(tk, wr[j], acc[j]);
    }
    #pragma unroll
    for (int j = 0; j < 64; j++) L[j*65 + lane] = acc[j];
    __syncthreads();

    // store (coalesced) + per-column stats
    float s = 0.f, s2 = 0.f;
    #pragma unroll 8
    for (int r = 0; r < 64; r++) {
        float v = L[lane*65 + r];
        big[base + (size_t)r*64 + lane] = v;
        s += v; s2 = fmaf(v, v, s2);
    }
    red[0][wv][lane] = s; red[1][wv][lane] = s2;
    __syncthreads();
    if (tid < 128) {
        int which = tid >> 6, c = tid & 63;
        float a = red[which][0][c] + red[which][1][c];
        unsafeAtomicAdd(stats + which*64 + c, a);
    }
}

// ------------------------------------------------------------------
// BN finalize: per-column scale/shift
// ------------------------------------------------------------------
__global__ void k_bnfin(const float* __restrict__ stats,
                        const float* __restrict__ gamma,
                        const float* __restrict__ beta,
                        float* __restrict__ bnp)
{
    int c = threadIdx.x;  // 64
    float mu  = stats[c]     * (1.0f/NN);
    float ex2 = stats[64+c]  * (1.0f/NN);
    float var = ex2 - mu*mu;
    float sc  = gamma[c] * rsqrtf(var + 1e-5f);
    bnp[c]     = sc;
    bnp[64+c]  = beta[c] - mu*sc;
}

// ------------------------------------------------------------------
// BN-apply + relu -> xf (next layer input) ; big <- inner = relu(x @ wi + bi)
// ------------------------------------------------------------------
__global__ __launch_bounds__(128, 2) void k_bn_inner(
    float* __restrict__ big, const float* __restrict__ bnp,
    const float* __restrict__ wi, const float* __restrict__ bi,
    float* __restrict__ xf)
{
    __shared__ float lh[2][64*65];
    int tid = threadIdx.x, wv = tid >> 6, lane = tid & 63;
    float* L = lh[wv];
    size_t base = ((size_t)blockIdx.x*128 + (size_t)wv*64) << 6;
    float sc = bnp[lane], sh = bnp[64 + lane];
    #pragma unroll 8
    for (int r = 0; r < 64; r++) {
        float v = big[base + (size_t)r*64 + lane];
        v = fmaxf(fmaf(v, sc, sh), 0.f);
        xf[base + (size_t)r*64 + lane] = v;
        L[lane*65 + r] = v;
    }
    __syncthreads();
    float acc[64];
    #pragma unroll
    for (int j = 0; j < 64; j++) acc[j] = bi[j];
    for (int k = 0; k < 64; k++) {
        float xk = L[k*65 + lane];
        const float* wr = wi + k*64;
        #pragma unroll
        for (int j = 0; j < 64; j++) acc[j] = fmaf(xk, wr[j], acc[j]);
    }
    #pragma unroll
    for (int j = 0; j < 64; j++) L[j*65 + lane] = fmaxf(acc[j], 0.f);
    __syncthreads();
    #pragma unroll 8
    for (int r = 0; r < 64; r++)
        big[base + (size_t)r*64 + lane] = L[lane*65 + r];
}

// ------------------------------------------------------------------
// Pool: one wave per graph, columnwise sum over [off[g], off[g+1])
// ------------------------------------------------------------------
__global__ __launch_bounds__(256) void k_pool(const float* __restrict__ inner,
    const int* __restrict__ off, float* __restrict__ pooled)
{
    int g = blockIdx.x*4 + (threadIdx.x >> 6);
    int lane = threadIdx.x & 63;
    int s = off[g], e = off[g+1];
    float a0=0.f, a1=0.f, a2=0.f, a3=0.f;
    int r = s;
    for (; r + 4 <= e; r += 4) {
        a0 += inner[(size_t)(r+0)*64 + lane];
        a1 += inner[(size_t)(r+1)*64 + lane];
        a2 += inner[(size_t)(r+2)*64 + lane];
        a3 += inner[(size_t)(r+3)*64 + lane];
    }
    for (; r < e; r++) a0 += inner[(size_t)r*64 + lane];
    pooled[g*64 + lane] = (a0+a1) + (a2+a3);
}

// ------------------------------------------------------------------
// Outer MLP: feats[:, coff:coff+64] = relu(pooled @ w + b)
// ------------------------------------------------------------------
__global__ __launch_bounds__(256) void k_outer(const float* __restrict__ pooled,
    const float* __restrict__ w, const float* __restrict__ b,
    float* __restrict__ feats, int coff)
{
    int g = blockIdx.x*256 + threadIdx.x;  // BG*64
    int bb = g >> 6, j = g & 63;
    const float* pr = pooled + bb*64;
    float a = b[j];
    for (int k = 0; k < 64; k++) a = fmaf(pr[k], w[k*64 + j], a);
    feats[bb*192 + coff + j] = fmaxf(a, 0.f);
}

// ------------------------------------------------------------------
// Tail: conv head + NTN + sim head; one block per graph pair
// ------------------------------------------------------------------
__global__ __launch_bounds__(128) void k_tail(
    const float* __restrict__ qf, const float* __restrict__ cf,
    const float* __restrict__ cw1, const float* __restrict__ cb1,
    const float* __restrict__ cw2, const float* __restrict__ cb2,
    const float* __restrict__ sw1, const float* __restrict__ sb1,
    const float* __restrict__ sw2, const float* __restrict__ sb2,
    const float* __restrict__ nw,  const float* __restrict__ nwb,
    const float* __restrict__ nb,
    const float* __restrict__ mw1, const float* __restrict__ mb1,
    const float* __restrict__ mw2, const float* __restrict__ mb2,
    const float* __restrict__ alpha, const float* __restrict__ beta,
    float* __restrict__ out)
{
    int b = blockIdx.x, t = threadIdx.x;
    __shared__ float diff[192], h1[96], h2[96], e1[64], e2[64], vred[128], s1[16], simrep[16];

    for (int i = t; i < 192; i += 128) {
        float q = qf[b*192 + i], c = cf[b*192 + i];
        float d = q - c;
        diff[i] = expf(-d*d);
    }
    for (int i = t; i < 64; i += 128) {
        e1[i] = qf[b*192 + 128 + i];
        e2[i] = cf[b*192 + 128 + i];
    }
    __syncthreads();

    if (t < 96) {
        float a = cb1[t];
        for (int f = 0; f < 192; f++) a = fmaf(diff[f], cw1[f*96 + t], a);
        h1[t] = fmaxf(a, 0.f);
    }
    __syncthreads();
    if (t < 96) {
        float a = cb2[t];
        for (int f = 0; f < 96; f++) a = fmaf(h1[f], cw2[f*96 + t], a);
        h2[t] = tanhf(a);
    }
    __syncthreads();
    if (t < 16) {
        float a = sb1[t];
        for (int f = 0; f < 96; f++) a = fmaf(h2[f], sw1[f*16 + t], a);
        s1[t] = fmaxf(a, 0.f);
    }

    // NTN: scoring[b,t] = sum_f sum_g e1[f] nw[f,g,t] e2[g]; split g over 8 chunks
    {
        int tt = t & 15, gc = t >> 4;
        float p = 0.f;
        for (int gi = 0; gi < 8; gi++) {
            int g = gc*8 + gi;
            float v = 0.f;
            for (int f = 0; f < 64; f++) v = fmaf(e1[f], nw[(f*64 + g)*16 + tt], v);
            p = fmaf(v, e2[g], p);
        }
        vred[t] = p;
    }
    __syncthreads();
    if (t < 16) {
        float sc = 0.f;
        for (int gc = 0; gc < 8; gc++) sc += vred[gc*16 + t];
        float blk = nb[t];
        for (int f = 0; f < 64; f++) blk = fmaf(e1[f], nwb[t*128 + f], blk);
        for (int f = 0; f < 64; f++) blk = fmaf(e2[f], nwb[t*128 + 64 + f], blk);
        simrep[t] = fmaxf(sc + blk, 0.f);
    }
    __syncthreads();
    if (t < 16) {
        float a = mb1[t];
        for (int f = 0; f < 16; f++) a = fmaf(simrep[f], mw1[f*16 + t], a);
        vred[t] = fmaxf(a, 0.f);
    }
    __syncthreads();
    if (t == 0) {
        float sco = sb2[0];
        for (int f = 0; f < 16; f++) sco = fmaf(s1[f], sw2[f], sco);
        float score = 1.f / (1.f + expf(-sco));
        float sm = mb2[0];
        for (int f = 0; f < 16; f++) sm = fmaf(vred[f], mw2[f], sm);
        float sim = 1.f / (1.f + expf(-sm));
        out[b] = alpha[0]*score + beta[0]*sim;
    }
}

// ------------------------------------------------------------------
extern "C" void kernel_launch(void* const* d_in, const int* in_sizes, int n_in,
                              void* d_out, int out_size, void* d_ws, size_t ws_size,
                              hipStream_t stream)
{
    const float* qx  = (const float*)d_in[0];
    const float* cx  = (const float*)d_in[1];
    const int*   qei = (const int*)d_in[2];
    const int*   cei = (const int*)d_in[3];
    const int*   qgi = (const int*)d_in[4];
    const int*   cgi = (const int*)d_in[5];
    const float* Wgw1 = (const float*)d_in[6];
    const float* Wgb1 = (const float*)d_in[7];
    const float* Wgw2 = (const float*)d_in[8];
    const float* Wgb2 = (const float*)d_in[9];
    const float* Wgam = (const float*)d_in[10];
    const float* Wbet = (const float*)d_in[11];
    const float* Weps = (const float*)d_in[12];
    const float* Wiw  = (const float*)d_in[13];
    const float* Wib  = (const float*)d_in[14];
    const float* Wow  = (const float*)d_in[15];
    const float* Wob  = (const float*)d_in[16];
    const float* Wcw1 = (const float*)d_in[17];
    const float* Wcb1 = (const float*)d_in[18];
    const float* Wcw2 = (const float*)d_in[19];
    const float* Wcb2 = (const float*)d_in[20];
    const float* Wsw1 = (const float*)d_in[21];
    const float* Wsb1 = (const float*)d_in[22];
    const float* Wsw2 = (const float*)d_in[23];
    const float* Wsb2 = (const float*)d_in[24];
    const float* Wnw  = (const float*)d_in[25];
    const float* Wnwb = (const float*)d_in[26];
    const float* Wnb  = (const float*)d_in[27];
    const float* Wmw1 = (const float*)d_in[28];
    const float* Wmb1 = (const float*)d_in[29];
    const float* Wmw2 = (const float*)d_in[30];
    const float* Wmb2 = (const float*)d_in[31];
    const float* Wal  = (const float*)d_in[32];
    const float* Wbe  = (const float*)d_in[33];

    float* F      = (float*)d_ws;
    float* big    = F;                       // N*64
    float* xbuf   = F + 8388608;             // N*64
    float* stats  = F + 16777216;            // 128
    float* bnp    = stats + 128;             // 128
    float* pooled = bnp + 128;               // BG*64
    float* qf     = pooled + 65536;          // BG*192
    float* cf     = qf + 196608;             // BG*192
    int*   qoff   = (int*)(cf + 196608);     // BG+1
    int*   coff   = qoff + (BG + 1);         // BG+1

    for (int side = 0; side < 2; side++) {
        const float* x0 = side ? cx  : qx;
        const int* ei   = side ? cei : qei;
        const int* gi   = side ? cgi : qgi;
        int* off        = side ? coff : qoff;
        float* feats    = side ? cf  : qf;

        k_offsets<<<5, 256, 0, stream>>>(gi, off);

        for (int l = 0; l < LAYERS; l++) {
            const float* xin = (l == 0) ? x0 : xbuf;
            k_init<<<32768, 256, 0, stream>>>(xin, Weps + l, big, stats);
            k_scatter<<<262144, 256, 0, stream>>>(xin, ei, big);
            k_gin<<<1024, 128, 0, stream>>>(big, Wgw1 + l*4096, Wgb1 + l*64,
                                            Wgw2 + l*4096, Wgb2 + l*64, stats);
            k_bnfin<<<1, 64, 0, stream>>>(stats, Wgam + l*64, Wbet + l*64, bnp);
            k_bn_inner<<<1024, 128, 0, stream>>>(big, bnp, Wiw + l*4096, Wib + l*64, xbuf);
            k_pool<<<BG/4, 256, 0, stream>>>(big, off, pooled);
            k_outer<<<BG*64/256, 256, 0, stream>>>(pooled, Wow + l*4096, Wob + l*64,
                                                   feats, l*64);
        }
    }

    k_tail<<<BG, 128, 0, stream>>>(qf, cf, Wcw1, Wcb1, Wcw2, Wcb2,
                                   Wsw1, Wsb1, Wsw2, Wsb2,
                                   Wnw, Wnwb, Wnb, Wmw1, Wmb1, Wmw2, Wmb2,
                                   Wal, Wbe, (float*)d_out);
}

// Round 3
// 1642.315 us; speedup vs baseline: 1.5248x; 1.5248x over previous
//
#include <hip/hip_runtime.h>

#define NN     131072
#define NEDGE  1048576
#define BG     1024
#define LAYERS 3

// ------------------------------------------------------------------
// Segment offsets: off[g] = lower_bound(graph_idx, g); graph_idx sorted.
// ------------------------------------------------------------------
__global__ __launch_bounds__(256) void k_offsets(const int* __restrict__ gi,
                                                 int* __restrict__ off)
{
    int g = blockIdx.x*256 + threadIdx.x;
    if (g > BG) return;
    int lo = 0, hi = NN;
    while (lo < hi) { int mid = (lo + hi) >> 1; if (gi[mid] < g) lo = mid + 1; else hi = mid; }
    off[g] = lo;
}

// ------------------------------------------------------------------
// CSR build: histogram of dst -> exclusive scan -> fill col with src
// ------------------------------------------------------------------
__global__ __launch_bounds__(256) void k_zero(int* __restrict__ cnt)
{
    int i = blockIdx.x*256 + threadIdx.x;
    if (i < NN) cnt[i] = 0;
}

__global__ __launch_bounds__(256) void k_hist(const int* __restrict__ ei,
                                              int* __restrict__ cnt)
{
    int e = blockIdx.x*256 + threadIdx.x;      // NEDGE threads
    atomicAdd(cnt + ei[NEDGE + e], 1);
}

// scan1: 128 blocks x 256 thr, 4 elems/thread (block covers 1024)
__global__ __launch_bounds__(256) void k_scan1(const int* __restrict__ cnt,
    int* __restrict__ rowptr, int* __restrict__ bsum)
{
    __shared__ int sd[256];
    int t = threadIdx.x;
    int base = blockIdx.x*1024 + t*4;
    int c0 = cnt[base], c1 = cnt[base+1], c2 = cnt[base+2], c3 = cnt[base+3];
    int tsum = c0 + c1 + c2 + c3;
    sd[t] = tsum;
    __syncthreads();
    for (int off = 1; off < 256; off <<= 1) {
        int v = (t >= off) ? sd[t-off] : 0;
        __syncthreads();
        sd[t] += v;
        __syncthreads();
    }
    int excl = sd[t] - tsum;
    rowptr[base]   = excl;
    rowptr[base+1] = excl + c0;
    rowptr[base+2] = excl + c0 + c1;
    rowptr[base+3] = excl + c0 + c1 + c2;
    if (t == 255) bsum[blockIdx.x] = sd[255];
}

// scan2: single block, exclusive scan of 128 block sums
__global__ __launch_bounds__(128) void k_scan2(const int* __restrict__ bsum,
    int* __restrict__ boff, int* __restrict__ rowptr)
{
    __shared__ int sd[128];
    int t = threadIdx.x;
    int v0 = bsum[t];
    sd[t] = v0;
    __syncthreads();
    for (int off = 1; off < 128; off <<= 1) {
        int v = (t >= off) ? sd[t-off] : 0;
        __syncthreads();
        sd[t] += v;
        __syncthreads();
    }
    boff[t] = sd[t] - v0;
    if (t == 0) rowptr[NN] = NEDGE;
}

// scan3: add block offsets; copy to wptr (fill cursor)
__global__ __launch_bounds__(256) void k_scan3(int* __restrict__ rowptr,
    const int* __restrict__ boff, int* __restrict__ wptr)
{
    int i = blockIdx.x*256 + threadIdx.x;      // NN threads
    int v = rowptr[i] + boff[i >> 10];
    rowptr[i] = v;
    wptr[i] = v;
}

__global__ __launch_bounds__(256) void k_fill(const int* __restrict__ ei,
    int* __restrict__ wptr, int* __restrict__ col)
{
    int e = blockIdx.x*256 + threadIdx.x;      // NEDGE threads
    int s = ei[e];
    int d = ei[NEDGE + e];
    int pos = atomicAdd(wptr + d, 1);
    col[pos] = s;
}

// ------------------------------------------------------------------
// Aggregate (replaces init+scatter): one wave per node, lane = feature.
// agg[n] = (1+eps)*x[n] + sum_{e in row n} x[col[e]]; zero BN stats.
// ------------------------------------------------------------------
__global__ __launch_bounds__(256) void k_aggregate(const float* __restrict__ x,
    const int* __restrict__ rowptr, const int* __restrict__ col,
    const float* __restrict__ epsp, float* __restrict__ agg,
    float* __restrict__ stats)
{
    int n = blockIdx.x*4 + (threadIdx.x >> 6);
    int lane = threadIdx.x & 63;
    float ep = 1.0f + *epsp;
    float a0 = ep * x[((size_t)n << 6) + lane];
    float a1 = 0.f, a2 = 0.f, a3 = 0.f;
    int s = rowptr[n], e = rowptr[n+1];
    int r = s;
    for (; r + 4 <= e; r += 4) {
        int c0 = col[r], c1 = col[r+1], c2 = col[r+2], c3 = col[r+3];
        a0 += x[((size_t)c0 << 6) + lane];
        a1 += x[((size_t)c1 << 6) + lane];
        a2 += x[((size_t)c2 << 6) + lane];
        a3 += x[((size_t)c3 << 6) + lane];
    }
    for (; r < e; r++) a0 += x[((size_t)col[r] << 6) + lane];
    agg[((size_t)n << 6) + lane] = (a0 + a1) + (a2 + a3);
    if (blockIdx.x == 0 && threadIdx.x < 128) stats[threadIdx.x] = 0.f;
}

// ------------------------------------------------------------------
// Fused GIN MLP: h = relu(h0 @ w1 + b1) @ w2 + b2  (in-place over agg)
// + BN statistics (sum, sumsq per column), one atomic per col per block.
// ------------------------------------------------------------------
__global__ __launch_bounds__(128, 2) void k_gin(
    float* __restrict__ big,
    const float* __restrict__ w1, const float* __restrict__ b1,
    const float* __restrict__ w2, const float* __restrict__ b2,
    float* __restrict__ stats)
{
    __shared__ float lh[2][64*65];
    __shared__ float red[2][2][64];
    int tid = threadIdx.x;
    int wv = tid >> 6, lane = tid & 63;
    float* L = lh[wv];
    size_t base = ((size_t)blockIdx.x*128 + (size_t)wv*64) << 6;

    #pragma unroll 8
    for (int r = 0; r < 64; r++)
        L[lane*65 + r] = big[base + (size_t)r*64 + lane];
    __syncthreads();

    float acc[64];
    #pragma unroll
    for (int j = 0; j < 64; j++) acc[j] = b1[j];
    for (int k = 0; k < 64; k++) {
        float hk = L[k*65 + lane];
        const float* wr = w1 + k*64;
        #pragma unroll
        for (int j = 0; j < 64; j++) acc[j] = fmaf(hk, wr[j], acc[j]);
    }
    #pragma unroll
    for (int j = 0; j < 64; j++) L[j*65 + lane] = fmaxf(acc[j], 0.f);

    #pragma unroll
    for (int j = 0; j < 64; j++) acc[j] = b2[j];
    for (int k = 0; k < 64; k++) {
        float tk = L[k*65 + lane];
        const float* wr = w2 + k*64;
        #pragma unroll
        for (int j = 0; j < 64; j++) acc[j] = fmaf(tk, wr[j], acc[j]);
    }
    #pragma unroll
    for (int j = 0; j < 64; j++) L[j*65 + lane] = acc[j];
    __syncthreads();

    float s = 0.f, s2 = 0.f;
    #pragma unroll 8
    for (int r = 0; r < 64; r++) {
        float v = L[lane*65 + r];
        big[base + (size_t)r*64 + lane] = v;
        s += v; s2 = fmaf(v, v, s2);
    }
    red[0][wv][lane] = s; red[1][wv][lane] = s2;
    __syncthreads();
    if (tid < 128) {
        int which = tid >> 6, c = tid & 63;
        float a = red[which][0][c] + red[which][1][c];
        unsafeAtomicAdd(stats + which*64 + c, a);
    }
}

// ------------------------------------------------------------------
// BN finalize: per-column scale/shift
// ------------------------------------------------------------------
__global__ void k_bnfin(const float* __restrict__ stats,
                        const float* __restrict__ gamma,
                        const float* __restrict__ beta,
                        float* __restrict__ bnp)
{
    int c = threadIdx.x;  // 64
    float mu  = stats[c]     * (1.0f/NN);
    float ex2 = stats[64+c]  * (1.0f/NN);
    float var = ex2 - mu*mu;
    float sc  = gamma[c] * rsqrtf(var + 1e-5f);
    bnp[c]     = sc;
    bnp[64+c]  = beta[c] - mu*sc;
}

// ------------------------------------------------------------------
// BN-apply + relu -> xf (next layer input) ; big <- inner = relu(x @ wi + bi)
// ------------------------------------------------------------------
__global__ __launch_bounds__(128, 2) void k_bn_inner(
    float* __restrict__ big, const float* __restrict__ bnp,
    const float* __restrict__ wi, const float* __restrict__ bi,
    float* __restrict__ xf)
{
    __shared__ float lh[2][64*65];
    int tid = threadIdx.x, wv = tid >> 6, lane = tid & 63;
    float* L = lh[wv];
    size_t base = ((size_t)blockIdx.x*128 + (size_t)wv*64) << 6;
    float sc = bnp[lane], sh = bnp[64 + lane];
    #pragma unroll 8
    for (int r = 0; r < 64; r++) {
        float v = big[base + (size_t)r*64 + lane];
        v = fmaxf(fmaf(v, sc, sh), 0.f);
        xf[base + (size_t)r*64 + lane] = v;
        L[lane*65 + r] = v;
    }
    __syncthreads();
    float acc[64];
    #pragma unroll
    for (int j = 0; j < 64; j++) acc[j] = bi[j];
    for (int k = 0; k < 64; k++) {
        float xk = L[k*65 + lane];
        const float* wr = wi + k*64;
        #pragma unroll
        for (int j = 0; j < 64; j++) acc[j] = fmaf(xk, wr[j], acc[j]);
    }
    #pragma unroll
    for (int j = 0; j < 64; j++) L[j*65 + lane] = fmaxf(acc[j], 0.f);
    __syncthreads();
    #pragma unroll 8
    for (int r = 0; r < 64; r++)
        big[base + (size_t)r*64 + lane] = L[lane*65 + r];
}

// ------------------------------------------------------------------
// Pool: one wave per graph, columnwise sum over [off[g], off[g+1])
// ------------------------------------------------------------------
__global__ __launch_bounds__(256) void k_pool(const float* __restrict__ inner,
    const int* __restrict__ off, float* __restrict__ pooled)
{
    int g = blockIdx.x*4 + (threadIdx.x >> 6);
    int lane = threadIdx.x & 63;
    int s = off[g], e = off[g+1];
    float a0=0.f, a1=0.f, a2=0.f, a3=0.f;
    int r = s;
    for (; r + 4 <= e; r += 4) {
        a0 += inner[(size_t)(r+0)*64 + lane];
        a1 += inner[(size_t)(r+1)*64 + lane];
        a2 += inner[(size_t)(r+2)*64 + lane];
        a3 += inner[(size_t)(r+3)*64 + lane];
    }
    for (; r < e; r++) a0 += inner[(size_t)r*64 + lane];
    pooled[g*64 + lane] = (a0+a1) + (a2+a3);
}

// ------------------------------------------------------------------
// Outer MLP: feats[:, coff:coff+64] = relu(pooled @ w + b)
// ------------------------------------------------------------------
__global__ __launch_bounds__(256) void k_outer(const float* __restrict__ pooled,
    const float* __restrict__ w, const float* __restrict__ b,
    float* __restrict__ feats, int coff)
{
    int g = blockIdx.x*256 + threadIdx.x;  // BG*64
    int bb = g >> 6, j = g & 63;
    const float* pr = pooled + bb*64;
    float a = b[j];
    for (int k = 0; k < 64; k++) a = fmaf(pr[k], w[k*64 + j], a);
    feats[bb*192 + coff + j] = fmaxf(a, 0.f);
}

// ------------------------------------------------------------------
// Tail: conv head + NTN + sim head; one block per graph pair
// ------------------------------------------------------------------
__global__ __launch_bounds__(128) void k_tail(
    const float* __restrict__ qf, const float* __restrict__ cf,
    const float* __restrict__ cw1, const float* __restrict__ cb1,
    const float* __restrict__ cw2, const float* __restrict__ cb2,
    const float* __restrict__ sw1, const float* __restrict__ sb1,
    const float* __restrict__ sw2, const float* __restrict__ sb2,
    const float* __restrict__ nw,  const float* __restrict__ nwb,
    const float* __restrict__ nb,
    const float* __restrict__ mw1, const float* __restrict__ mb1,
    const float* __restrict__ mw2, const float* __restrict__ mb2,
    const float* __restrict__ alpha, const float* __restrict__ beta,
    float* __restrict__ out)
{
    int b = blockIdx.x, t = threadIdx.x;
    __shared__ float diff[192], h1[96], h2[96], e1[64], e2[64], vred[128], s1[16], simrep[16];

    for (int i = t; i < 192; i += 128) {
        float q = qf[b*192 + i], c = cf[b*192 + i];
        float d = q - c;
        diff[i] = expf(-d*d);
    }
    for (int i = t; i < 64; i += 128) {
        e1[i] = qf[b*192 + 128 + i];
        e2[i] = cf[b*192 + 128 + i];
    }
    __syncthreads();

    if (t < 96) {
        float a = cb1[t];
        for (int f = 0; f < 192; f++) a = fmaf(diff[f], cw1[f*96 + t], a);
        h1[t] = fmaxf(a, 0.f);
    }
    __syncthreads();
    if (t < 96) {
        float a = cb2[t];
        for (int f = 0; f < 96; f++) a = fmaf(h1[f], cw2[f*96 + t], a);
        h2[t] = tanhf(a);
    }
    __syncthreads();
    if (t < 16) {
        float a = sb1[t];
        for (int f = 0; f < 96; f++) a = fmaf(h2[f], sw1[f*16 + t], a);
        s1[t] = fmaxf(a, 0.f);
    }

    {
        int tt = t & 15, gc = t >> 4;
        float p = 0.f;
        for (int gi = 0; gi < 8; gi++) {
            int g = gc*8 + gi;
            float v = 0.f;
            for (int f = 0; f < 64; f++) v = fmaf(e1[f], nw[(f*64 + g)*16 + tt], v);
            p = fmaf(v, e2[g], p);
        }
        vred[t] = p;
    }
    __syncthreads();
    if (t < 16) {
        float sc = 0.f;
        for (int gc = 0; gc < 8; gc++) sc += vred[gc*16 + t];
        float blk = nb[t];
        for (int f = 0; f < 64; f++) blk = fmaf(e1[f], nwb[t*128 + f], blk);
        for (int f = 0; f < 64; f++) blk = fmaf(e2[f], nwb[t*128 + 64 + f], blk);
        simrep[t] = fmaxf(sc + blk, 0.f);
    }
    __syncthreads();
    if (t < 16) {
        float a = mb1[t];
        for (int f = 0; f < 16; f++) a = fmaf(simrep[f], mw1[f*16 + t], a);
        vred[t] = fmaxf(a, 0.f);
    }
    __syncthreads();
    if (t == 0) {
        float sco = sb2[0];
        for (int f = 0; f < 16; f++) sco = fmaf(s1[f], sw2[f], sco);
        float score = 1.f / (1.f + expf(-sco));
        float sm = mb2[0];
        for (int f = 0; f < 16; f++) sm = fmaf(vred[f], mw2[f], sm);
        float sim = 1.f / (1.f + expf(-sm));
        out[b] = alpha[0]*score + beta[0]*sim;
    }
}

// ------------------------------------------------------------------
extern "C" void kernel_launch(void* const* d_in, const int* in_sizes, int n_in,
                              void* d_out, int out_size, void* d_ws, size_t ws_size,
                              hipStream_t stream)
{
    const float* qx  = (const float*)d_in[0];
    const float* cx  = (const float*)d_in[1];
    const int*   qei = (const int*)d_in[2];
    const int*   cei = (const int*)d_in[3];
    const int*   qgi = (const int*)d_in[4];
    const int*   cgi = (const int*)d_in[5];
    const float* Wgw1 = (const float*)d_in[6];
    const float* Wgb1 = (const float*)d_in[7];
    const float* Wgw2 = (const float*)d_in[8];
    const float* Wgb2 = (const float*)d_in[9];
    const float* Wgam = (const float*)d_in[10];
    const float* Wbet = (const float*)d_in[11];
    const float* Weps = (const float*)d_in[12];
    const float* Wiw  = (const float*)d_in[13];
    const float* Wib  = (const float*)d_in[14];
    const float* Wow  = (const float*)d_in[15];
    const float* Wob  = (const float*)d_in[16];
    const float* Wcw1 = (const float*)d_in[17];
    const float* Wcb1 = (const float*)d_in[18];
    const float* Wcw2 = (const float*)d_in[19];
    const float* Wcb2 = (const float*)d_in[20];
    const float* Wsw1 = (const float*)d_in[21];
    const float* Wsb1 = (const float*)d_in[22];
    const float* Wsw2 = (const float*)d_in[23];
    const float* Wsb2 = (const float*)d_in[24];
    const float* Wnw  = (const float*)d_in[25];
    const float* Wnwb = (const float*)d_in[26];
    const float* Wnb  = (const float*)d_in[27];
    const float* Wmw1 = (const float*)d_in[28];
    const float* Wmb1 = (const float*)d_in[29];
    const float* Wmw2 = (const float*)d_in[30];
    const float* Wmb2 = (const float*)d_in[31];
    const float* Wal  = (const float*)d_in[32];
    const float* Wbe  = (const float*)d_in[33];

    float* F      = (float*)d_ws;
    float* big    = F;                       // N*64
    float* xbuf   = F + 8388608;             // N*64
    float* stats  = F + 16777216;            // 128
    float* bnp    = stats + 128;             // 128
    float* pooled = bnp + 128;               // BG*64
    float* qf     = pooled + 65536;          // BG*192
    float* cf     = qf + 196608;             // BG*192
    int*   qoff   = (int*)(cf + 196608);     // BG+1
    int*   coff   = qoff + (BG + 1);         // BG+1
    int*   rowptr = coff + (BG + 1);         // NN+1
    int*   wptr   = rowptr + (NN + 1);       // NN   (aliases histogram cnt)
    int*   col    = wptr + NN;               // NEDGE
    int*   bsum   = col + NEDGE;             // 128
    int*   boff   = bsum + 128;              // 128

    for (int side = 0; side < 2; side++) {
        const float* x0 = side ? cx  : qx;
        const int* ei   = side ? cei : qei;
        const int* gi   = side ? cgi : qgi;
        int* off        = side ? coff : qoff;
        float* feats    = side ? cf  : qf;

        k_offsets<<<5, 256, 0, stream>>>(gi, off);

        // CSR build for this side (reused by all 3 layers)
        k_zero<<<NN/256, 256, 0, stream>>>(wptr);             // wptr as cnt
        k_hist<<<NEDGE/256, 256, 0, stream>>>(ei, wptr);
        k_scan1<<<128, 256, 0, stream>>>(wptr, rowptr, bsum);
        k_scan2<<<1, 128, 0, stream>>>(bsum, boff, rowptr);
        k_scan3<<<NN/256, 256, 0, stream>>>(rowptr, boff, wptr);
        k_fill<<<NEDGE/256, 256, 0, stream>>>(ei, wptr, col);

        for (int l = 0; l < LAYERS; l++) {
            const float* xin = (l == 0) ? x0 : xbuf;
            k_aggregate<<<NN/4, 256, 0, stream>>>(xin, rowptr, col, Weps + l,
                                                  big, stats);
            k_gin<<<1024, 128, 0, stream>>>(big, Wgw1 + l*4096, Wgb1 + l*64,
                                            Wgw2 + l*4096, Wgb2 + l*64, stats);
            k_bnfin<<<1, 64, 0, stream>>>(stats, Wgam + l*64, Wbet + l*64, bnp);
            k_bn_inner<<<1024, 128, 0, stream>>>(big, bnp, Wiw + l*4096, Wib + l*64, xbuf);
            k_pool<<<BG/4, 256, 0, stream>>>(big, off, pooled);
            k_outer<<<BG*64/256, 256, 0, stream>>>(pooled, Wow + l*4096, Wob + l*64,
                                                   feats, l*64);
        }
    }

    k_tail<<<BG, 128, 0, stream>>>(qf, cf, Wcw1, Wcb1, Wcw2, Wcb2,
                                   Wsw1, Wsb1, Wsw2, Wsb2,
                                   Wnw, Wnwb, Wnb, Wmw1, Wmb1, Wmw2, Wmb2,
                                   Wal, Wbe, (float*)d_out);
}

// Round 4
// 1531.666 us; speedup vs baseline: 1.6349x; 1.0722x over previous
//
#include <hip/hip_runtime.h>
#include <hip/hip_bf16.h>

typedef __hip_bfloat16 bf16;

#define NN     131072
#define NEDGE  1048576
#define BG     1024
#define LAYERS 3
#define TG     8      // graphs per tail block

// ------------------------------------------------------------------
// Segment offsets: off[g] = lower_bound(graph_idx, g); graph_idx sorted.
// ------------------------------------------------------------------
__global__ __launch_bounds__(256) void k_offsets(const int* __restrict__ gi,
                                                 int* __restrict__ off)
{
    int g = blockIdx.x*256 + threadIdx.x;
    if (g > BG) return;
    int lo = 0, hi = NN;
    while (lo < hi) { int mid = (lo + hi) >> 1; if (gi[mid] < g) lo = mid + 1; else hi = mid; }
    off[g] = lo;
}

// ------------------------------------------------------------------
// CSR build: histogram of dst -> exclusive scan -> fill col with src
// ------------------------------------------------------------------
__global__ __launch_bounds__(256) void k_zero(int* __restrict__ cnt)
{
    int i = blockIdx.x*256 + threadIdx.x;
    if (i < NN) cnt[i] = 0;
}

__global__ __launch_bounds__(256) void k_hist(const int* __restrict__ ei,
                                              int* __restrict__ cnt)
{
    int e = blockIdx.x*256 + threadIdx.x;
    atomicAdd(cnt + ei[NEDGE + e], 1);
}

__global__ __launch_bounds__(256) void k_scan1(const int* __restrict__ cnt,
    int* __restrict__ rowptr, int* __restrict__ bsum)
{
    __shared__ int sd[256];
    int t = threadIdx.x;
    int base = blockIdx.x*1024 + t*4;
    int c0 = cnt[base], c1 = cnt[base+1], c2 = cnt[base+2], c3 = cnt[base+3];
    int tsum = c0 + c1 + c2 + c3;
    sd[t] = tsum;
    __syncthreads();
    for (int off = 1; off < 256; off <<= 1) {
        int v = (t >= off) ? sd[t-off] : 0;
        __syncthreads();
        sd[t] += v;
        __syncthreads();
    }
    int excl = sd[t] - tsum;
    rowptr[base]   = excl;
    rowptr[base+1] = excl + c0;
    rowptr[base+2] = excl + c0 + c1;
    rowptr[base+3] = excl + c0 + c1 + c2;
    if (t == 255) bsum[blockIdx.x] = sd[255];
}

__global__ __launch_bounds__(128) void k_scan2(const int* __restrict__ bsum,
    int* __restrict__ boff, int* __restrict__ rowptr)
{
    __shared__ int sd[128];
    int t = threadIdx.x;
    int v0 = bsum[t];
    sd[t] = v0;
    __syncthreads();
    for (int off = 1; off < 128; off <<= 1) {
        int v = (t >= off) ? sd[t-off] : 0;
        __syncthreads();
        sd[t] += v;
        __syncthreads();
    }
    boff[t] = sd[t] - v0;
    if (t == 0) rowptr[NN] = NEDGE;
}

__global__ __launch_bounds__(256) void k_scan3(int* __restrict__ rowptr,
    const int* __restrict__ boff, int* __restrict__ wptr)
{
    int i = blockIdx.x*256 + threadIdx.x;
    int v = rowptr[i] + boff[i >> 10];
    rowptr[i] = v;
    wptr[i] = v;
}

__global__ __launch_bounds__(256) void k_fill(const int* __restrict__ ei,
    int* __restrict__ wptr, int* __restrict__ col)
{
    int e = blockIdx.x*256 + threadIdx.x;
    int s = ei[e];
    int d = ei[NEDGE + e];
    int pos = atomicAdd(wptr + d, 1);
    col[pos] = s;
}

// ------------------------------------------------------------------
// fp32 -> bf16 shadow copy of node features (layer-0 input)
// ------------------------------------------------------------------
__global__ __launch_bounds__(256) void k_cvt(const float* __restrict__ x,
                                             bf16* __restrict__ xh)
{
    int i = blockIdx.x*256 + threadIdx.x;
    xh[i] = __float2bfloat16(x[i]);
}

// ------------------------------------------------------------------
// Aggregate from bf16 table: one wave per node, lane = feature.
// agg[n] = (1+eps)*x[n] + sum_{e in row n} x[col[e]]; zero BN stats.
// Each bf16 row = 128 B = one cache line.
// ------------------------------------------------------------------
__global__ __launch_bounds__(256) void k_aggregate(const bf16* __restrict__ xh,
    const int* __restrict__ rowptr, const int* __restrict__ col,
    const float* __restrict__ epsp, float* __restrict__ agg,
    float* __restrict__ stats)
{
    int n = blockIdx.x*4 + (threadIdx.x >> 6);
    int lane = threadIdx.x & 63;
    float ep = 1.0f + *epsp;
    float a0 = ep * __bfloat162float(xh[((size_t)n << 6) + lane]);
    float a1 = 0.f, a2 = 0.f, a3 = 0.f;
    int s = rowptr[n], e = rowptr[n+1];
    int r = s;
    for (; r + 4 <= e; r += 4) {
        int c0 = col[r], c1 = col[r+1], c2 = col[r+2], c3 = col[r+3];
        a0 += __bfloat162float(xh[((size_t)c0 << 6) + lane]);
        a1 += __bfloat162float(xh[((size_t)c1 << 6) + lane]);
        a2 += __bfloat162float(xh[((size_t)c2 << 6) + lane]);
        a3 += __bfloat162float(xh[((size_t)c3 << 6) + lane]);
    }
    for (; r < e; r++) a0 += __bfloat162float(xh[((size_t)col[r] << 6) + lane]);
    agg[((size_t)n << 6) + lane] = (a0 + a1) + (a2 + a3);
    if (blockIdx.x == 0 && threadIdx.x < 128) stats[threadIdx.x] = 0.f;
}

// ------------------------------------------------------------------
// Fused GIN MLP: h = relu(h0 @ w1 + b1) @ w2 + b2  (in-place over agg)
// + BN statistics (sum, sumsq per column), one atomic per col per block.
// ------------------------------------------------------------------
__global__ __launch_bounds__(128, 2) void k_gin(
    float* __restrict__ big,
    const float* __restrict__ w1, const float* __restrict__ b1,
    const float* __restrict__ w2, const float* __restrict__ b2,
    float* __restrict__ stats)
{
    __shared__ float lh[2][64*65];
    __shared__ float red[2][2][64];
    int tid = threadIdx.x;
    int wv = tid >> 6, lane = tid & 63;
    float* L = lh[wv];
    size_t base = ((size_t)blockIdx.x*128 + (size_t)wv*64) << 6;

    #pragma unroll 8
    for (int r = 0; r < 64; r++)
        L[lane*65 + r] = big[base + (size_t)r*64 + lane];
    __syncthreads();

    float acc[64];
    #pragma unroll
    for (int j = 0; j < 64; j++) acc[j] = b1[j];
    for (int k = 0; k < 64; k++) {
        float hk = L[k*65 + lane];
        const float* wr = w1 + k*64;
        #pragma unroll
        for (int j = 0; j < 64; j++) acc[j] = fmaf(hk, wr[j], acc[j]);
    }
    #pragma unroll
    for (int j = 0; j < 64; j++) L[j*65 + lane] = fmaxf(acc[j], 0.f);

    #pragma unroll
    for (int j = 0; j < 64; j++) acc[j] = b2[j];
    for (int k = 0; k < 64; k++) {
        float tk = L[k*65 + lane];
        const float* wr = w2 + k*64;
        #pragma unroll
        for (int j = 0; j < 64; j++) acc[j] = fmaf(tk, wr[j], acc[j]);
    }
    #pragma unroll
    for (int j = 0; j < 64; j++) L[j*65 + lane] = acc[j];
    __syncthreads();

    float s = 0.f, s2 = 0.f;
    #pragma unroll 8
    for (int r = 0; r < 64; r++) {
        float v = L[lane*65 + r];
        big[base + (size_t)r*64 + lane] = v;
        s += v; s2 = fmaf(v, v, s2);
    }
    red[0][wv][lane] = s; red[1][wv][lane] = s2;
    __syncthreads();
    if (tid < 128) {
        int which = tid >> 6, c = tid & 63;
        float a = red[which][0][c] + red[which][1][c];
        unsafeAtomicAdd(stats + which*64 + c, a);
    }
}

// ------------------------------------------------------------------
// BN finalize: per-column scale/shift
// ------------------------------------------------------------------
__global__ void k_bnfin(const float* __restrict__ stats,
                        const float* __restrict__ gamma,
                        const float* __restrict__ beta,
                        float* __restrict__ bnp)
{
    int c = threadIdx.x;  // 64
    float mu  = stats[c]     * (1.0f/NN);
    float ex2 = stats[64+c]  * (1.0f/NN);
    float var = ex2 - mu*mu;
    float sc  = gamma[c] * rsqrtf(var + 1e-5f);
    bnp[c]     = sc;
    bnp[64+c]  = beta[c] - mu*sc;
}

// ------------------------------------------------------------------
// BN-apply + relu -> xh (bf16, next layer gather table)
// big <- inner = relu(x @ wi + bi)
// ------------------------------------------------------------------
__global__ __launch_bounds__(128, 2) void k_bn_inner(
    float* __restrict__ big, const float* __restrict__ bnp,
    const float* __restrict__ wi, const float* __restrict__ bi,
    bf16* __restrict__ xh)
{
    __shared__ float lh[2][64*65];
    int tid = threadIdx.x, wv = tid >> 6, lane = tid & 63;
    float* L = lh[wv];
    size_t base = ((size_t)blockIdx.x*128 + (size_t)wv*64) << 6;
    float sc = bnp[lane], sh = bnp[64 + lane];
    #pragma unroll 8
    for (int r = 0; r < 64; r++) {
        float v = big[base + (size_t)r*64 + lane];
        v = fmaxf(fmaf(v, sc, sh), 0.f);
        xh[base + (size_t)r*64 + lane] = __float2bfloat16(v);
        L[lane*65 + r] = v;
    }
    __syncthreads();
    float acc[64];
    #pragma unroll
    for (int j = 0; j < 64; j++) acc[j] = bi[j];
    for (int k = 0; k < 64; k++) {
        float xk = L[k*65 + lane];
        const float* wr = wi + k*64;
        #pragma unroll
        for (int j = 0; j < 64; j++) acc[j] = fmaf(xk, wr[j], acc[j]);
    }
    #pragma unroll
    for (int j = 0; j < 64; j++) L[j*65 + lane] = fmaxf(acc[j], 0.f);
    __syncthreads();
    #pragma unroll 8
    for (int r = 0; r < 64; r++)
        big[base + (size_t)r*64 + lane] = L[lane*65 + r];
}

// ------------------------------------------------------------------
// Pool: one wave per graph, columnwise sum over [off[g], off[g+1])
// ------------------------------------------------------------------
__global__ __launch_bounds__(256) void k_pool(const float* __restrict__ inner,
    const int* __restrict__ off, float* __restrict__ pooled)
{
    int g = blockIdx.x*4 + (threadIdx.x >> 6);
    int lane = threadIdx.x & 63;
    int s = off[g], e = off[g+1];
    float a0=0.f, a1=0.f, a2=0.f, a3=0.f;
    int r = s;
    for (; r + 4 <= e; r += 4) {
        a0 += inner[(size_t)(r+0)*64 + lane];
        a1 += inner[(size_t)(r+1)*64 + lane];
        a2 += inner[(size_t)(r+2)*64 + lane];
        a3 += inner[(size_t)(r+3)*64 + lane];
    }
    for (; r < e; r++) a0 += inner[(size_t)r*64 + lane];
    pooled[g*64 + lane] = (a0+a1) + (a2+a3);
}

// ------------------------------------------------------------------
// Outer MLP: feats[:, coff:coff+64] = relu(pooled @ w + b)
// ------------------------------------------------------------------
__global__ __launch_bounds__(256) void k_outer(const float* __restrict__ pooled,
    const float* __restrict__ w, const float* __restrict__ b,
    float* __restrict__ feats, int coff)
{
    int g = blockIdx.x*256 + threadIdx.x;  // BG*64
    int bb = g >> 6, j = g & 63;
    const float* pr = pooled + bb*64;
    float a = b[j];
    for (int k = 0; k < 64; k++) a = fmaf(pr[k], w[k*64 + j], a);
    feats[bb*192 + coff + j] = fmaxf(a, 0.f);
}

// ------------------------------------------------------------------
// Tail v2: TG graphs per block, weights LDS-staged, NTN register-blocked
// so each block reads nw exactly once.
// ------------------------------------------------------------------
__global__ __launch_bounds__(256) void k_tail(
    const float* __restrict__ qf, const float* __restrict__ cf,
    const float* __restrict__ cw1, const float* __restrict__ cb1,
    const float* __restrict__ cw2, const float* __restrict__ cb2,
    const float* __restrict__ sw1, const float* __restrict__ sb1,
    const float* __restrict__ sw2, const float* __restrict__ sb2,
    const float* __restrict__ nw,  const float* __restrict__ nwb,
    const float* __restrict__ nb,
    const float* __restrict__ mw1, const float* __restrict__ mb1,
    const float* __restrict__ mw2, const float* __restrict__ mb2,
    const float* __restrict__ alpha, const float* __restrict__ beta,
    float* __restrict__ out)
{
    __shared__ float cws[192*96];          // 72 KB: cw1, then reused for cw2
    __shared__ float diff[TG][192];
    __shared__ float e1s[TG][64], e2s[TG][64];
    __shared__ float h1s[TG][96], h2s[TG][96];
    __shared__ float s1s[TG][16], s2s[TG][16], srep[TG][16];
    __shared__ float red[16][16][TG];      // [gq][t][b]

    int t = threadIdx.x;
    int b0 = blockIdx.x * TG;

    // stage cw1 + per-graph vectors
    for (int i = t; i < 192*96; i += 256) cws[i] = cw1[i];
    for (int i = t; i < TG*192; i += 256) {
        int b = i / 192, f = i % 192;
        float q = qf[(b0+b)*192 + f], c = cf[(b0+b)*192 + f];
        float d = q - c;
        diff[b][f] = __expf(-d*d);
        if (f >= 128) { e1s[b][f-128] = q; e2s[b][f-128] = c; }
    }
    __syncthreads();

    // h1 = relu(diff @ cw1 + cb1): thread = (b, 3 consecutive o)
    {
        int b = t >> 5, o = (t & 31) * 3;
        float a0 = cb1[o], a1 = cb1[o+1], a2 = cb1[o+2];
        for (int f = 0; f < 192; f++) {
            float d = diff[b][f];
            const float* w = cws + f*96 + o;
            a0 = fmaf(d, w[0], a0);
            a1 = fmaf(d, w[1], a1);
            a2 = fmaf(d, w[2], a2);
        }
        h1s[b][o] = fmaxf(a0, 0.f);
        h1s[b][o+1] = fmaxf(a1, 0.f);
        h1s[b][o+2] = fmaxf(a2, 0.f);
    }
    __syncthreads();
    // stage cw2
    for (int i = t; i < 96*96; i += 256) cws[i] = cw2[i];
    __syncthreads();
    // h2 = tanh(h1 @ cw2 + cb2)
    {
        int b = t >> 5, o = (t & 31) * 3;
        float a0 = cb2[o], a1 = cb2[o+1], a2 = cb2[o+2];
        for (int f = 0; f < 96; f++) {
            float d = h1s[b][f];
            const float* w = cws + f*96 + o;
            a0 = fmaf(d, w[0], a0);
            a1 = fmaf(d, w[1], a1);
            a2 = fmaf(d, w[2], a2);
        }
        h2s[b][o] = tanhf(a0);
        h2s[b][o+1] = tanhf(a1);
        h2s[b][o+2] = tanhf(a2);
    }
    __syncthreads();
    // s1 = relu(h2 @ sw1 + sb1)
    if (t < TG*16) {
        int b = t >> 4, o = t & 15;
        float a = sb1[o];
        for (int f = 0; f < 96; f++) a = fmaf(h2s[b][f], sw1[f*16+o], a);
        s1s[b][o] = fmaxf(a, 0.f);
    }

    // NTN: v[b,g,tt] = sum_f e1[b,f]*nw[f,g,tt]; thread = (tt, 4 g's)
    {
        int tt = t & 15, gq = t >> 4;
        int g0 = gq * 4;
        int lane = t & 63;
        float e1v[TG];
        #pragma unroll
        for (int b = 0; b < TG; b++) e1v[b] = e1s[b][lane];
        float v0[TG], v1[TG], v2[TG], v3[TG];
        #pragma unroll
        for (int b = 0; b < TG; b++) { v0[b]=0.f; v1[b]=0.f; v2[b]=0.f; v3[b]=0.f; }
        for (int f = 0; f < 64; f++) {
            const float* wp = nw + ((size_t)f*64 + g0)*16 + tt;
            float w0 = wp[0], w1 = wp[16], w2 = wp[32], w3 = wp[48];
            #pragma unroll
            for (int b = 0; b < TG; b++) {
                float e = __shfl(e1v[b], f, 64);
                v0[b] = fmaf(e, w0, v0[b]);
                v1[b] = fmaf(e, w1, v1[b]);
                v2[b] = fmaf(e, w2, v2[b]);
                v3[b] = fmaf(e, w3, v3[b]);
            }
        }
        #pragma unroll
        for (int b = 0; b < TG; b++) {
            float p = v0[b]*e2s[b][g0] + v1[b]*e2s[b][g0+1]
                    + v2[b]*e2s[b][g0+2] + v3[b]*e2s[b][g0+3];
            red[gq][tt][b] = p;
        }
    }
    __syncthreads();
    // reduce over gq + block term + bias + relu
    if (t < TG*16) {
        int b = t >> 4, tt = t & 15;
        float sc = 0.f;
        #pragma unroll
        for (int gq = 0; gq < 16; gq++) sc += red[gq][tt][b];
        float blk = nb[tt];
        for (int f = 0; f < 64; f++) blk = fmaf(e1s[b][f], nwb[tt*128 + f], blk);
        for (int f = 0; f < 64; f++) blk = fmaf(e2s[b][f], nwb[tt*128 + 64 + f], blk);
        srep[b][tt] = fmaxf(sc + blk, 0.f);
    }
    __syncthreads();
    if (t < TG*16) {
        int b = t >> 4, o = t & 15;
        float a = mb1[o];
        #pragma unroll
        for (int f = 0; f < 16; f++) a = fmaf(srep[b][f], mw1[f*16+o], a);
        s2s[b][o] = fmaxf(a, 0.f);
    }
    __syncthreads();
    if (t < TG) {
        float sco = sb2[0], sm = mb2[0];
        #pragma unroll
        for (int f = 0; f < 16; f++) {
            sco = fmaf(s1s[t][f], sw2[f], sco);
            sm  = fmaf(s2s[t][f], mw2[f], sm);
        }
        float score = 1.f / (1.f + __expf(-sco));
        float sim   = 1.f / (1.f + __expf(-sm));
        out[b0 + t] = alpha[0]*score + beta[0]*sim;
    }
}

// ------------------------------------------------------------------
extern "C" void kernel_launch(void* const* d_in, const int* in_sizes, int n_in,
                              void* d_out, int out_size, void* d_ws, size_t ws_size,
                              hipStream_t stream)
{
    const float* qx  = (const float*)d_in[0];
    const float* cx  = (const float*)d_in[1];
    const int*   qei = (const int*)d_in[2];
    const int*   cei = (const int*)d_in[3];
    const int*   qgi = (const int*)d_in[4];
    const int*   cgi = (const int*)d_in[5];
    const float* Wgw1 = (const float*)d_in[6];
    const float* Wgb1 = (const float*)d_in[7];
    const float* Wgw2 = (const float*)d_in[8];
    const float* Wgb2 = (const float*)d_in[9];
    const float* Wgam = (const float*)d_in[10];
    const float* Wbet = (const float*)d_in[11];
    const float* Weps = (const float*)d_in[12];
    const float* Wiw  = (const float*)d_in[13];
    const float* Wib  = (const float*)d_in[14];
    const float* Wow  = (const float*)d_in[15];
    const float* Wob  = (const float*)d_in[16];
    const float* Wcw1 = (const float*)d_in[17];
    const float* Wcb1 = (const float*)d_in[18];
    const float* Wcw2 = (const float*)d_in[19];
    const float* Wcb2 = (const float*)d_in[20];
    const float* Wsw1 = (const float*)d_in[21];
    const float* Wsb1 = (const float*)d_in[22];
    const float* Wsw2 = (const float*)d_in[23];
    const float* Wsb2 = (const float*)d_in[24];
    const float* Wnw  = (const float*)d_in[25];
    const float* Wnwb = (const float*)d_in[26];
    const float* Wnb  = (const float*)d_in[27];
    const float* Wmw1 = (const float*)d_in[28];
    const float* Wmb1 = (const float*)d_in[29];
    const float* Wmw2 = (const float*)d_in[30];
    const float* Wmb2 = (const float*)d_in[31];
    const float* Wal  = (const float*)d_in[32];
    const float* Wbe  = (const float*)d_in[33];

    float* F      = (float*)d_ws;
    float* big    = F;                       // N*64
    float* stats  = F + 8388608;             // 128
    float* bnp    = stats + 128;             // 128
    float* pooled = bnp + 128;               // BG*64
    float* qf     = pooled + 65536;          // BG*192
    float* cf     = qf + 196608;             // BG*192
    int*   qoff   = (int*)(cf + 196608);     // BG+1
    int*   coff   = qoff + (BG + 1);         // BG+1
    int*   rowptr = coff + (BG + 1);         // NN+1
    int*   wptr   = rowptr + (NN + 1);       // NN   (aliases histogram cnt)
    int*   col    = wptr + NN;               // NEDGE
    int*   bsum   = col + NEDGE;             // 128
    int*   boff   = bsum + 128;              // 128
    bf16*  xh     = (bf16*)(boff + 128);     // N*64 bf16

    for (int side = 0; side < 2; side++) {
        const float* x0 = side ? cx  : qx;
        const int* ei   = side ? cei : qei;
        const int* gi   = side ? cgi : qgi;
        int* off        = side ? coff : qoff;
        float* feats    = side ? cf  : qf;

        k_offsets<<<5, 256, 0, stream>>>(gi, off);

        // CSR build for this side (reused by all 3 layers)
        k_zero<<<NN/256, 256, 0, stream>>>(wptr);
        k_hist<<<NEDGE/256, 256, 0, stream>>>(ei, wptr);
        k_scan1<<<128, 256, 0, stream>>>(wptr, rowptr, bsum);
        k_scan2<<<1, 128, 0, stream>>>(bsum, boff, rowptr);
        k_scan3<<<NN/256, 256, 0, stream>>>(rowptr, boff, wptr);
        k_fill<<<NEDGE/256, 256, 0, stream>>>(ei, wptr, col);

        // bf16 shadow of layer-0 features
        k_cvt<<<NN*64/256, 256, 0, stream>>>(x0, xh);

        for (int l = 0; l < LAYERS; l++) {
            k_aggregate<<<NN/4, 256, 0, stream>>>(xh, rowptr, col, Weps + l,
                                                  big, stats);
            k_gin<<<1024, 128, 0, stream>>>(big, Wgw1 + l*4096, Wgb1 + l*64,
                                            Wgw2 + l*4096, Wgb2 + l*64, stats);
            k_bnfin<<<1, 64, 0, stream>>>(stats, Wgam + l*64, Wbet + l*64, bnp);
            k_bn_inner<<<1024, 128, 0, stream>>>(big, bnp, Wiw + l*4096,
                                                 Wib + l*64, xh);
            k_pool<<<BG/4, 256, 0, stream>>>(big, off, pooled);
            k_outer<<<BG*64/256, 256, 0, stream>>>(pooled, Wow + l*4096, Wob + l*64,
                                                   feats, l*64);
        }
    }

    k_tail<<<BG/TG, 256, 0, stream>>>(qf, cf, Wcw1, Wcb1, Wcw2, Wcb2,
                                      Wsw1, Wsb1, Wsw2, Wsb2,
                                      Wnw, Wnwb, Wnb, Wmw1, Wmb1, Wmw2, Wmb2,
                                      Wal, Wbe, (float*)d_out);
}

// Round 5
// 1265.078 us; speedup vs baseline: 1.9795x; 1.2107x over previous
//
#include <hip/hip_runtime.h>
#include <hip/hip_bf16.h>

typedef __hip_bfloat16 bf16;
typedef __attribute__((ext_vector_type(8))) short short8;
typedef __attribute__((ext_vector_type(4))) float floatx4;

#define NN     131072
#define NEDGE  1048576
#define BG     1024
#define LAYERS 3
#define TG     8      // graphs per tail block

// bf16 split helpers (RNE)
__device__ __forceinline__ short f2bf_s(float f){
    union { float f; unsigned u; } x; x.f = f;
    unsigned r = x.u + 0x7fffu + ((x.u >> 16) & 1u);
    return (short)(r >> 16);
}
__device__ __forceinline__ float bf2f_s(short s){
    union { unsigned u; float f; } x; x.u = ((unsigned)(unsigned short)s) << 16;
    return x.f;
}

// ------------------------------------------------------------------
// Segment offsets: off[g] = lower_bound(graph_idx, g)
// ------------------------------------------------------------------
__global__ __launch_bounds__(256) void k_offsets(const int* __restrict__ gi,
                                                 int* __restrict__ off)
{
    int g = blockIdx.x*256 + threadIdx.x;
    if (g > BG) return;
    int lo = 0, hi = NN;
    while (lo < hi) { int mid = (lo + hi) >> 1; if (gi[mid] < g) lo = mid + 1; else hi = mid; }
    off[g] = lo;
}

// ------------------------------------------------------------------
// CSR build
// ------------------------------------------------------------------
__global__ __launch_bounds__(256) void k_zero(int* __restrict__ cnt)
{
    int i = blockIdx.x*256 + threadIdx.x;
    if (i < NN) cnt[i] = 0;
}

__global__ __launch_bounds__(256) void k_hist(const int* __restrict__ ei,
                                              int* __restrict__ cnt)
{
    int e = blockIdx.x*256 + threadIdx.x;
    atomicAdd(cnt + ei[NEDGE + e], 1);
}

__global__ __launch_bounds__(256) void k_scan1(const int* __restrict__ cnt,
    int* __restrict__ rowptr, int* __restrict__ bsum)
{
    __shared__ int sd[256];
    int t = threadIdx.x;
    int base = blockIdx.x*1024 + t*4;
    int c0 = cnt[base], c1 = cnt[base+1], c2 = cnt[base+2], c3 = cnt[base+3];
    int tsum = c0 + c1 + c2 + c3;
    sd[t] = tsum;
    __syncthreads();
    for (int off = 1; off < 256; off <<= 1) {
        int v = (t >= off) ? sd[t-off] : 0;
        __syncthreads();
        sd[t] += v;
        __syncthreads();
    }
    int excl = sd[t] - tsum;
    rowptr[base]   = excl;
    rowptr[base+1] = excl + c0;
    rowptr[base+2] = excl + c0 + c1;
    rowptr[base+3] = excl + c0 + c1 + c2;
    if (t == 255) bsum[blockIdx.x] = sd[255];
}

__global__ __launch_bounds__(128) void k_scan2(const int* __restrict__ bsum,
    int* __restrict__ boff, int* __restrict__ rowptr)
{
    __shared__ int sd[128];
    int t = threadIdx.x;
    int v0 = bsum[t];
    sd[t] = v0;
    __syncthreads();
    for (int off = 1; off < 128; off <<= 1) {
        int v = (t >= off) ? sd[t-off] : 0;
        __syncthreads();
        sd[t] += v;
        __syncthreads();
    }
    boff[t] = sd[t] - v0;
    if (t == 0) rowptr[NN] = NEDGE;
}

__global__ __launch_bounds__(256) void k_scan3(int* __restrict__ rowptr,
    const int* __restrict__ boff, int* __restrict__ wptr)
{
    int i = blockIdx.x*256 + threadIdx.x;
    int v = rowptr[i] + boff[i >> 10];
    rowptr[i] = v;
    wptr[i] = v;
}

__global__ __launch_bounds__(256) void k_fill(const int* __restrict__ ei,
    int* __restrict__ wptr, int* __restrict__ col)
{
    int e = blockIdx.x*256 + threadIdx.x;
    int s = ei[e];
    int d = ei[NEDGE + e];
    int pos = atomicAdd(wptr + d, 1);
    col[pos] = s;
}

// ------------------------------------------------------------------
// fp32 -> bf16 shadow copy of node features (layer-0 input)
// ------------------------------------------------------------------
__global__ __launch_bounds__(256) void k_cvt(const float* __restrict__ x,
                                             bf16* __restrict__ xh)
{
    int i = blockIdx.x*256 + threadIdx.x;
    xh[i] = __float2bfloat16(x[i]);
}

// ------------------------------------------------------------------
// Weight prep (once/launch): Wt[n][k] = W[k][n], split bf16 hi/lo.
// mats: 0 = gin_w1, 1 = gin_w2, 2 = inner_w, each [L][64][64].
// ------------------------------------------------------------------
__global__ __launch_bounds__(256) void k_wprep(
    const float* __restrict__ gw1, const float* __restrict__ gw2,
    const float* __restrict__ iw,
    short* __restrict__ w1h, short* __restrict__ w1l,
    short* __restrict__ w2h, short* __restrict__ w2l,
    short* __restrict__ wih, short* __restrict__ wil)
{
    int i = blockIdx.x*256 + threadIdx.x;
    if (i >= 3*LAYERS*4096) return;
    int msel = i / (LAYERS*4096);
    int rem  = i % (LAYERS*4096);
    int l = rem >> 12, idx = rem & 4095;
    int n = idx >> 6, k = idx & 63;
    const float* src = (msel==0) ? gw1 : (msel==1) ? gw2 : iw;
    float v = src[l*4096 + k*64 + n];
    short hi = f2bf_s(v);
    short lo = f2bf_s(v - bf2f_s(hi));
    short* dh = (msel==0) ? w1h : (msel==1) ? w2h : wih;
    short* dl = (msel==0) ? w1l : (msel==1) ? w2l : wil;
    dh[rem] = hi;   // dst = l*4096 + n*64 + k  (== rem by construction)
    dl[rem] = lo;
}

// ------------------------------------------------------------------
// Aggregate: one wave per node, lane = feature; bf16 gather table.
// Also zeroes stats and pooled for this layer.
// ------------------------------------------------------------------
__global__ __launch_bounds__(256) void k_aggregate(const bf16* __restrict__ xh,
    const int* __restrict__ rowptr, const int* __restrict__ col,
    const float* __restrict__ epsp, float* __restrict__ agg,
    float* __restrict__ stats, float* __restrict__ pooled)
{
    int n = blockIdx.x*4 + (threadIdx.x >> 6);
    int lane = threadIdx.x & 63;
    float ep = 1.0f + *epsp;
    float a0 = ep * __bfloat162float(xh[((size_t)n << 6) + lane]);
    float a1 = 0.f, a2 = 0.f, a3 = 0.f;
    int s = rowptr[n], e = rowptr[n+1];
    int r = s;
    for (; r + 4 <= e; r += 4) {
        int c0 = col[r], c1 = col[r+1], c2 = col[r+2], c3 = col[r+3];
        a0 += __bfloat162float(xh[((size_t)c0 << 6) + lane]);
        a1 += __bfloat162float(xh[((size_t)c1 << 6) + lane]);
        a2 += __bfloat162float(xh[((size_t)c2 << 6) + lane]);
        a3 += __bfloat162float(xh[((size_t)c3 << 6) + lane]);
    }
    for (; r < e; r++) a0 += __bfloat162float(xh[((size_t)col[r] << 6) + lane]);
    agg[((size_t)n << 6) + lane] = (a0 + a1) + (a2 + a3);
    if (blockIdx.x == 0 && threadIdx.x < 128) stats[threadIdx.x] = 0.f;
    if (blockIdx.x < 256) pooled[blockIdx.x*256 + threadIdx.x] = 0.f;
}

// ------------------------------------------------------------------
// MFMA GIN MLP: big <- relu(big@W1+b1)@W2+b2, + BN stats.
// Wave = 32 nodes x 64 feats. Split-bf16 (3 mfma/tile) ~ fp32 precision.
// MFMA 16x16x32 layouts: A[m=lane&15][k=q*8+j]; B[k=q*8+j][n=lane&15];
// D[row=q*4+r][col=lane&15]  (q = lane>>4).
// ------------------------------------------------------------------
__global__ __launch_bounds__(256) void k_gin(
    float* __restrict__ big,
    const short* __restrict__ w1h, const short* __restrict__ w1l,
    const float* __restrict__ b1,
    const short* __restrict__ w2h, const short* __restrict__ w2l,
    const float* __restrict__ b2,
    float* __restrict__ stats)
{
    __shared__ __align__(16) char buf[4][9472];
    __shared__ float red[2][4][64];
    int tid = threadIdx.x, wv = tid >> 6, lane = tid & 63;
    int q = lane >> 4, m = lane & 15;
    int nb = blockIdx.x*128 + wv*32;
    short* Sh = (short*)buf[wv];
    short* Sl = Sh + 2304;      // 32*72

    // GEMM1 A-frags direct from fp32 big, split in-register
    short8 Ah[2][2], Al[2][2];
    #pragma unroll
    for (int mc=0; mc<2; mc++)
      #pragma unroll
      for (int kc=0; kc<2; kc++){
        const float* ap = big + (((size_t)(nb + mc*16 + m)) << 6) + kc*32 + q*8;
        short8 h, l;
        #pragma unroll
        for (int j=0;j<8;j++){
            float a = ap[j];
            short hb = f2bf_s(a);
            h[j] = hb; l[j] = f2bf_s(a - bf2f_s(hb));
        }
        Ah[mc][kc] = h; Al[mc][kc] = l;
      }

    floatx4 acc[2][4];
    #pragma unroll
    for (int mc=0;mc<2;mc++)
      #pragma unroll
      for (int nc=0;nc<4;nc++) acc[mc][nc] = (floatx4){0.f,0.f,0.f,0.f};

    #pragma unroll
    for (int nc=0;nc<4;nc++){
      #pragma unroll
      for (int kc=0;kc<2;kc++){
        short8 bh = *(const short8*)(w1h + (nc*16+m)*64 + kc*32 + q*8);
        short8 bl = *(const short8*)(w1l + (nc*16+m)*64 + kc*32 + q*8);
        #pragma unroll
        for (int mc=0;mc<2;mc++){
          acc[mc][nc] = __builtin_amdgcn_mfma_f32_16x16x32_bf16(Ah[mc][kc], bh, acc[mc][nc],0,0,0);
          acc[mc][nc] = __builtin_amdgcn_mfma_f32_16x16x32_bf16(Al[mc][kc], bh, acc[mc][nc],0,0,0);
          acc[mc][nc] = __builtin_amdgcn_mfma_f32_16x16x32_bf16(Ah[mc][kc], bl, acc[mc][nc],0,0,0);
        }
      }
    }

    // epilogue 1: bias + relu, split into LDS (stride 72 shorts, 16B-aligned rows)
    #pragma unroll
    for (int nc=0;nc<4;nc++){
      float bia = b1[nc*16+m];
      #pragma unroll
      for (int mc=0;mc<2;mc++)
        #pragma unroll
        for (int r=0;r<4;r++){
          float v = fmaxf(acc[mc][nc][r] + bia, 0.f);
          int row = mc*16 + q*4 + r, cl = nc*16 + m;
          short hb = f2bf_s(v);
          Sh[row*72+cl] = hb;
          Sl[row*72+cl] = f2bf_s(v - bf2f_s(hb));
        }
    }
    __syncthreads();

    // GEMM2: A from LDS
    short8 A2h[2][2], A2l[2][2];
    #pragma unroll
    for (int mc=0; mc<2; mc++)
      #pragma unroll
      for (int kc=0; kc<2; kc++){
        A2h[mc][kc] = *(const short8*)(Sh + (mc*16+m)*72 + kc*32 + q*8);
        A2l[mc][kc] = *(const short8*)(Sl + (mc*16+m)*72 + kc*32 + q*8);
      }
    floatx4 acc2[2][4];
    #pragma unroll
    for (int mc=0;mc<2;mc++)
      #pragma unroll
      for (int nc=0;nc<4;nc++) acc2[mc][nc] = (floatx4){0.f,0.f,0.f,0.f};
    #pragma unroll
    for (int nc=0;nc<4;nc++){
      #pragma unroll
      for (int kc=0;kc<2;kc++){
        short8 bh = *(const short8*)(w2h + (nc*16+m)*64 + kc*32 + q*8);
        short8 bl = *(const short8*)(w2l + (nc*16+m)*64 + kc*32 + q*8);
        #pragma unroll
        for (int mc=0;mc<2;mc++){
          acc2[mc][nc] = __builtin_amdgcn_mfma_f32_16x16x32_bf16(A2h[mc][kc], bh, acc2[mc][nc],0,0,0);
          acc2[mc][nc] = __builtin_amdgcn_mfma_f32_16x16x32_bf16(A2l[mc][kc], bh, acc2[mc][nc],0,0,0);
          acc2[mc][nc] = __builtin_amdgcn_mfma_f32_16x16x32_bf16(A2h[mc][kc], bl, acc2[mc][nc],0,0,0);
        }
      }
    }

    // epilogue 2: bias, store, BN stats
    #pragma unroll
    for (int nc=0;nc<4;nc++){
      float bia = b2[nc*16+m];
      float s = 0.f, s2 = 0.f;
      #pragma unroll
      for (int mc=0;mc<2;mc++)
        #pragma unroll
        for (int r=0;r<4;r++){
          float v = acc2[mc][nc][r] + bia;
          big[(((size_t)(nb + mc*16 + q*4 + r)) << 6) + nc*16 + m] = v;
          s += v; s2 = fmaf(v, v, s2);
        }
      s  += __shfl_xor(s, 16, 64);  s  += __shfl_xor(s, 32, 64);
      s2 += __shfl_xor(s2,16, 64);  s2 += __shfl_xor(s2,32, 64);
      if (q == 0){ red[0][wv][nc*16+m] = s; red[1][wv][nc*16+m] = s2; }
    }
    __syncthreads();
    if (tid < 128){
      int which = tid >> 6, c = tid & 63;
      float a = red[which][0][c]+red[which][1][c]+red[which][2][c]+red[which][3][c];
      unsafeAtomicAdd(stats + which*64 + c, a);
    }
}

// ------------------------------------------------------------------
// BN finalize: per-column scale/shift
// ------------------------------------------------------------------
__global__ void k_bnfin(const float* __restrict__ stats,
                        const float* __restrict__ gamma,
                        const float* __restrict__ beta,
                        float* __restrict__ bnp)
{
    int c = threadIdx.x;  // 64
    float mu  = stats[c]     * (1.0f/NN);
    float ex2 = stats[64+c]  * (1.0f/NN);
    float var = ex2 - mu*mu;
    float sc  = gamma[c] * rsqrtf(var + 1e-5f);
    bnp[c]     = sc;
    bnp[64+c]  = beta[c] - mu*sc;
}

// ------------------------------------------------------------------
// MFMA BN-apply + inner MLP + fused segment-pool.
// x = relu(BN(big)) -> xh (bf16 table); inner = relu(x@Wi+bi) -> pooled.
// ------------------------------------------------------------------
__global__ __launch_bounds__(256) void k_bn_inner(
    const float* __restrict__ big, const float* __restrict__ bnp,
    const short* __restrict__ wih, const short* __restrict__ wil,
    const float* __restrict__ bi,
    bf16* __restrict__ xh,
    const int* __restrict__ gidx, float* __restrict__ pooled)
{
    __shared__ __align__(16) char buf[4][9472];
    int tid = threadIdx.x, wv = tid >> 6, lane = tid & 63;
    int q = lane >> 4, m = lane & 15;
    int nb = blockIdx.x*128 + wv*32;
    short* Sh = (short*)buf[wv];
    short* Sl = Sh + 2304;

    float sc = bnp[lane], sh = bnp[64 + lane];
    for (int rr = 0; rr < 32; rr++){
        float v = big[(((size_t)(nb+rr)) << 6) + lane];
        v = fmaxf(fmaf(v, sc, sh), 0.f);
        xh[(((size_t)(nb+rr)) << 6) + lane] = __float2bfloat16(v);
        short hb = f2bf_s(v);
        Sh[rr*72 + lane] = hb;
        Sl[rr*72 + lane] = f2bf_s(v - bf2f_s(hb));
    }
    __syncthreads();

    short8 A2h[2][2], A2l[2][2];
    #pragma unroll
    for (int mc=0; mc<2; mc++)
      #pragma unroll
      for (int kc=0; kc<2; kc++){
        A2h[mc][kc] = *(const short8*)(Sh + (mc*16+m)*72 + kc*32 + q*8);
        A2l[mc][kc] = *(const short8*)(Sl + (mc*16+m)*72 + kc*32 + q*8);
      }
    floatx4 acc[2][4];
    #pragma unroll
    for (int mc=0;mc<2;mc++)
      #pragma unroll
      for (int nc=0;nc<4;nc++) acc[mc][nc] = (floatx4){0.f,0.f,0.f,0.f};
    #pragma unroll
    for (int nc=0;nc<4;nc++){
      #pragma unroll
      for (int kc=0;kc<2;kc++){
        short8 bh = *(const short8*)(wih + (nc*16+m)*64 + kc*32 + q*8);
        short8 bl = *(const short8*)(wil + (nc*16+m)*64 + kc*32 + q*8);
        #pragma unroll
        for (int mc=0;mc<2;mc++){
          acc[mc][nc] = __builtin_amdgcn_mfma_f32_16x16x32_bf16(A2h[mc][kc], bh, acc[mc][nc],0,0,0);
          acc[mc][nc] = __builtin_amdgcn_mfma_f32_16x16x32_bf16(A2l[mc][kc], bh, acc[mc][nc],0,0,0);
          acc[mc][nc] = __builtin_amdgcn_mfma_f32_16x16x32_bf16(A2h[mc][kc], bl, acc[mc][nc],0,0,0);
        }
      }
    }
    __syncthreads();   // LDS reads done; safe to repurpose buf

    // inner (bias+relu) -> LDS float tile (stride 66), then segment-pool
    float* P = (float*)buf[wv];
    #pragma unroll
    for (int nc=0;nc<4;nc++){
      float bia = bi[nc*16+m];
      #pragma unroll
      for (int mc=0;mc<2;mc++)
        #pragma unroll
        for (int r=0;r<4;r++){
          float v = fmaxf(acc[mc][nc][r] + bia, 0.f);
          P[(mc*16 + q*4 + r)*66 + nc*16 + m] = v;
        }
    }
    __syncthreads();

    int gv = (lane < 32) ? gidx[nb + lane] : 0;
    int cur = __shfl(gv, 0, 64);
    float a = 0.f;
    for (int rr = 0; rr < 32; rr++){
        int g = __shfl(gv, rr, 64);
        if (g != cur){
            unsafeAtomicAdd(pooled + (size_t)cur*64 + lane, a);
            a = 0.f; cur = g;
        }
        a += P[rr*66 + lane];
    }
    unsafeAtomicAdd(pooled + (size_t)cur*64 + lane, a);
}

// ------------------------------------------------------------------
// Outer MLP: feats[:, coff:coff+64] = relu(pooled @ w + b)
// ------------------------------------------------------------------
__global__ __launch_bounds__(256) void k_outer(const float* __restrict__ pooled,
    const float* __restrict__ w, const float* __restrict__ b,
    float* __restrict__ feats, int coff)
{
    int g = blockIdx.x*256 + threadIdx.x;  // BG*64
    int bb = g >> 6, j = g & 63;
    const float* pr = pooled + bb*64;
    float a = b[j];
    for (int k = 0; k < 64; k++) a = fmaf(pr[k], w[k*64 + j], a);
    feats[bb*192 + coff + j] = fmaxf(a, 0.f);
}

// ------------------------------------------------------------------
// Tail: TG graphs per block, weights LDS-staged, NTN register-blocked
// ------------------------------------------------------------------
__global__ __launch_bounds__(256) void k_tail(
    const float* __restrict__ qf, const float* __restrict__ cf,
    const float* __restrict__ cw1, const float* __restrict__ cb1,
    const float* __restrict__ cw2, const float* __restrict__ cb2,
    const float* __restrict__ sw1, const float* __restrict__ sb1,
    const float* __restrict__ sw2, const float* __restrict__ sb2,
    const float* __restrict__ nw,  const float* __restrict__ nwb,
    const float* __restrict__ nb,
    const float* __restrict__ mw1, const float* __restrict__ mb1,
    const float* __restrict__ mw2, const float* __restrict__ mb2,
    const float* __restrict__ alpha, const float* __restrict__ beta,
    float* __restrict__ out)
{
    __shared__ float cws[192*96];
    __shared__ float diff[TG][192];
    __shared__ float e1s[TG][64], e2s[TG][64];
    __shared__ float h1s[TG][96], h2s[TG][96];
    __shared__ float s1s[TG][16], s2s[TG][16], srep[TG][16];
    __shared__ float red[16][16][TG];

    int t = threadIdx.x;
    int b0 = blockIdx.x * TG;

    for (int i = t; i < 192*96; i += 256) cws[i] = cw1[i];
    for (int i = t; i < TG*192; i += 256) {
        int b = i / 192, f = i % 192;
        float qv = qf[(b0+b)*192 + f], cv = cf[(b0+b)*192 + f];
        float d = qv - cv;
        diff[b][f] = __expf(-d*d);
        if (f >= 128) { e1s[b][f-128] = qv; e2s[b][f-128] = cv; }
    }
    __syncthreads();

    {
        int b = t >> 5, o = (t & 31) * 3;
        float a0 = cb1[o], a1 = cb1[o+1], a2 = cb1[o+2];
        for (int f = 0; f < 192; f++) {
            float d = diff[b][f];
            const float* w = cws + f*96 + o;
            a0 = fmaf(d, w[0], a0);
            a1 = fmaf(d, w[1], a1);
            a2 = fmaf(d, w[2], a2);
        }
        h1s[b][o] = fmaxf(a0, 0.f);
        h1s[b][o+1] = fmaxf(a1, 0.f);
        h1s[b][o+2] = fmaxf(a2, 0.f);
    }
    __syncthreads();
    for (int i = t; i < 96*96; i += 256) cws[i] = cw2[i];
    __syncthreads();
    {
        int b = t >> 5, o = (t & 31) * 3;
        float a0 = cb2[o], a1 = cb2[o+1], a2 = cb2[o+2];
        for (int f = 0; f < 96; f++) {
            float d = h1s[b][f];
            const float* w = cws + f*96 + o;
            a0 = fmaf(d, w[0], a0);
            a1 = fmaf(d, w[1], a1);
            a2 = fmaf(d, w[2], a2);
        }
        h2s[b][o] = tanhf(a0);
        h2s[b][o+1] = tanhf(a1);
        h2s[b][o+2] = tanhf(a2);
    }
    __syncthreads();
    if (t < TG*16) {
        int b = t >> 4, o = t & 15;
        float a = sb1[o];
        for (int f = 0; f < 96; f++) a = fmaf(h2s[b][f], sw1[f*16+o], a);
        s1s[b][o] = fmaxf(a, 0.f);
    }

    {
        int tt = t & 15, gq = t >> 4;
        int g0 = gq * 4;
        int lane = t & 63;
        float e1v[TG];
        #pragma unroll
        for (int b = 0; b < TG; b++) e1v[b] = e1s[b][lane];
        float v0[TG], v1[TG], v2[TG], v3[TG];
        #pragma unroll
        for (int b = 0; b < TG; b++) { v0[b]=0.f; v1[b]=0.f; v2[b]=0.f; v3[b]=0.f; }
        for (int f = 0; f < 64; f++) {
            const float* wp = nw + ((size_t)f*64 + g0)*16 + tt;
            float w0 = wp[0], w1 = wp[16], w2 = wp[32], w3 = wp[48];
            #pragma unroll
            for (int b = 0; b < TG; b++) {
                float e = __shfl(e1v[b], f, 64);
                v0[b] = fmaf(e, w0, v0[b]);
                v1[b] = fmaf(e, w1, v1[b]);
                v2[b] = fmaf(e, w2, v2[b]);
                v3[b] = fmaf(e, w3, v3[b]);
            }
        }
        #pragma unroll
        for (int b = 0; b < TG; b++) {
            float p = v0[b]*e2s[b][g0] + v1[b]*e2s[b][g0+1]
                    + v2[b]*e2s[b][g0+2] + v3[b]*e2s[b][g0+3];
            red[gq][tt][b] = p;
        }
    }
    __syncthreads();
    if (t < TG*16) {
        int b = t >> 4, tt = t & 15;
        float scv = 0.f;
        #pragma unroll
        for (int gq = 0; gq < 16; gq++) scv += red[gq][tt][b];
        float blk = nb[tt];
        for (int f = 0; f < 64; f++) blk = fmaf(e1s[b][f], nwb[tt*128 + f], blk);
        for (int f = 0; f < 64; f++) blk = fmaf(e2s[b][f], nwb[tt*128 + 64 + f], blk);
        srep[b][tt] = fmaxf(scv + blk, 0.f);
    }
    __syncthreads();
    if (t < TG*16) {
        int b = t >> 4, o = t & 15;
        float a = mb1[o];
        #pragma unroll
        for (int f = 0; f < 16; f++) a = fmaf(srep[b][f], mw1[f*16+o], a);
        s2s[b][o] = fmaxf(a, 0.f);
    }
    __syncthreads();
    if (t < TG) {
        float sco = sb2[0], sm = mb2[0];
        #pragma unroll
        for (int f = 0; f < 16; f++) {
            sco = fmaf(s1s[t][f], sw2[f], sco);
            sm  = fmaf(s2s[t][f], mw2[f], sm);
        }
        float score = 1.f / (1.f + __expf(-sco));
        float sim   = 1.f / (1.f + __expf(-sm));
        out[b0 + t] = alpha[0]*score + beta[0]*sim;
    }
}

// ------------------------------------------------------------------
extern "C" void kernel_launch(void* const* d_in, const int* in_sizes, int n_in,
                              void* d_out, int out_size, void* d_ws, size_t ws_size,
                              hipStream_t stream)
{
    const float* qx  = (const float*)d_in[0];
    const float* cx  = (const float*)d_in[1];
    const int*   qei = (const int*)d_in[2];
    const int*   cei = (const int*)d_in[3];
    const int*   qgi = (const int*)d_in[4];
    const int*   cgi = (const int*)d_in[5];
    const float* Wgw1 = (const float*)d_in[6];
    const float* Wgb1 = (const float*)d_in[7];
    const float* Wgw2 = (const float*)d_in[8];
    const float* Wgb2 = (const float*)d_in[9];
    const float* Wgam = (const float*)d_in[10];
    const float* Wbet = (const float*)d_in[11];
    const float* Weps = (const float*)d_in[12];
    const float* Wiw  = (const float*)d_in[13];
    const float* Wib  = (const float*)d_in[14];
    const float* Wow  = (const float*)d_in[15];
    const float* Wob  = (const float*)d_in[16];
    const float* Wcw1 = (const float*)d_in[17];
    const float* Wcb1 = (const float*)d_in[18];
    const float* Wcw2 = (const float*)d_in[19];
    const float* Wcb2 = (const float*)d_in[20];
    const float* Wsw1 = (const float*)d_in[21];
    const float* Wsb1 = (const float*)d_in[22];
    const float* Wsw2 = (const float*)d_in[23];
    const float* Wsb2 = (const float*)d_in[24];
    const float* Wnw  = (const float*)d_in[25];
    const float* Wnwb = (const float*)d_in[26];
    const float* Wnb  = (const float*)d_in[27];
    const float* Wmw1 = (const float*)d_in[28];
    const float* Wmb1 = (const float*)d_in[29];
    const float* Wmw2 = (const float*)d_in[30];
    const float* Wmb2 = (const float*)d_in[31];
    const float* Wal  = (const float*)d_in[32];
    const float* Wbe  = (const float*)d_in[33];

    float* F      = (float*)d_ws;
    float* big    = F;                       // N*64
    float* stats  = F + 8388608;             // 128
    float* bnp    = stats + 128;             // 128
    float* pooled = bnp + 128;               // BG*64
    float* qf     = pooled + 65536;          // BG*192
    float* cf     = qf + 196608;             // BG*192
    int*   qoff   = (int*)(cf + 196608);     // BG+1
    int*   coff   = qoff + (BG + 1);         // BG+1
    int*   rowptr = coff + (BG + 1);         // NN+1
    int*   wptr   = rowptr + (NN + 1);       // NN (histogram alias)
    int*   col    = wptr + NN;               // NEDGE
    int*   bsum   = col + NEDGE;             // 128
    int*   boff   = bsum + 128;              // 128
    bf16*  xh     = (bf16*)(boff + 128);     // N*64 bf16
    uintptr_t wtb = (uintptr_t)(xh + (size_t)NN*64);
    wtb = (wtb + 63) & ~((uintptr_t)63);
    short* w1h = (short*)wtb;                // 3*4096 each
    short* w1l = w1h + 3*4096;
    short* w2h = w1l + 3*4096;
    short* w2l = w2h + 3*4096;
    short* wih = w2l + 3*4096;
    short* wil = wih + 3*4096;

    k_wprep<<<144, 256, 0, stream>>>(Wgw1, Wgw2, Wiw, w1h, w1l, w2h, w2l, wih, wil);

    for (int side = 0; side < 2; side++) {
        const float* x0 = side ? cx  : qx;
        const int* ei   = side ? cei : qei;
        const int* gi   = side ? cgi : qgi;
        int* off        = side ? coff : qoff;
        float* feats    = side ? cf  : qf;

        k_offsets<<<5, 256, 0, stream>>>(gi, off);

        k_zero<<<NN/256, 256, 0, stream>>>(wptr);
        k_hist<<<NEDGE/256, 256, 0, stream>>>(ei, wptr);
        k_scan1<<<128, 256, 0, stream>>>(wptr, rowptr, bsum);
        k_scan2<<<1, 128, 0, stream>>>(bsum, boff, rowptr);
        k_scan3<<<NN/256, 256, 0, stream>>>(rowptr, boff, wptr);
        k_fill<<<NEDGE/256, 256, 0, stream>>>(ei, wptr, col);

        k_cvt<<<NN*64/256, 256, 0, stream>>>(x0, xh);

        for (int l = 0; l < LAYERS; l++) {
            k_aggregate<<<NN/4, 256, 0, stream>>>(xh, rowptr, col, Weps + l,
                                                  big, stats, pooled);
            k_gin<<<NN/128, 256, 0, stream>>>(big,
                                              w1h + l*4096, w1l + l*4096, Wgb1 + l*64,
                                              w2h + l*4096, w2l + l*4096, Wgb2 + l*64,
                                              stats);
            k_bnfin<<<1, 64, 0, stream>>>(stats, Wgam + l*64, Wbet + l*64, bnp);
            k_bn_inner<<<NN/128, 256, 0, stream>>>(big, bnp,
                                                   wih + l*4096, wil + l*4096,
                                                   Wib + l*64, xh, gi, pooled);
            k_outer<<<BG*64/256, 256, 0, stream>>>(pooled, Wow + l*4096, Wob + l*64,
                                                   feats, l*64);
        }
    }

    k_tail<<<BG/TG, 256, 0, stream>>>(qf, cf, Wcw1, Wcb1, Wcw2, Wcb2,
                                      Wsw1, Wsb1, Wsw2, Wsb2,
                                      Wnw, Wnwb, Wnb, Wmw1, Wmb1, Wmw2, Wmb2,
                                      Wal, Wbe, (float*)d_out);
}

// Round 6
// 1125.672 us; speedup vs baseline: 2.2246x; 1.1238x over previous
//
#include <hip/hip_runtime.h>
#include <hip/hip_bf16.h>

typedef __hip_bfloat16 bf16;
typedef __attribute__((ext_vector_type(8))) short short8;
typedef __attribute__((ext_vector_type(4))) float floatx4;

#define NN     131072
#define NEDGE  1048576
#define BG     1024
#define LAYERS 3
#define TG     8      // graphs per tail block

// bf16 split helpers (RNE)
__device__ __forceinline__ short f2bf_s(float f){
    union { float f; unsigned u; } x; x.f = f;
    unsigned r = x.u + 0x7fffu + ((x.u >> 16) & 1u);
    return (short)(r >> 16);
}
__device__ __forceinline__ float bf2f_s(short s){
    union { unsigned u; float f; } x; x.u = ((unsigned)(unsigned short)s) << 16;
    return x.f;
}
__device__ __forceinline__ void acc4(const unsigned short* p,
                                     float& a0, float& a1, float& a2, float& a3){
    ushort4 u = *(const ushort4*)p;
    a0 += bf2f_s((short)u.x); a1 += bf2f_s((short)u.y);
    a2 += bf2f_s((short)u.z); a3 += bf2f_s((short)u.w);
}

// ------------------------------------------------------------------
// Segment offsets: off[g] = lower_bound(graph_idx, g)
// ------------------------------------------------------------------
__global__ __launch_bounds__(256) void k_offsets(const int* __restrict__ gi,
                                                 int* __restrict__ off)
{
    int g = blockIdx.x*256 + threadIdx.x;
    if (g > BG) return;
    int lo = 0, hi = NN;
    while (lo < hi) { int mid = (lo + hi) >> 1; if (gi[mid] < g) lo = mid + 1; else hi = mid; }
    off[g] = lo;
}

// ------------------------------------------------------------------
// CSR build
// ------------------------------------------------------------------
__global__ __launch_bounds__(256) void k_zero(int* __restrict__ cnt)
{
    int i = blockIdx.x*256 + threadIdx.x;
    if (i < NN) cnt[i] = 0;
}

__global__ __launch_bounds__(256) void k_hist(const int* __restrict__ ei,
                                              int* __restrict__ cnt)
{
    int e = blockIdx.x*256 + threadIdx.x;
    atomicAdd(cnt + ei[NEDGE + e], 1);
}

__global__ __launch_bounds__(256) void k_scan1(const int* __restrict__ cnt,
    int* __restrict__ rowptr, int* __restrict__ bsum)
{
    __shared__ int sd[256];
    int t = threadIdx.x;
    int base = blockIdx.x*1024 + t*4;
    int c0 = cnt[base], c1 = cnt[base+1], c2 = cnt[base+2], c3 = cnt[base+3];
    int tsum = c0 + c1 + c2 + c3;
    sd[t] = tsum;
    __syncthreads();
    for (int off = 1; off < 256; off <<= 1) {
        int v = (t >= off) ? sd[t-off] : 0;
        __syncthreads();
        sd[t] += v;
        __syncthreads();
    }
    int excl = sd[t] - tsum;
    rowptr[base]   = excl;
    rowptr[base+1] = excl + c0;
    rowptr[base+2] = excl + c0 + c1;
    rowptr[base+3] = excl + c0 + c1 + c2;
    if (t == 255) bsum[blockIdx.x] = sd[255];
}

__global__ __launch_bounds__(128) void k_scan2(const int* __restrict__ bsum,
    int* __restrict__ boff, int* __restrict__ rowptr)
{
    __shared__ int sd[128];
    int t = threadIdx.x;
    int v0 = bsum[t];
    sd[t] = v0;
    __syncthreads();
    for (int off = 1; off < 128; off <<= 1) {
        int v = (t >= off) ? sd[t-off] : 0;
        __syncthreads();
        sd[t] += v;
        __syncthreads();
    }
    boff[t] = sd[t] - v0;
    if (t == 0) rowptr[NN] = NEDGE;
}

__global__ __launch_bounds__(256) void k_scan3(int* __restrict__ rowptr,
    const int* __restrict__ boff, int* __restrict__ wptr)
{
    int i = blockIdx.x*256 + threadIdx.x;
    int v = rowptr[i] + boff[i >> 10];
    rowptr[i] = v;
    wptr[i] = v;
}

__global__ __launch_bounds__(256) void k_fill(const int* __restrict__ ei,
    int* __restrict__ wptr, int* __restrict__ col)
{
    int e = blockIdx.x*256 + threadIdx.x;
    int s = ei[e];
    int d = ei[NEDGE + e];
    int pos = atomicAdd(wptr + d, 1);
    col[pos] = s;
}

// ------------------------------------------------------------------
// fp32 -> bf16 shadow copy of node features; zero stats for layer 0
// ------------------------------------------------------------------
__global__ __launch_bounds__(256) void k_cvt(const float* __restrict__ x,
                                             bf16* __restrict__ xh,
                                             float* __restrict__ stats)
{
    int i = blockIdx.x*256 + threadIdx.x;
    xh[i] = __float2bfloat16(x[i]);
    if (blockIdx.x == 0 && threadIdx.x < 128) stats[threadIdx.x] = 0.f;
}

// ------------------------------------------------------------------
// Weight prep (once/launch): Wt[n][k] = W[k][n], split bf16 hi/lo.
// ------------------------------------------------------------------
__global__ __launch_bounds__(256) void k_wprep(
    const float* __restrict__ gw1, const float* __restrict__ gw2,
    const float* __restrict__ iw,
    short* __restrict__ w1h, short* __restrict__ w1l,
    short* __restrict__ w2h, short* __restrict__ w2l,
    short* __restrict__ wih, short* __restrict__ wil)
{
    int i = blockIdx.x*256 + threadIdx.x;
    if (i >= 3*LAYERS*4096) return;
    int msel = i / (LAYERS*4096);
    int rem  = i % (LAYERS*4096);
    int l = rem >> 12, idx = rem & 4095;
    int n = idx >> 6, k = idx & 63;
    const float* src = (msel==0) ? gw1 : (msel==1) ? gw2 : iw;
    float v = src[l*4096 + k*64 + n];
    short hi = f2bf_s(v);
    short lo = f2bf_s(v - bf2f_s(hi));
    short* dh = (msel==0) ? w1h : (msel==1) ? w2h : wih;
    short* dl = (msel==0) ? w1l : (msel==1) ? w2l : wil;
    dh[rem] = hi;
    dl[rem] = lo;
}

// ------------------------------------------------------------------
// FUSED aggregate + GIN MLP.
// Wave = 32 nodes. Phase 1: CSR gather from bf16 table, 4 edges per
// wave-instr (16 lanes x 8B each), 2 nodes interleaved; shfl_xor group
// reduce; split-bf16 into LDS tile. Phase 2: two split-bf16 MFMA GEMMs
// (hidden under gather latency), BN stats.
// MFMA 16x16x32 layouts: A[m=lane&15][k=q*8+j]; B[k][n=lane&15];
// D[row=q*4+r][col=lane&15]  (q = lane>>4).
// ------------------------------------------------------------------
__global__ __launch_bounds__(256) void k_agg_gin(
    const bf16* __restrict__ xh,
    const int* __restrict__ rowptr, const int* __restrict__ col,
    const float* __restrict__ epsp,
    const short* __restrict__ w1h, const short* __restrict__ w1l,
    const float* __restrict__ b1,
    const short* __restrict__ w2h, const short* __restrict__ w2l,
    const float* __restrict__ b2,
    float* __restrict__ big, float* __restrict__ stats)
{
    __shared__ __align__(16) char buf[4][9472];
    __shared__ float red[2][4][64];
    int tid = threadIdx.x, wv = tid >> 6, lane = tid & 63;
    int q = lane >> 4, m = lane & 15;
    int nb = blockIdx.x*128 + wv*32;
    short* Sh = (short*)buf[wv];
    short* Sl = Sh + 2304;      // 32*72
    float ep = 1.0f + *epsp;

    // ---- Phase 1: gather ----
    int gv = rowptr[nb + (lane < 33 ? lane : 32)];
    int j  = lane >> 4;          // edge slot 0..3
    int fo = (lane & 15) * 4;    // feature offset
    const unsigned short* xt = (const unsigned short*)xh;

    for (int rr = 0; rr < 32; rr += 2) {
        int s0 = __shfl(gv, rr, 64);
        int e0 = __shfl(gv, rr+1, 64);
        int e1 = __shfl(gv, rr+2, 64);
        float a0=0.f,a1=0.f,a2=0.f,a3=0.f;   // node rr
        float c0=0.f,c1=0.f,c2=0.f,c3=0.f;   // node rr+1
        int r0 = s0 + j, r1 = e0 + j;
        for (; r0 < e0 && r1 < e1; r0 += 4, r1 += 4) {
            int ca = col[r0], cb = col[r1];
            acc4(xt + (((size_t)ca) << 6) + fo, a0,a1,a2,a3);
            acc4(xt + (((size_t)cb) << 6) + fo, c0,c1,c2,c3);
        }
        for (; r0 < e0; r0 += 4) {
            int ca = col[r0];
            acc4(xt + (((size_t)ca) << 6) + fo, a0,a1,a2,a3);
        }
        for (; r1 < e1; r1 += 4) {
            int cb = col[r1];
            acc4(xt + (((size_t)cb) << 6) + fo, c0,c1,c2,c3);
        }
        // reduce across the 4 edge-slot groups (lanes differing in bits 4,5)
        a0 += __shfl_xor(a0,16,64); a0 += __shfl_xor(a0,32,64);
        a1 += __shfl_xor(a1,16,64); a1 += __shfl_xor(a1,32,64);
        a2 += __shfl_xor(a2,16,64); a2 += __shfl_xor(a2,32,64);
        a3 += __shfl_xor(a3,16,64); a3 += __shfl_xor(a3,32,64);
        c0 += __shfl_xor(c0,16,64); c0 += __shfl_xor(c0,32,64);
        c1 += __shfl_xor(c1,16,64); c1 += __shfl_xor(c1,32,64);
        c2 += __shfl_xor(c2,16,64); c2 += __shfl_xor(c2,32,64);
        c3 += __shfl_xor(c3,16,64); c3 += __shfl_xor(c3,32,64);
        // self term
        {
            ushort4 sa = *(const ushort4*)(xt + (((size_t)(nb+rr))   << 6) + fo);
            ushort4 sb = *(const ushort4*)(xt + (((size_t)(nb+rr+1)) << 6) + fo);
            a0 = fmaf(ep, bf2f_s((short)sa.x), a0);
            a1 = fmaf(ep, bf2f_s((short)sa.y), a1);
            a2 = fmaf(ep, bf2f_s((short)sa.z), a2);
            a3 = fmaf(ep, bf2f_s((short)sa.w), a3);
            c0 = fmaf(ep, bf2f_s((short)sb.x), c0);
            c1 = fmaf(ep, bf2f_s((short)sb.y), c1);
            c2 = fmaf(ep, bf2f_s((short)sb.z), c2);
            c3 = fmaf(ep, bf2f_s((short)sb.w), c3);
        }
        // split and store rows rr, rr+1 (lanes 0-15 hold feats lane*4..+3)
        short4 ha, la, hb, lb;
        ha.x = f2bf_s(a0); la.x = f2bf_s(a0 - bf2f_s(ha.x));
        ha.y = f2bf_s(a1); la.y = f2bf_s(a1 - bf2f_s(ha.y));
        ha.z = f2bf_s(a2); la.z = f2bf_s(a2 - bf2f_s(ha.z));
        ha.w = f2bf_s(a3); la.w = f2bf_s(a3 - bf2f_s(ha.w));
        hb.x = f2bf_s(c0); lb.x = f2bf_s(c0 - bf2f_s(hb.x));
        hb.y = f2bf_s(c1); lb.y = f2bf_s(c1 - bf2f_s(hb.y));
        hb.z = f2bf_s(c2); lb.z = f2bf_s(c2 - bf2f_s(hb.z));
        hb.w = f2bf_s(c3); lb.w = f2bf_s(c3 - bf2f_s(hb.w));
        if (lane < 16) {
            *(short4*)(Sh + rr*72 + fo)     = ha;
            *(short4*)(Sl + rr*72 + fo)     = la;
            *(short4*)(Sh + (rr+1)*72 + fo) = hb;
            *(short4*)(Sl + (rr+1)*72 + fo) = lb;
        }
    }
    __syncthreads();

    // ---- Phase 2: GEMM1 (A from LDS) ----
    short8 Ah[2][2], Al[2][2];
    #pragma unroll
    for (int mc=0; mc<2; mc++)
      #pragma unroll
      for (int kc=0; kc<2; kc++){
        Ah[mc][kc] = *(const short8*)(Sh + (mc*16+m)*72 + kc*32 + q*8);
        Al[mc][kc] = *(const short8*)(Sl + (mc*16+m)*72 + kc*32 + q*8);
      }
    floatx4 acc[2][4];
    #pragma unroll
    for (int mc=0;mc<2;mc++)
      #pragma unroll
      for (int nc=0;nc<4;nc++) acc[mc][nc] = (floatx4){0.f,0.f,0.f,0.f};
    #pragma unroll
    for (int nc=0;nc<4;nc++){
      #pragma unroll
      for (int kc=0;kc<2;kc++){
        short8 bh = *(const short8*)(w1h + (nc*16+m)*64 + kc*32 + q*8);
        short8 bl = *(const short8*)(w1l + (nc*16+m)*64 + kc*32 + q*8);
        #pragma unroll
        for (int mc=0;mc<2;mc++){
          acc[mc][nc] = __builtin_amdgcn_mfma_f32_16x16x32_bf16(Ah[mc][kc], bh, acc[mc][nc],0,0,0);
          acc[mc][nc] = __builtin_amdgcn_mfma_f32_16x16x32_bf16(Al[mc][kc], bh, acc[mc][nc],0,0,0);
          acc[mc][nc] = __builtin_amdgcn_mfma_f32_16x16x32_bf16(Ah[mc][kc], bl, acc[mc][nc],0,0,0);
        }
      }
    }

    // epilogue 1: bias + relu, split back into LDS
    #pragma unroll
    for (int nc=0;nc<4;nc++){
      float bia = b1[nc*16+m];
      #pragma unroll
      for (int mc=0;mc<2;mc++)
        #pragma unroll
        for (int r=0;r<4;r++){
          float v = fmaxf(acc[mc][nc][r] + bia, 0.f);
          int row = mc*16 + q*4 + r, cl = nc*16 + m;
          short hb = f2bf_s(v);
          Sh[row*72+cl] = hb;
          Sl[row*72+cl] = f2bf_s(v - bf2f_s(hb));
        }
    }
    __syncthreads();

    // GEMM2
    short8 A2h[2][2], A2l[2][2];
    #pragma unroll
    for (int mc=0; mc<2; mc++)
      #pragma unroll
      for (int kc=0; kc<2; kc++){
        A2h[mc][kc] = *(const short8*)(Sh + (mc*16+m)*72 + kc*32 + q*8);
        A2l[mc][kc] = *(const short8*)(Sl + (mc*16+m)*72 + kc*32 + q*8);
      }
    floatx4 acc2[2][4];
    #pragma unroll
    for (int mc=0;mc<2;mc++)
      #pragma unroll
      for (int nc=0;nc<4;nc++) acc2[mc][nc] = (floatx4){0.f,0.f,0.f,0.f};
    #pragma unroll
    for (int nc=0;nc<4;nc++){
      #pragma unroll
      for (int kc=0;kc<2;kc++){
        short8 bh = *(const short8*)(w2h + (nc*16+m)*64 + kc*32 + q*8);
        short8 bl = *(const short8*)(w2l + (nc*16+m)*64 + kc*32 + q*8);
        #pragma unroll
        for (int mc=0;mc<2;mc++){
          acc2[mc][nc] = __builtin_amdgcn_mfma_f32_16x16x32_bf16(A2h[mc][kc], bh, acc2[mc][nc],0,0,0);
          acc2[mc][nc] = __builtin_amdgcn_mfma_f32_16x16x32_bf16(A2l[mc][kc], bh, acc2[mc][nc],0,0,0);
          acc2[mc][nc] = __builtin_amdgcn_mfma_f32_16x16x32_bf16(A2h[mc][kc], bl, acc2[mc][nc],0,0,0);
        }
      }
    }

    // epilogue 2: bias, store h2, BN stats
    #pragma unroll
    for (int nc=0;nc<4;nc++){
      float bia = b2[nc*16+m];
      float s = 0.f, s2 = 0.f;
      #pragma unroll
      for (int mc=0;mc<2;mc++)
        #pragma unroll
        for (int r=0;r<4;r++){
          float v = acc2[mc][nc][r] + bia;
          big[(((size_t)(nb + mc*16 + q*4 + r)) << 6) + nc*16 + m] = v;
          s += v; s2 = fmaf(v, v, s2);
        }
      s  += __shfl_xor(s, 16, 64);  s  += __shfl_xor(s, 32, 64);
      s2 += __shfl_xor(s2,16, 64);  s2 += __shfl_xor(s2,32, 64);
      if (q == 0){ red[0][wv][nc*16+m] = s; red[1][wv][nc*16+m] = s2; }
    }
    __syncthreads();
    if (tid < 128){
      int which = tid >> 6, c = tid & 63;
      float a = red[which][0][c]+red[which][1][c]+red[which][2][c]+red[which][3][c];
      unsafeAtomicAdd(stats + which*64 + c, a);
    }
}

// ------------------------------------------------------------------
// BN finalize (block 0) + zero stats for next layer + zero pooled
// ------------------------------------------------------------------
__global__ __launch_bounds__(64) void k_bnfin(float* __restrict__ stats,
                        const float* __restrict__ gamma,
                        const float* __restrict__ beta,
                        float* __restrict__ bnp,
                        float* __restrict__ pooled)
{
    if (blockIdx.x == 0) {
        int c = threadIdx.x;  // 64
        float mu  = stats[c]     * (1.0f/NN);
        float ex2 = stats[64+c]  * (1.0f/NN);
        float var = ex2 - mu*mu;
        float sc  = gamma[c] * rsqrtf(var + 1e-5f);
        bnp[c]     = sc;
        bnp[64+c]  = beta[c] - mu*sc;
        stats[c] = 0.f; stats[64+c] = 0.f;
    } else {
        int base = (blockIdx.x - 1)*256 + threadIdx.x;
        #pragma unroll
        for (int i = 0; i < 4; i++) pooled[base + i*64] = 0.f;
    }
}

// ------------------------------------------------------------------
// MFMA BN-apply + inner MLP + fused segment-pool.
// ------------------------------------------------------------------
__global__ __launch_bounds__(256) void k_bn_inner(
    const float* __restrict__ big, const float* __restrict__ bnp,
    const short* __restrict__ wih, const short* __restrict__ wil,
    const float* __restrict__ bi,
    bf16* __restrict__ xh,
    const int* __restrict__ gidx, float* __restrict__ pooled)
{
    __shared__ __align__(16) char buf[4][9472];
    int tid = threadIdx.x, wv = tid >> 6, lane = tid & 63;
    int q = lane >> 4, m = lane & 15;
    int nb = blockIdx.x*128 + wv*32;
    short* Sh = (short*)buf[wv];
    short* Sl = Sh + 2304;

    float sc = bnp[lane], sh = bnp[64 + lane];
    for (int rr = 0; rr < 32; rr++){
        float v = big[(((size_t)(nb+rr)) << 6) + lane];
        v = fmaxf(fmaf(v, sc, sh), 0.f);
        xh[(((size_t)(nb+rr)) << 6) + lane] = __float2bfloat16(v);
        short hb = f2bf_s(v);
        Sh[rr*72 + lane] = hb;
        Sl[rr*72 + lane] = f2bf_s(v - bf2f_s(hb));
    }
    __syncthreads();

    short8 A2h[2][2], A2l[2][2];
    #pragma unroll
    for (int mc=0; mc<2; mc++)
      #pragma unroll
      for (int kc=0; kc<2; kc++){
        A2h[mc][kc] = *(const short8*)(Sh + (mc*16+m)*72 + kc*32 + q*8);
        A2l[mc][kc] = *(const short8*)(Sl + (mc*16+m)*72 + kc*32 + q*8);
      }
    floatx4 acc[2][4];
    #pragma unroll
    for (int mc=0;mc<2;mc++)
      #pragma unroll
      for (int nc=0;nc<4;nc++) acc[mc][nc] = (floatx4){0.f,0.f,0.f,0.f};
    #pragma unroll
    for (int nc=0;nc<4;nc++){
      #pragma unroll
      for (int kc=0;kc<2;kc++){
        short8 bh = *(const short8*)(wih + (nc*16+m)*64 + kc*32 + q*8);
        short8 bl = *(const short8*)(wil + (nc*16+m)*64 + kc*32 + q*8);
        #pragma unroll
        for (int mc=0;mc<2;mc++){
          acc[mc][nc] = __builtin_amdgcn_mfma_f32_16x16x32_bf16(A2h[mc][kc], bh, acc[mc][nc],0,0,0);
          acc[mc][nc] = __builtin_amdgcn_mfma_f32_16x16x32_bf16(A2l[mc][kc], bh, acc[mc][nc],0,0,0);
          acc[mc][nc] = __builtin_amdgcn_mfma_f32_16x16x32_bf16(A2h[mc][kc], bl, acc[mc][nc],0,0,0);
        }
      }
    }
    __syncthreads();   // LDS reads done; safe to repurpose buf

    float* P = (float*)buf[wv];
    #pragma unroll
    for (int nc=0;nc<4;nc++){
      float bia = bi[nc*16+m];
      #pragma unroll
      for (int mc=0;mc<2;mc++)
        #pragma unroll
        for (int r=0;r<4;r++){
          float v = fmaxf(acc[mc][nc][r] + bia, 0.f);
          P[(mc*16 + q*4 + r)*66 + nc*16 + m] = v;
        }
    }
    __syncthreads();

    int gv = (lane < 32) ? gidx[nb + lane] : 0;
    int cur = __shfl(gv, 0, 64);
    float a = 0.f;
    for (int rr = 0; rr < 32; rr++){
        int g = __shfl(gv, rr, 64);
        if (g != cur){
            unsafeAtomicAdd(pooled + (size_t)cur*64 + lane, a);
            a = 0.f; cur = g;
        }
        a += P[rr*66 + lane];
    }
    unsafeAtomicAdd(pooled + (size_t)cur*64 + lane, a);
}

// ------------------------------------------------------------------
// Outer MLP: feats[:, coff:coff+64] = relu(pooled @ w + b)
// ------------------------------------------------------------------
__global__ __launch_bounds__(256) void k_outer(const float* __restrict__ pooled,
    const float* __restrict__ w, const float* __restrict__ b,
    float* __restrict__ feats, int coff)
{
    int g = blockIdx.x*256 + threadIdx.x;  // BG*64
    int bb = g >> 6, j = g & 63;
    const float* pr = pooled + bb*64;
    float a = b[j];
    for (int k = 0; k < 64; k++) a = fmaf(pr[k], w[k*64 + j], a);
    feats[bb*192 + coff + j] = fmaxf(a, 0.f);
}

// ------------------------------------------------------------------
// Tail: TG graphs per block, weights LDS-staged, NTN register-blocked
// ------------------------------------------------------------------
__global__ __launch_bounds__(256) void k_tail(
    const float* __restrict__ qf, const float* __restrict__ cf,
    const float* __restrict__ cw1, const float* __restrict__ cb1,
    const float* __restrict__ cw2, const float* __restrict__ cb2,
    const float* __restrict__ sw1, const float* __restrict__ sb1,
    const float* __restrict__ sw2, const float* __restrict__ sb2,
    const float* __restrict__ nw,  const float* __restrict__ nwb,
    const float* __restrict__ nb,
    const float* __restrict__ mw1, const float* __restrict__ mb1,
    const float* __restrict__ mw2, const float* __restrict__ mb2,
    const float* __restrict__ alpha, const float* __restrict__ beta,
    float* __restrict__ out)
{
    __shared__ float cws[192*96];
    __shared__ float diff[TG][192];
    __shared__ float e1s[TG][64], e2s[TG][64];
    __shared__ float h1s[TG][96], h2s[TG][96];
    __shared__ float s1s[TG][16], s2s[TG][16], srep[TG][16];
    __shared__ float red[16][16][TG];

    int t = threadIdx.x;
    int b0 = blockIdx.x * TG;

    for (int i = t; i < 192*96; i += 256) cws[i] = cw1[i];
    for (int i = t; i < TG*192; i += 256) {
        int b = i / 192, f = i % 192;
        float qv = qf[(b0+b)*192 + f], cv = cf[(b0+b)*192 + f];
        float d = qv - cv;
        diff[b][f] = __expf(-d*d);
        if (f >= 128) { e1s[b][f-128] = qv; e2s[b][f-128] = cv; }
    }
    __syncthreads();

    {
        int b = t >> 5, o = (t & 31) * 3;
        float a0 = cb1[o], a1 = cb1[o+1], a2 = cb1[o+2];
        for (int f = 0; f < 192; f++) {
            float d = diff[b][f];
            const float* w = cws + f*96 + o;
            a0 = fmaf(d, w[0], a0);
            a1 = fmaf(d, w[1], a1);
            a2 = fmaf(d, w[2], a2);
        }
        h1s[b][o] = fmaxf(a0, 0.f);
        h1s[b][o+1] = fmaxf(a1, 0.f);
        h1s[b][o+2] = fmaxf(a2, 0.f);
    }
    __syncthreads();
    for (int i = t; i < 96*96; i += 256) cws[i] = cw2[i];
    __syncthreads();
    {
        int b = t >> 5, o = (t & 31) * 3;
        float a0 = cb2[o], a1 = cb2[o+1], a2 = cb2[o+2];
        for (int f = 0; f < 96; f++) {
            float d = h1s[b][f];
            const float* w = cws + f*96 + o;
            a0 = fmaf(d, w[0], a0);
            a1 = fmaf(d, w[1], a1);
            a2 = fmaf(d, w[2], a2);
        }
        h2s[b][o] = tanhf(a0);
        h2s[b][o+1] = tanhf(a1);
        h2s[b][o+2] = tanhf(a2);
    }
    __syncthreads();
    if (t < TG*16) {
        int b = t >> 4, o = t & 15;
        float a = sb1[o];
        for (int f = 0; f < 96; f++) a = fmaf(h2s[b][f], sw1[f*16+o], a);
        s1s[b][o] = fmaxf(a, 0.f);
    }

    {
        int tt = t & 15, gq = t >> 4;
        int g0 = gq * 4;
        int lane = t & 63;
        float e1v[TG];
        #pragma unroll
        for (int b = 0; b < TG; b++) e1v[b] = e1s[b][lane];
        float v0[TG], v1[TG], v2[TG], v3[TG];
        #pragma unroll
        for (int b = 0; b < TG; b++) { v0[b]=0.f; v1[b]=0.f; v2[b]=0.f; v3[b]=0.f; }
        for (int f = 0; f < 64; f++) {
            const float* wp = nw + ((size_t)f*64 + g0)*16 + tt;
            float w0 = wp[0], w1 = wp[16], w2 = wp[32], w3 = wp[48];
            #pragma unroll
            for (int b = 0; b < TG; b++) {
                float e = __shfl(e1v[b], f, 64);
                v0[b] = fmaf(e, w0, v0[b]);
                v1[b] = fmaf(e, w1, v1[b]);
                v2[b] = fmaf(e, w2, v2[b]);
                v3[b] = fmaf(e, w3, v3[b]);
            }
        }
        #pragma unroll
        for (int b = 0; b < TG; b++) {
            float p = v0[b]*e2s[b][g0] + v1[b]*e2s[b][g0+1]
                    + v2[b]*e2s[b][g0+2] + v3[b]*e2s[b][g0+3];
            red[gq][tt][b] = p;
        }
    }
    __syncthreads();
    if (t < TG*16) {
        int b = t >> 4, tt = t & 15;
        float scv = 0.f;
        #pragma unroll
        for (int gq = 0; gq < 16; gq++) scv += red[gq][tt][b];
        float blk = nb[tt];
        for (int f = 0; f < 64; f++) blk = fmaf(e1s[b][f], nwb[tt*128 + f], blk);
        for (int f = 0; f < 64; f++) blk = fmaf(e2s[b][f], nwb[tt*128 + 64 + f], blk);
        srep[b][tt] = fmaxf(scv + blk, 0.f);
    }
    __syncthreads();
    if (t < TG*16) {
        int b = t >> 4, o = t & 15;
        float a = mb1[o];
        #pragma unroll
        for (int f = 0; f < 16; f++) a = fmaf(srep[b][f], mw1[f*16+o], a);
        s2s[b][o] = fmaxf(a, 0.f);
    }
    __syncthreads();
    if (t < TG) {
        float sco = sb2[0], sm = mb2[0];
        #pragma unroll
        for (int f = 0; f < 16; f++) {
            sco = fmaf(s1s[t][f], sw2[f], sco);
            sm  = fmaf(s2s[t][f], mw2[f], sm);
        }
        float score = 1.f / (1.f + __expf(-sco));
        float sim   = 1.f / (1.f + __expf(-sm));
        out[b0 + t] = alpha[0]*score + beta[0]*sim;
    }
}

// ------------------------------------------------------------------
extern "C" void kernel_launch(void* const* d_in, const int* in_sizes, int n_in,
                              void* d_out, int out_size, void* d_ws, size_t ws_size,
                              hipStream_t stream)
{
    const float* qx  = (const float*)d_in[0];
    const float* cx  = (const float*)d_in[1];
    const int*   qei = (const int*)d_in[2];
    const int*   cei = (const int*)d_in[3];
    const int*   qgi = (const int*)d_in[4];
    const int*   cgi = (const int*)d_in[5];
    const float* Wgw1 = (const float*)d_in[6];
    const float* Wgb1 = (const float*)d_in[7];
    const float* Wgw2 = (const float*)d_in[8];
    const float* Wgb2 = (const float*)d_in[9];
    const float* Wgam = (const float*)d_in[10];
    const float* Wbet = (const float*)d_in[11];
    const float* Weps = (const float*)d_in[12];
    const float* Wiw  = (const float*)d_in[13];
    const float* Wib  = (const float*)d_in[14];
    const float* Wow  = (const float*)d_in[15];
    const float* Wob  = (const float*)d_in[16];
    const float* Wcw1 = (const float*)d_in[17];
    const float* Wcb1 = (const float*)d_in[18];
    const float* Wcw2 = (const float*)d_in[19];
    const float* Wcb2 = (const float*)d_in[20];
    const float* Wsw1 = (const float*)d_in[21];
    const float* Wsb1 = (const float*)d_in[22];
    const float* Wsw2 = (const float*)d_in[23];
    const float* Wsb2 = (const float*)d_in[24];
    const float* Wnw  = (const float*)d_in[25];
    const float* Wnwb = (const float*)d_in[26];
    const float* Wnb  = (const float*)d_in[27];
    const float* Wmw1 = (const float*)d_in[28];
    const float* Wmb1 = (const float*)d_in[29];
    const float* Wmw2 = (const float*)d_in[30];
    const float* Wmb2 = (const float*)d_in[31];
    const float* Wal  = (const float*)d_in[32];
    const float* Wbe  = (const float*)d_in[33];

    float* F      = (float*)d_ws;
    float* big    = F;                       // N*64
    float* stats  = F + 8388608;             // 128
    float* bnp    = stats + 128;             // 128
    float* pooled = bnp + 128;               // BG*64
    float* qf     = pooled + 65536;          // BG*192
    float* cf     = qf + 196608;             // BG*192
    int*   qoff   = (int*)(cf + 196608);     // BG+1
    int*   coff   = qoff + (BG + 1);         // BG+1
    int*   rowptr = coff + (BG + 1);         // NN+1
    int*   wptr   = rowptr + (NN + 1);       // NN (histogram alias)
    int*   col    = wptr + NN;               // NEDGE
    int*   bsum   = col + NEDGE;             // 128
    int*   boff   = bsum + 128;              // 128
    bf16*  xh     = (bf16*)(boff + 128);     // N*64 bf16
    uintptr_t wtb = (uintptr_t)(xh + (size_t)NN*64);
    wtb = (wtb + 63) & ~((uintptr_t)63);
    short* w1h = (short*)wtb;                // 3*4096 each
    short* w1l = w1h + 3*4096;
    short* w2h = w1l + 3*4096;
    short* w2l = w2h + 3*4096;
    short* wih = w2l + 3*4096;
    short* wil = wih + 3*4096;

    k_wprep<<<144, 256, 0, stream>>>(Wgw1, Wgw2, Wiw, w1h, w1l, w2h, w2l, wih, wil);

    for (int side = 0; side < 2; side++) {
        const float* x0 = side ? cx  : qx;
        const int* ei   = side ? cei : qei;
        const int* gi   = side ? cgi : qgi;
        int* off        = side ? coff : qoff;
        float* feats    = side ? cf  : qf;

        k_offsets<<<5, 256, 0, stream>>>(gi, off);

        k_zero<<<NN/256, 256, 0, stream>>>(wptr);
        k_hist<<<NEDGE/256, 256, 0, stream>>>(ei, wptr);
        k_scan1<<<128, 256, 0, stream>>>(wptr, rowptr, bsum);
        k_scan2<<<1, 128, 0, stream>>>(bsum, boff, rowptr);
        k_scan3<<<NN/256, 256, 0, stream>>>(rowptr, boff, wptr);
        k_fill<<<NEDGE/256, 256, 0, stream>>>(ei, wptr, col);

        k_cvt<<<NN*64/256, 256, 0, stream>>>(x0, xh, stats);

        for (int l = 0; l < LAYERS; l++) {
            k_agg_gin<<<NN/128, 256, 0, stream>>>(xh, rowptr, col, Weps + l,
                                                  w1h + l*4096, w1l + l*4096, Wgb1 + l*64,
                                                  w2h + l*4096, w2l + l*4096, Wgb2 + l*64,
                                                  big, stats);
            k_bnfin<<<257, 64, 0, stream>>>(stats, Wgam + l*64, Wbet + l*64, bnp, pooled);
            k_bn_inner<<<NN/128, 256, 0, stream>>>(big, bnp,
                                                   wih + l*4096, wil + l*4096,
                                                   Wib + l*64, xh, gi, pooled);
            k_outer<<<BG*64/256, 256, 0, stream>>>(pooled, Wow + l*4096, Wob + l*64,
                                                   feats, l*64);
        }
    }

    k_tail<<<BG/TG, 256, 0, stream>>>(qf, cf, Wcw1, Wcb1, Wcw2, Wcb2,
                                      Wsw1, Wsb1, Wsw2, Wsb2,
                                      Wnw, Wnwb, Wnb, Wmw1, Wmb1, Wmw2, Wmb2,
                                      Wal, Wbe, (float*)d_out);
}

// Round 7
// 1068.364 us; speedup vs baseline: 2.3439x; 1.0536x over previous
//
#include <hip/hip_runtime.h>
#include <hip/hip_bf16.h>

typedef __hip_bfloat16 bf16;
typedef __attribute__((ext_vector_type(8))) short short8;
typedef __attribute__((ext_vector_type(4))) float floatx4;

#define NN     131072
#define NEDGE  1048576
#define BG     1024
#define LAYERS 3
#define TG     8      // graphs per tail block

// bf16 split helpers (RNE)
__device__ __forceinline__ short f2bf_s(float f){
    union { float f; unsigned u; } x; x.f = f;
    unsigned r = x.u + 0x7fffu + ((x.u >> 16) & 1u);
    return (short)(r >> 16);
}
__device__ __forceinline__ float bf2f_s(short s){
    union { unsigned u; float f; } x; x.u = ((unsigned)(unsigned short)s) << 16;
    return x.f;
}
__device__ __forceinline__ void acc4(const unsigned short* p,
                                     float& a0, float& a1, float& a2, float& a3){
    ushort4 u = *(const ushort4*)p;
    a0 += bf2f_s((short)u.x); a1 += bf2f_s((short)u.y);
    a2 += bf2f_s((short)u.z); a3 += bf2f_s((short)u.w);
}

// ------------------------------------------------------------------
// Segment offsets: off[g] = lower_bound(graph_idx, g)
// ------------------------------------------------------------------
__global__ __launch_bounds__(256) void k_offsets(const int* __restrict__ gi,
                                                 int* __restrict__ off)
{
    int g = blockIdx.x*256 + threadIdx.x;
    if (g > BG) return;
    int lo = 0, hi = NN;
    while (lo < hi) { int mid = (lo + hi) >> 1; if (gi[mid] < g) lo = mid + 1; else hi = mid; }
    off[g] = lo;
}

// ------------------------------------------------------------------
// CSR build (deterministic fill via rank captured in k_hist)
// ------------------------------------------------------------------
__global__ __launch_bounds__(256) void k_zero(int* __restrict__ cnt)
{
    int i = blockIdx.x*256 + threadIdx.x;
    if (i < NN) cnt[i] = 0;
}

__global__ __launch_bounds__(256) void k_hist(const int* __restrict__ ei,
                                              int* __restrict__ cnt,
                                              int* __restrict__ rank)
{
    int e = blockIdx.x*256 + threadIdx.x;
    rank[e] = atomicAdd(cnt + ei[NEDGE + e], 1);
}

__global__ __launch_bounds__(256) void k_scan1(const int* __restrict__ cnt,
    int* __restrict__ rowptr, int* __restrict__ bsum)
{
    __shared__ int sd[256];
    int t = threadIdx.x;
    int base = blockIdx.x*1024 + t*4;
    int c0 = cnt[base], c1 = cnt[base+1], c2 = cnt[base+2], c3 = cnt[base+3];
    int tsum = c0 + c1 + c2 + c3;
    sd[t] = tsum;
    __syncthreads();
    for (int off = 1; off < 256; off <<= 1) {
        int v = (t >= off) ? sd[t-off] : 0;
        __syncthreads();
        sd[t] += v;
        __syncthreads();
    }
    int excl = sd[t] - tsum;
    rowptr[base]   = excl;
    rowptr[base+1] = excl + c0;
    rowptr[base+2] = excl + c0 + c1;
    rowptr[base+3] = excl + c0 + c1 + c2;
    if (t == 255) bsum[blockIdx.x] = sd[255];
}

__global__ __launch_bounds__(128) void k_scan2(const int* __restrict__ bsum,
    int* __restrict__ boff, int* __restrict__ rowptr)
{
    __shared__ int sd[128];
    int t = threadIdx.x;
    int v0 = bsum[t];
    sd[t] = v0;
    __syncthreads();
    for (int off = 1; off < 128; off <<= 1) {
        int v = (t >= off) ? sd[t-off] : 0;
        __syncthreads();
        sd[t] += v;
        __syncthreads();
    }
    boff[t] = sd[t] - v0;
    if (t == 0) rowptr[NN] = NEDGE;
}

__global__ __launch_bounds__(256) void k_scan3(int* __restrict__ rowptr,
    const int* __restrict__ boff)
{
    int i = blockIdx.x*256 + threadIdx.x;
    rowptr[i] += boff[i >> 10];
}

__global__ __launch_bounds__(256) void k_fill(const int* __restrict__ ei,
    const int* __restrict__ rowptr, const int* __restrict__ rank,
    int* __restrict__ col)
{
    int e = blockIdx.x*256 + threadIdx.x;
    int s = ei[e];
    int d = ei[NEDGE + e];
    col[rowptr[d] + rank[e]] = s;
}

// ------------------------------------------------------------------
// fp32 -> bf16 shadow copy of node features; zero stats for layer 0
// ------------------------------------------------------------------
__global__ __launch_bounds__(256) void k_cvt(const float* __restrict__ x,
                                             bf16* __restrict__ xh,
                                             float* __restrict__ stats)
{
    int i = blockIdx.x*256 + threadIdx.x;
    xh[i] = __float2bfloat16(x[i]);
    if (blockIdx.x == 0 && threadIdx.x < 128) stats[threadIdx.x] = 0.f;
}

// ------------------------------------------------------------------
// Weight prep (once/launch): Wt[n][k] = W[k][n], split bf16 hi/lo.
// ------------------------------------------------------------------
__global__ __launch_bounds__(256) void k_wprep(
    const float* __restrict__ gw1, const float* __restrict__ gw2,
    const float* __restrict__ iw,
    short* __restrict__ w1h, short* __restrict__ w1l,
    short* __restrict__ w2h, short* __restrict__ w2l,
    short* __restrict__ wih, short* __restrict__ wil)
{
    int i = blockIdx.x*256 + threadIdx.x;
    if (i >= 3*LAYERS*4096) return;
    int msel = i / (LAYERS*4096);
    int rem  = i % (LAYERS*4096);
    int l = rem >> 12, idx = rem & 4095;
    int n = idx >> 6, k = idx & 63;
    const float* src = (msel==0) ? gw1 : (msel==1) ? gw2 : iw;
    float v = src[l*4096 + k*64 + n];
    short hi = f2bf_s(v);
    short lo = f2bf_s(v - bf2f_s(hi));
    short* dh = (msel==0) ? w1h : (msel==1) ? w2h : wih;
    short* dl = (msel==0) ? w1l : (msel==1) ? w2l : wil;
    dh[rem] = hi;
    dl[rem] = lo;
}

// ------------------------------------------------------------------
// FUSED aggregate + GIN MLP.
// Wave = 32 nodes. Phase 1: CSR gather, 4 edge slots x 16 lanes x 8B,
// 2 nodes interleaved + unroll-by-2 = 4 independent gathers in flight;
// shfl_xor slot reduce; split-bf16 into LDS tile. Phase 2: two
// split-bf16 MFMA GEMMs, BN stats.
// ------------------------------------------------------------------
__global__ __launch_bounds__(256) void k_agg_gin(
    const bf16* __restrict__ xh,
    const int* __restrict__ rowptr, const int* __restrict__ col,
    const float* __restrict__ epsp,
    const short* __restrict__ w1h, const short* __restrict__ w1l,
    const float* __restrict__ b1,
    const short* __restrict__ w2h, const short* __restrict__ w2l,
    const float* __restrict__ b2,
    float* __restrict__ big, float* __restrict__ stats)
{
    __shared__ __align__(16) char buf[4][9472];
    __shared__ float red[2][4][64];
    int tid = threadIdx.x, wv = tid >> 6, lane = tid & 63;
    int q = lane >> 4, m = lane & 15;
    int nb = blockIdx.x*128 + wv*32;
    short* Sh = (short*)buf[wv];
    short* Sl = Sh + 2304;      // 32*72
    float ep = 1.0f + *epsp;

    // ---- Phase 1: gather ----
    int gv = rowptr[nb + (lane < 33 ? lane : 32)];
    int j  = lane >> 4;          // edge slot 0..3
    int fo = (lane & 15) * 4;    // feature offset
    const unsigned short* xt = (const unsigned short*)xh;

    for (int rr = 0; rr < 32; rr += 2) {
        int s0 = __shfl(gv, rr, 64);
        int e0 = __shfl(gv, rr+1, 64);
        int e1 = __shfl(gv, rr+2, 64);
        float a0=0.f,a1=0.f,a2=0.f,a3=0.f;   // node rr   bank A
        float b0=0.f,b1=0.f,b2=0.f,b3=0.f;   // node rr   bank B
        float c0=0.f,c1=0.f,c2=0.f,c3=0.f;   // node rr+1 bank A
        float d0=0.f,d1=0.f,d2=0.f,d3=0.f;   // node rr+1 bank B
        int r0 = s0 + j, r1 = e0 + j;
        int nm = ((e0 - s0) < (e1 - e0) ? (e0 - s0) : (e1 - e0)) >> 3;
        for (int it = 0; it < nm; ++it) {
            int ca0 = col[r0], ca1 = col[r0+4];
            int cb0 = col[r1], cb1 = col[r1+4];
            r0 += 8; r1 += 8;
            acc4(xt + (((size_t)ca0) << 6) + fo, a0,a1,a2,a3);
            acc4(xt + (((size_t)ca1) << 6) + fo, b0,b1,b2,b3);
            acc4(xt + (((size_t)cb0) << 6) + fo, c0,c1,c2,c3);
            acc4(xt + (((size_t)cb1) << 6) + fo, d0,d1,d2,d3);
        }
        for (; r0 < e0; r0 += 4)
            acc4(xt + (((size_t)col[r0]) << 6) + fo, a0,a1,a2,a3);
        for (; r1 < e1; r1 += 4)
            acc4(xt + (((size_t)col[r1]) << 6) + fo, c0,c1,c2,c3);
        a0 += b0; a1 += b1; a2 += b2; a3 += b3;
        c0 += d0; c1 += d1; c2 += d2; c3 += d3;
        // reduce across the 4 edge-slot groups (lanes differing in bits 4,5)
        a0 += __shfl_xor(a0,16,64); a0 += __shfl_xor(a0,32,64);
        a1 += __shfl_xor(a1,16,64); a1 += __shfl_xor(a1,32,64);
        a2 += __shfl_xor(a2,16,64); a2 += __shfl_xor(a2,32,64);
        a3 += __shfl_xor(a3,16,64); a3 += __shfl_xor(a3,32,64);
        c0 += __shfl_xor(c0,16,64); c0 += __shfl_xor(c0,32,64);
        c1 += __shfl_xor(c1,16,64); c1 += __shfl_xor(c1,32,64);
        c2 += __shfl_xor(c2,16,64); c2 += __shfl_xor(c2,32,64);
        c3 += __shfl_xor(c3,16,64); c3 += __shfl_xor(c3,32,64);
        // self term
        {
            ushort4 sa = *(const ushort4*)(xt + (((size_t)(nb+rr))   << 6) + fo);
            ushort4 sb = *(const ushort4*)(xt + (((size_t)(nb+rr+1)) << 6) + fo);
            a0 = fmaf(ep, bf2f_s((short)sa.x), a0);
            a1 = fmaf(ep, bf2f_s((short)sa.y), a1);
            a2 = fmaf(ep, bf2f_s((short)sa.z), a2);
            a3 = fmaf(ep, bf2f_s((short)sa.w), a3);
            c0 = fmaf(ep, bf2f_s((short)sb.x), c0);
            c1 = fmaf(ep, bf2f_s((short)sb.y), c1);
            c2 = fmaf(ep, bf2f_s((short)sb.z), c2);
            c3 = fmaf(ep, bf2f_s((short)sb.w), c3);
        }
        // split and store rows rr, rr+1 (lanes 0-15 hold feats lane*4..+3)
        short4 ha, la, hb, lb;
        ha.x = f2bf_s(a0); la.x = f2bf_s(a0 - bf2f_s(ha.x));
        ha.y = f2bf_s(a1); la.y = f2bf_s(a1 - bf2f_s(ha.y));
        ha.z = f2bf_s(a2); la.z = f2bf_s(a2 - bf2f_s(ha.z));
        ha.w = f2bf_s(a3); la.w = f2bf_s(a3 - bf2f_s(ha.w));
        hb.x = f2bf_s(c0); lb.x = f2bf_s(c0 - bf2f_s(hb.x));
        hb.y = f2bf_s(c1); lb.y = f2bf_s(c1 - bf2f_s(hb.y));
        hb.z = f2bf_s(c2); lb.z = f2bf_s(c2 - bf2f_s(hb.z));
        hb.w = f2bf_s(c3); lb.w = f2bf_s(c3 - bf2f_s(hb.w));
        if (lane < 16) {
            *(short4*)(Sh + rr*72 + fo)     = ha;
            *(short4*)(Sl + rr*72 + fo)     = la;
            *(short4*)(Sh + (rr+1)*72 + fo) = hb;
            *(short4*)(Sl + (rr+1)*72 + fo) = lb;
        }
    }
    __syncthreads();

    // ---- Phase 2: GEMM1 (A from LDS) ----
    short8 Ah[2][2], Al[2][2];
    #pragma unroll
    for (int mc=0; mc<2; mc++)
      #pragma unroll
      for (int kc=0; kc<2; kc++){
        Ah[mc][kc] = *(const short8*)(Sh + (mc*16+m)*72 + kc*32 + q*8);
        Al[mc][kc] = *(const short8*)(Sl + (mc*16+m)*72 + kc*32 + q*8);
      }
    floatx4 acc[2][4];
    #pragma unroll
    for (int mc=0;mc<2;mc++)
      #pragma unroll
      for (int nc=0;nc<4;nc++) acc[mc][nc] = (floatx4){0.f,0.f,0.f,0.f};
    #pragma unroll
    for (int nc=0;nc<4;nc++){
      #pragma unroll
      for (int kc=0;kc<2;kc++){
        short8 bh = *(const short8*)(w1h + (nc*16+m)*64 + kc*32 + q*8);
        short8 bl = *(const short8*)(w1l + (nc*16+m)*64 + kc*32 + q*8);
        #pragma unroll
        for (int mc=0;mc<2;mc++){
          acc[mc][nc] = __builtin_amdgcn_mfma_f32_16x16x32_bf16(Ah[mc][kc], bh, acc[mc][nc],0,0,0);
          acc[mc][nc] = __builtin_amdgcn_mfma_f32_16x16x32_bf16(Al[mc][kc], bh, acc[mc][nc],0,0,0);
          acc[mc][nc] = __builtin_amdgcn_mfma_f32_16x16x32_bf16(Ah[mc][kc], bl, acc[mc][nc],0,0,0);
        }
      }
    }

    // epilogue 1: bias + relu, split back into LDS
    #pragma unroll
    for (int nc=0;nc<4;nc++){
      float bia = b1[nc*16+m];
      #pragma unroll
      for (int mc=0;mc<2;mc++)
        #pragma unroll
        for (int r=0;r<4;r++){
          float v = fmaxf(acc[mc][nc][r] + bia, 0.f);
          int row = mc*16 + q*4 + r, cl = nc*16 + m;
          short hb = f2bf_s(v);
          Sh[row*72+cl] = hb;
          Sl[row*72+cl] = f2bf_s(v - bf2f_s(hb));
        }
    }
    __syncthreads();

    // GEMM2
    short8 A2h[2][2], A2l[2][2];
    #pragma unroll
    for (int mc=0; mc<2; mc++)
      #pragma unroll
      for (int kc=0; kc<2; kc++){
        A2h[mc][kc] = *(const short8*)(Sh + (mc*16+m)*72 + kc*32 + q*8);
        A2l[mc][kc] = *(const short8*)(Sl + (mc*16+m)*72 + kc*32 + q*8);
      }
    floatx4 acc2[2][4];
    #pragma unroll
    for (int mc=0;mc<2;mc++)
      #pragma unroll
      for (int nc=0;nc<4;nc++) acc2[mc][nc] = (floatx4){0.f,0.f,0.f,0.f};
    #pragma unroll
    for (int nc=0;nc<4;nc++){
      #pragma unroll
      for (int kc=0;kc<2;kc++){
        short8 bh = *(const short8*)(w2h + (nc*16+m)*64 + kc*32 + q*8);
        short8 bl = *(const short8*)(w2l + (nc*16+m)*64 + kc*32 + q*8);
        #pragma unroll
        for (int mc=0;mc<2;mc++){
          acc2[mc][nc] = __builtin_amdgcn_mfma_f32_16x16x32_bf16(A2h[mc][kc], bh, acc2[mc][nc],0,0,0);
          acc2[mc][nc] = __builtin_amdgcn_mfma_f32_16x16x32_bf16(A2l[mc][kc], bh, acc2[mc][nc],0,0,0);
          acc2[mc][nc] = __builtin_amdgcn_mfma_f32_16x16x32_bf16(A2h[mc][kc], bl, acc2[mc][nc],0,0,0);
        }
      }
    }

    // epilogue 2: bias, store h2, BN stats
    #pragma unroll
    for (int nc=0;nc<4;nc++){
      float bia = b2[nc*16+m];
      float s = 0.f, s2 = 0.f;
      #pragma unroll
      for (int mc=0;mc<2;mc++)
        #pragma unroll
        for (int r=0;r<4;r++){
          float v = acc2[mc][nc][r] + bia;
          big[(((size_t)(nb + mc*16 + q*4 + r)) << 6) + nc*16 + m] = v;
          s += v; s2 = fmaf(v, v, s2);
        }
      s  += __shfl_xor(s, 16, 64);  s  += __shfl_xor(s, 32, 64);
      s2 += __shfl_xor(s2,16, 64);  s2 += __shfl_xor(s2,32, 64);
      if (q == 0){ red[0][wv][nc*16+m] = s; red[1][wv][nc*16+m] = s2; }
    }
    __syncthreads();
    if (tid < 128){
      int which = tid >> 6, c = tid & 63;
      float a = red[which][0][c]+red[which][1][c]+red[which][2][c]+red[which][3][c];
      unsafeAtomicAdd(stats + which*64 + c, a);
    }
}

// ------------------------------------------------------------------
// BN finalize (block 0) + zero stats for next layer + zero pooled
// ------------------------------------------------------------------
__global__ __launch_bounds__(64) void k_bnfin(float* __restrict__ stats,
                        const float* __restrict__ gamma,
                        const float* __restrict__ beta,
                        float* __restrict__ bnp,
                        float* __restrict__ pooled)
{
    if (blockIdx.x == 0) {
        int c = threadIdx.x;  // 64
        float mu  = stats[c]     * (1.0f/NN);
        float ex2 = stats[64+c]  * (1.0f/NN);
        float var = ex2 - mu*mu;
        float sc  = gamma[c] * rsqrtf(var + 1e-5f);
        bnp[c]     = sc;
        bnp[64+c]  = beta[c] - mu*sc;
        stats[c] = 0.f; stats[64+c] = 0.f;
    } else {
        int base = (blockIdx.x - 1)*256 + threadIdx.x;
        #pragma unroll
        for (int i = 0; i < 4; i++) pooled[base + i*64] = 0.f;
    }
}

// ------------------------------------------------------------------
// MFMA BN-apply + inner MLP + fused segment-pool.
// ------------------------------------------------------------------
__global__ __launch_bounds__(256) void k_bn_inner(
    const float* __restrict__ big, const float* __restrict__ bnp,
    const short* __restrict__ wih, const short* __restrict__ wil,
    const float* __restrict__ bi,
    bf16* __restrict__ xh,
    const int* __restrict__ gidx, float* __restrict__ pooled)
{
    __shared__ __align__(16) char buf[4][9472];
    int tid = threadIdx.x, wv = tid >> 6, lane = tid & 63;
    int q = lane >> 4, m = lane & 15;
    int nb = blockIdx.x*128 + wv*32;
    short* Sh = (short*)buf[wv];
    short* Sl = Sh + 2304;

    float sc = bnp[lane], sh = bnp[64 + lane];
    for (int rr = 0; rr < 32; rr++){
        float v = big[(((size_t)(nb+rr)) << 6) + lane];
        v = fmaxf(fmaf(v, sc, sh), 0.f);
        xh[(((size_t)(nb+rr)) << 6) + lane] = __float2bfloat16(v);
        short hb = f2bf_s(v);
        Sh[rr*72 + lane] = hb;
        Sl[rr*72 + lane] = f2bf_s(v - bf2f_s(hb));
    }
    __syncthreads();

    short8 A2h[2][2], A2l[2][2];
    #pragma unroll
    for (int mc=0; mc<2; mc++)
      #pragma unroll
      for (int kc=0; kc<2; kc++){
        A2h[mc][kc] = *(const short8*)(Sh + (mc*16+m)*72 + kc*32 + q*8);
        A2l[mc][kc] = *(const short8*)(Sl + (mc*16+m)*72 + kc*32 + q*8);
      }
    floatx4 acc[2][4];
    #pragma unroll
    for (int mc=0;mc<2;mc++)
      #pragma unroll
      for (int nc=0;nc<4;nc++) acc[mc][nc] = (floatx4){0.f,0.f,0.f,0.f};
    #pragma unroll
    for (int nc=0;nc<4;nc++){
      #pragma unroll
      for (int kc=0;kc<2;kc++){
        short8 bh = *(const short8*)(wih + (nc*16+m)*64 + kc*32 + q*8);
        short8 bl = *(const short8*)(wil + (nc*16+m)*64 + kc*32 + q*8);
        #pragma unroll
        for (int mc=0;mc<2;mc++){
          acc[mc][nc] = __builtin_amdgcn_mfma_f32_16x16x32_bf16(A2h[mc][kc], bh, acc[mc][nc],0,0,0);
          acc[mc][nc] = __builtin_amdgcn_mfma_f32_16x16x32_bf16(A2l[mc][kc], bh, acc[mc][nc],0,0,0);
          acc[mc][nc] = __builtin_amdgcn_mfma_f32_16x16x32_bf16(A2h[mc][kc], bl, acc[mc][nc],0,0,0);
        }
      }
    }
    __syncthreads();   // LDS reads done; safe to repurpose buf

    float* P = (float*)buf[wv];
    #pragma unroll
    for (int nc=0;nc<4;nc++){
      float bia = bi[nc*16+m];
      #pragma unroll
      for (int mc=0;mc<2;mc++)
        #pragma unroll
        for (int r=0;r<4;r++){
          float v = fmaxf(acc[mc][nc][r] + bia, 0.f);
          P[(mc*16 + q*4 + r)*66 + nc*16 + m] = v;
        }
    }
    __syncthreads();

    int gv = (lane < 32) ? gidx[nb + lane] : 0;
    int cur = __shfl(gv, 0, 64);
    float a = 0.f;
    for (int rr = 0; rr < 32; rr++){
        int g = __shfl(gv, rr, 64);
        if (g != cur){
            unsafeAtomicAdd(pooled + (size_t)cur*64 + lane, a);
            a = 0.f; cur = g;
        }
        a += P[rr*66 + lane];
    }
    unsafeAtomicAdd(pooled + (size_t)cur*64 + lane, a);
}

// ------------------------------------------------------------------
// Outer MLP: feats[:, coff:coff+64] = relu(pooled @ w + b)
// ------------------------------------------------------------------
__global__ __launch_bounds__(256) void k_outer(const float* __restrict__ pooled,
    const float* __restrict__ w, const float* __restrict__ b,
    float* __restrict__ feats, int coff)
{
    int g = blockIdx.x*256 + threadIdx.x;  // BG*64
    int bb = g >> 6, j = g & 63;
    const float* pr = pooled + bb*64;
    float a = b[j];
    for (int k = 0; k < 64; k++) a = fmaf(pr[k], w[k*64 + j], a);
    feats[bb*192 + coff + j] = fmaxf(a, 0.f);
}

// ------------------------------------------------------------------
// Tail: TG graphs per block, weights LDS-staged, NTN register-blocked
// ------------------------------------------------------------------
__global__ __launch_bounds__(256) void k_tail(
    const float* __restrict__ qf, const float* __restrict__ cf,
    const float* __restrict__ cw1, const float* __restrict__ cb1,
    const float* __restrict__ cw2, const float* __restrict__ cb2,
    const float* __restrict__ sw1, const float* __restrict__ sb1,
    const float* __restrict__ sw2, const float* __restrict__ sb2,
    const float* __restrict__ nw,  const float* __restrict__ nwb,
    const float* __restrict__ nb,
    const float* __restrict__ mw1, const float* __restrict__ mb1,
    const float* __restrict__ mw2, const float* __restrict__ mb2,
    const float* __restrict__ alpha, const float* __restrict__ beta,
    float* __restrict__ out)
{
    __shared__ float cws[192*96];
    __shared__ float diff[TG][192];
    __shared__ float e1s[TG][64], e2s[TG][64];
    __shared__ float h1s[TG][96], h2s[TG][96];
    __shared__ float s1s[TG][16], s2s[TG][16], srep[TG][16];
    __shared__ float red[16][16][TG];

    int t = threadIdx.x;
    int b0 = blockIdx.x * TG;

    for (int i = t; i < 192*96; i += 256) cws[i] = cw1[i];
    for (int i = t; i < TG*192; i += 256) {
        int b = i / 192, f = i % 192;
        float qv = qf[(b0+b)*192 + f], cv = cf[(b0+b)*192 + f];
        float d = qv - cv;
        diff[b][f] = __expf(-d*d);
        if (f >= 128) { e1s[b][f-128] = qv; e2s[b][f-128] = cv; }
    }
    __syncthreads();

    {
        int b = t >> 5, o = (t & 31) * 3;
        float a0 = cb1[o], a1 = cb1[o+1], a2 = cb1[o+2];
        for (int f = 0; f < 192; f++) {
            float d = diff[b][f];
            const float* w = cws + f*96 + o;
            a0 = fmaf(d, w[0], a0);
            a1 = fmaf(d, w[1], a1);
            a2 = fmaf(d, w[2], a2);
        }
        h1s[b][o] = fmaxf(a0, 0.f);
        h1s[b][o+1] = fmaxf(a1, 0.f);
        h1s[b][o+2] = fmaxf(a2, 0.f);
    }
    __syncthreads();
    for (int i = t; i < 96*96; i += 256) cws[i] = cw2[i];
    __syncthreads();
    {
        int b = t >> 5, o = (t & 31) * 3;
        float a0 = cb2[o], a1 = cb2[o+1], a2 = cb2[o+2];
        for (int f = 0; f < 96; f++) {
            float d = h1s[b][f];
            const float* w = cws + f*96 + o;
            a0 = fmaf(d, w[0], a0);
            a1 = fmaf(d, w[1], a1);
            a2 = fmaf(d, w[2], a2);
        }
        h2s[b][o] = tanhf(a0);
        h2s[b][o+1] = tanhf(a1);
        h2s[b][o+2] = tanhf(a2);
    }
    __syncthreads();
    if (t < TG*16) {
        int b = t >> 4, o = t & 15;
        float a = sb1[o];
        for (int f = 0; f < 96; f++) a = fmaf(h2s[b][f], sw1[f*16+o], a);
        s1s[b][o] = fmaxf(a, 0.f);
    }

    {
        int tt = t & 15, gq = t >> 4;
        int g0 = gq * 4;
        int lane = t & 63;
        float e1v[TG];
        #pragma unroll
        for (int b = 0; b < TG; b++) e1v[b] = e1s[b][lane];
        float v0[TG], v1[TG], v2[TG], v3[TG];
        #pragma unroll
        for (int b = 0; b < TG; b++) { v0[b]=0.f; v1[b]=0.f; v2[b]=0.f; v3[b]=0.f; }
        for (int f = 0; f < 64; f++) {
            const float* wp = nw + ((size_t)f*64 + g0)*16 + tt;
            float w0 = wp[0], w1 = wp[16], w2 = wp[32], w3 = wp[48];
            #pragma unroll
            for (int b = 0; b < TG; b++) {
                float e = __shfl(e1v[b], f, 64);
                v0[b] = fmaf(e, w0, v0[b]);
                v1[b] = fmaf(e, w1, v1[b]);
                v2[b] = fmaf(e, w2, v2[b]);
                v3[b] = fmaf(e, w3, v3[b]);
            }
        }
        #pragma unroll
        for (int b = 0; b < TG; b++) {
            float p = v0[b]*e2s[b][g0] + v1[b]*e2s[b][g0+1]
                    + v2[b]*e2s[b][g0+2] + v3[b]*e2s[b][g0+3];
            red[gq][tt][b] = p;
        }
    }
    __syncthreads();
    if (t < TG*16) {
        int b = t >> 4, tt = t & 15;
        float scv = 0.f;
        #pragma unroll
        for (int gq = 0; gq < 16; gq++) scv += red[gq][tt][b];
        float blk = nb[tt];
        for (int f = 0; f < 64; f++) blk = fmaf(e1s[b][f], nwb[tt*128 + f], blk);
        for (int f = 0; f < 64; f++) blk = fmaf(e2s[b][f], nwb[tt*128 + 64 + f], blk);
        srep[b][tt] = fmaxf(scv + blk, 0.f);
    }
    __syncthreads();
    if (t < TG*16) {
        int b = t >> 4, o = t & 15;
        float a = mb1[o];
        #pragma unroll
        for (int f = 0; f < 16; f++) a = fmaf(srep[b][f], mw1[f*16+o], a);
        s2s[b][o] = fmaxf(a, 0.f);
    }
    __syncthreads();
    if (t < TG) {
        float sco = sb2[0], sm = mb2[0];
        #pragma unroll
        for (int f = 0; f < 16; f++) {
            sco = fmaf(s1s[t][f], sw2[f], sco);
            sm  = fmaf(s2s[t][f], mw2[f], sm);
        }
        float score = 1.f / (1.f + __expf(-sco));
        float sim   = 1.f / (1.f + __expf(-sm));
        out[b0 + t] = alpha[0]*score + beta[0]*sim;
    }
}

// ------------------------------------------------------------------
extern "C" void kernel_launch(void* const* d_in, const int* in_sizes, int n_in,
                              void* d_out, int out_size, void* d_ws, size_t ws_size,
                              hipStream_t stream)
{
    const float* qx  = (const float*)d_in[0];
    const float* cx  = (const float*)d_in[1];
    const int*   qei = (const int*)d_in[2];
    const int*   cei = (const int*)d_in[3];
    const int*   qgi = (const int*)d_in[4];
    const int*   cgi = (const int*)d_in[5];
    const float* Wgw1 = (const float*)d_in[6];
    const float* Wgb1 = (const float*)d_in[7];
    const float* Wgw2 = (const float*)d_in[8];
    const float* Wgb2 = (const float*)d_in[9];
    const float* Wgam = (const float*)d_in[10];
    const float* Wbet = (const float*)d_in[11];
    const float* Weps = (const float*)d_in[12];
    const float* Wiw  = (const float*)d_in[13];
    const float* Wib  = (const float*)d_in[14];
    const float* Wow  = (const float*)d_in[15];
    const float* Wob  = (const float*)d_in[16];
    const float* Wcw1 = (const float*)d_in[17];
    const float* Wcb1 = (const float*)d_in[18];
    const float* Wcw2 = (const float*)d_in[19];
    const float* Wcb2 = (const float*)d_in[20];
    const float* Wsw1 = (const float*)d_in[21];
    const float* Wsb1 = (const float*)d_in[22];
    const float* Wsw2 = (const float*)d_in[23];
    const float* Wsb2 = (const float*)d_in[24];
    const float* Wnw  = (const float*)d_in[25];
    const float* Wnwb = (const float*)d_in[26];
    const float* Wnb  = (const float*)d_in[27];
    const float* Wmw1 = (const float*)d_in[28];
    const float* Wmb1 = (const float*)d_in[29];
    const float* Wmw2 = (const float*)d_in[30];
    const float* Wmb2 = (const float*)d_in[31];
    const float* Wal  = (const float*)d_in[32];
    const float* Wbe  = (const float*)d_in[33];

    float* F      = (float*)d_ws;
    float* big    = F;                       // N*64
    float* stats  = F + 8388608;             // 128
    float* bnp    = stats + 128;             // 128
    float* pooled = bnp + 128;               // BG*64
    float* qf     = pooled + 65536;          // BG*192
    float* cf     = qf + 196608;             // BG*192
    int*   qoff   = (int*)(cf + 196608);     // BG+1
    int*   coff   = qoff + (BG + 1);         // BG+1
    int*   rowptr = coff + (BG + 1);         // NN+1
    int*   cnt    = rowptr + (NN + 1);       // NN (histogram)
    int*   col    = cnt + NN;                // NEDGE
    int*   bsum   = col + NEDGE;             // 128
    int*   boff   = bsum + 128;              // 128
    bf16*  xh     = (bf16*)(boff + 128);     // N*64 bf16
    int*   rank   = (int*)big;               // NEDGE (aliases big; dead during CSR build)
    uintptr_t wtb = (uintptr_t)(xh + (size_t)NN*64);
    wtb = (wtb + 63) & ~((uintptr_t)63);
    short* w1h = (short*)wtb;                // 3*4096 each
    short* w1l = w1h + 3*4096;
    short* w2h = w1l + 3*4096;
    short* w2l = w2h + 3*4096;
    short* wih = w2l + 3*4096;
    short* wil = wih + 3*4096;

    k_wprep<<<144, 256, 0, stream>>>(Wgw1, Wgw2, Wiw, w1h, w1l, w2h, w2l, wih, wil);

    for (int side = 0; side < 2; side++) {
        const float* x0 = side ? cx  : qx;
        const int* ei   = side ? cei : qei;
        const int* gi   = side ? cgi : qgi;
        int* off        = side ? coff : qoff;
        float* feats    = side ? cf  : qf;

        k_offsets<<<5, 256, 0, stream>>>(gi, off);

        k_zero<<<NN/256, 256, 0, stream>>>(cnt);
        k_hist<<<NEDGE/256, 256, 0, stream>>>(ei, cnt, rank);
        k_scan1<<<128, 256, 0, stream>>>(cnt, rowptr, bsum);
        k_scan2<<<1, 128, 0, stream>>>(bsum, boff, rowptr);
        k_scan3<<<NN/256, 256, 0, stream>>>(rowptr, boff);
        k_fill<<<NEDGE/256, 256, 0, stream>>>(ei, rowptr, rank, col);

        k_cvt<<<NN*64/256, 256, 0, stream>>>(x0, xh, stats);

        for (int l = 0; l < LAYERS; l++) {
            k_agg_gin<<<NN/128, 256, 0, stream>>>(xh, rowptr, col, Weps + l,
                                                  w1h + l*4096, w1l + l*4096, Wgb1 + l*64,
                                                  w2h + l*4096, w2l + l*4096, Wgb2 + l*64,
                                                  big, stats);
            k_bnfin<<<257, 64, 0, stream>>>(stats, Wgam + l*64, Wbet + l*64, bnp, pooled);
            k_bn_inner<<<NN/128, 256, 0, stream>>>(big, bnp,
                                                   wih + l*4096, wil + l*4096,
                                                   Wib + l*64, xh, gi, pooled);
            k_outer<<<BG*64/256, 256, 0, stream>>>(pooled, Wow + l*4096, Wob + l*64,
                                                   feats, l*64);
        }
    }

    k_tail<<<BG/TG, 256, 0, stream>>>(qf, cf, Wcw1, Wcb1, Wcw2, Wcb2,
                                      Wsw1, Wsb1, Wsw2, Wsb2,
                                      Wnw, Wnwb, Wnb, Wmw1, Wmb1, Wmw2, Wmb2,
                                      Wal, Wbe, (float*)d_out);
}

// Round 8
// 976.436 us; speedup vs baseline: 2.5646x; 1.0941x over previous
//
#include <hip/hip_runtime.h>
#include <hip/hip_bf16.h>

typedef __hip_bfloat16 bf16;
typedef __attribute__((ext_vector_type(8))) short short8;
typedef __attribute__((ext_vector_type(4))) float floatx4;

#define NN     131072
#define NEDGE  1048576
#define BG     1024
#define LAYERS 3
#define TG     8      // graphs per tail block

// bf16 split helpers (RNE)
__device__ __forceinline__ short f2bf_s(float f){
    union { float f; unsigned u; } x; x.f = f;
    unsigned r = x.u + 0x7fffu + ((x.u >> 16) & 1u);
    return (short)(r >> 16);
}
__device__ __forceinline__ float bf2f_s(short s){
    union { unsigned u; float f; } x; x.u = ((unsigned)(unsigned short)s) << 16;
    return x.f;
}
__device__ __forceinline__ void acc4(const unsigned short* p,
                                     float& a0, float& a1, float& a2, float& a3){
    ushort4 u = *(const ushort4*)p;
    a0 += bf2f_s((short)u.x); a1 += bf2f_s((short)u.y);
    a2 += bf2f_s((short)u.z); a3 += bf2f_s((short)u.w);
}

// ------------------------------------------------------------------
// Segment offsets: off[g] = lower_bound(graph_idx, g)
// ------------------------------------------------------------------
__global__ __launch_bounds__(256) void k_offsets(const int* __restrict__ gi,
                                                 int* __restrict__ off)
{
    int g = blockIdx.x*256 + threadIdx.x;
    if (g > BG) return;
    int lo = 0, hi = NN;
    while (lo < hi) { int mid = (lo + hi) >> 1; if (gi[mid] < g) lo = mid + 1; else hi = mid; }
    off[g] = lo;
}

// ------------------------------------------------------------------
// CSR build (deterministic fill via rank captured in k_hist)
// ------------------------------------------------------------------
__global__ __launch_bounds__(256) void k_zero(int* __restrict__ cnt)
{
    int i = blockIdx.x*256 + threadIdx.x;
    if (i < NN) cnt[i] = 0;
}

__global__ __launch_bounds__(256) void k_hist(const int* __restrict__ ei,
                                              int* __restrict__ cnt,
                                              int* __restrict__ rank)
{
    int e = blockIdx.x*256 + threadIdx.x;
    rank[e] = atomicAdd(cnt + ei[NEDGE + e], 1);
}

__global__ __launch_bounds__(256) void k_scan1(const int* __restrict__ cnt,
    int* __restrict__ rowptr, int* __restrict__ bsum)
{
    __shared__ int sd[256];
    int t = threadIdx.x;
    int base = blockIdx.x*1024 + t*4;
    int c0 = cnt[base], c1 = cnt[base+1], c2 = cnt[base+2], c3 = cnt[base+3];
    int tsum = c0 + c1 + c2 + c3;
    sd[t] = tsum;
    __syncthreads();
    for (int off = 1; off < 256; off <<= 1) {
        int v = (t >= off) ? sd[t-off] : 0;
        __syncthreads();
        sd[t] += v;
        __syncthreads();
    }
    int excl = sd[t] - tsum;
    rowptr[base]   = excl;
    rowptr[base+1] = excl + c0;
    rowptr[base+2] = excl + c0 + c1;
    rowptr[base+3] = excl + c0 + c1 + c2;
    if (t == 255) bsum[blockIdx.x] = sd[255];
}

__global__ __launch_bounds__(128) void k_scan2(const int* __restrict__ bsum,
    int* __restrict__ boff, int* __restrict__ rowptr)
{
    __shared__ int sd[128];
    int t = threadIdx.x;
    int v0 = bsum[t];
    sd[t] = v0;
    __syncthreads();
    for (int off = 1; off < 128; off <<= 1) {
        int v = (t >= off) ? sd[t-off] : 0;
        __syncthreads();
        sd[t] += v;
        __syncthreads();
    }
    boff[t] = sd[t] - v0;
    if (t == 0) rowptr[NN] = NEDGE;
}

__global__ __launch_bounds__(256) void k_scan3(int* __restrict__ rowptr,
    const int* __restrict__ boff)
{
    int i = blockIdx.x*256 + threadIdx.x;
    rowptr[i] += boff[i >> 10];
}

__global__ __launch_bounds__(256) void k_fill(const int* __restrict__ ei,
    const int* __restrict__ rowptr, const int* __restrict__ rank,
    int* __restrict__ col)
{
    int e = blockIdx.x*256 + threadIdx.x;
    int s = ei[e];
    int d = ei[NEDGE + e];
    col[rowptr[d] + rank[e]] = s;
}

// ------------------------------------------------------------------
// fp32 -> bf16 shadow copy of node features; zero stats for layer 0
// ------------------------------------------------------------------
__global__ __launch_bounds__(256) void k_cvt(const float* __restrict__ x,
                                             bf16* __restrict__ xh,
                                             float* __restrict__ stats)
{
    int i = blockIdx.x*256 + threadIdx.x;
    xh[i] = __float2bfloat16(x[i]);
    if (blockIdx.x == 0 && threadIdx.x < 128) stats[threadIdx.x] = 0.f;
}

// ------------------------------------------------------------------
// Weight prep (once/launch): Wt[n][k] = W[k][n], split bf16 hi/lo.
// ------------------------------------------------------------------
__global__ __launch_bounds__(256) void k_wprep(
    const float* __restrict__ gw1, const float* __restrict__ gw2,
    const float* __restrict__ iw,
    short* __restrict__ w1h, short* __restrict__ w1l,
    short* __restrict__ w2h, short* __restrict__ w2l,
    short* __restrict__ wih, short* __restrict__ wil)
{
    int i = blockIdx.x*256 + threadIdx.x;
    if (i >= 3*LAYERS*4096) return;
    int msel = i / (LAYERS*4096);
    int rem  = i % (LAYERS*4096);
    int l = rem >> 12, idx = rem & 4095;
    int n = idx >> 6, k = idx & 63;
    const float* src = (msel==0) ? gw1 : (msel==1) ? gw2 : iw;
    float v = src[l*4096 + k*64 + n];
    short hi = f2bf_s(v);
    short lo = f2bf_s(v - bf2f_s(hi));
    short* dh = (msel==0) ? w1h : (msel==1) ? w2h : wih;
    short* dl = (msel==0) ? w1l : (msel==1) ? w2l : wil;
    dh[rem] = hi;
    dl[rem] = lo;
}

// ------------------------------------------------------------------
// FUSED aggregate + GIN MLP.
// Wave = 32 nodes. Phase 1 (group-per-node): each 16-lane group owns
// one node; one gather instr = one full 128B row; 4-bank unrolled row
// walk => up to 16 rows in flight per wave. Phase 2: two split-bf16
// MFMA GEMMs, BN stats.
// ------------------------------------------------------------------
__global__ __launch_bounds__(256) void k_agg_gin(
    const bf16* __restrict__ xh,
    const int* __restrict__ rowptr, const int* __restrict__ col,
    const float* __restrict__ epsp,
    const short* __restrict__ w1h, const short* __restrict__ w1l,
    const float* __restrict__ b1,
    const short* __restrict__ w2h, const short* __restrict__ w2l,
    const float* __restrict__ b2,
    float* __restrict__ big, float* __restrict__ stats)
{
    __shared__ __align__(16) char buf[4][9472];
    __shared__ float red[2][4][64];
    int tid = threadIdx.x, wv = tid >> 6, lane = tid & 63;
    int q = lane >> 4, m = lane & 15;
    int nb = blockIdx.x*128 + wv*32;
    short* Sh = (short*)buf[wv];
    short* Sl = Sh + 2304;      // 32*72
    float ep = 1.0f + *epsp;

    // ---- Phase 1: group-per-node gather ----
    int gv = rowptr[nb + (lane < 33 ? lane : 32)];
    int grp = q;                 // group 0..3 owns node row = i*4+grp
    int fo = m * 4;              // ushort feature offset (8 B per lane)
    const unsigned short* xt = (const unsigned short*)xh;

    for (int i = 0; i < 8; i++) {
        int row = i*4 + grp;
        int rs = __shfl(gv, row, 64);
        int re = __shfl(gv, row+1, 64);
        float a0=0.f,a1=0.f,a2=0.f,a3=0.f;   // bank A
        float e0=0.f,e1=0.f,e2=0.f,e3=0.f;   // bank B
        float g0=0.f,g1=0.f,g2=0.f,g3=0.f;   // bank C
        float h0=0.f,h1=0.f,h2=0.f,h3=0.f;   // bank D
        int r = rs;
        for (; r + 4 <= re; r += 4) {
            int ca = col[r], cb = col[r+1], cc = col[r+2], cd = col[r+3];
            acc4(xt + (((size_t)ca) << 6) + fo, a0,a1,a2,a3);
            acc4(xt + (((size_t)cb) << 6) + fo, e0,e1,e2,e3);
            acc4(xt + (((size_t)cc) << 6) + fo, g0,g1,g2,g3);
            acc4(xt + (((size_t)cd) << 6) + fo, h0,h1,h2,h3);
        }
        for (; r < re; r++)
            acc4(xt + (((size_t)col[r]) << 6) + fo, a0,a1,a2,a3);
        a0 += e0 + g0 + h0;
        a1 += e1 + g1 + h1;
        a2 += e2 + g2 + h2;
        a3 += e3 + g3 + h3;
        // self term
        ushort4 sv = *(const ushort4*)(xt + (((size_t)(nb+row)) << 6) + fo);
        a0 = fmaf(ep, bf2f_s((short)sv.x), a0);
        a1 = fmaf(ep, bf2f_s((short)sv.y), a1);
        a2 = fmaf(ep, bf2f_s((short)sv.z), a2);
        a3 = fmaf(ep, bf2f_s((short)sv.w), a3);
        // split and store (all 64 lanes store 8 B each)
        short4 hh, ll;
        hh.x = f2bf_s(a0); ll.x = f2bf_s(a0 - bf2f_s(hh.x));
        hh.y = f2bf_s(a1); ll.y = f2bf_s(a1 - bf2f_s(hh.y));
        hh.z = f2bf_s(a2); ll.z = f2bf_s(a2 - bf2f_s(hh.z));
        hh.w = f2bf_s(a3); ll.w = f2bf_s(a3 - bf2f_s(hh.w));
        *(short4*)(Sh + row*72 + fo) = hh;
        *(short4*)(Sl + row*72 + fo) = ll;
    }
    __syncthreads();

    // ---- Phase 2: GEMM1 (A from LDS) ----
    short8 Ah[2][2], Al[2][2];
    #pragma unroll
    for (int mc=0; mc<2; mc++)
      #pragma unroll
      for (int kc=0; kc<2; kc++){
        Ah[mc][kc] = *(const short8*)(Sh + (mc*16+m)*72 + kc*32 + q*8);
        Al[mc][kc] = *(const short8*)(Sl + (mc*16+m)*72 + kc*32 + q*8);
      }
    floatx4 acc[2][4];
    #pragma unroll
    for (int mc=0;mc<2;mc++)
      #pragma unroll
      for (int nc=0;nc<4;nc++) acc[mc][nc] = (floatx4){0.f,0.f,0.f,0.f};
    #pragma unroll
    for (int nc=0;nc<4;nc++){
      #pragma unroll
      for (int kc=0;kc<2;kc++){
        short8 bh = *(const short8*)(w1h + (nc*16+m)*64 + kc*32 + q*8);
        short8 bl = *(const short8*)(w1l + (nc*16+m)*64 + kc*32 + q*8);
        #pragma unroll
        for (int mc=0;mc<2;mc++){
          acc[mc][nc] = __builtin_amdgcn_mfma_f32_16x16x32_bf16(Ah[mc][kc], bh, acc[mc][nc],0,0,0);
          acc[mc][nc] = __builtin_amdgcn_mfma_f32_16x16x32_bf16(Al[mc][kc], bh, acc[mc][nc],0,0,0);
          acc[mc][nc] = __builtin_amdgcn_mfma_f32_16x16x32_bf16(Ah[mc][kc], bl, acc[mc][nc],0,0,0);
        }
      }
    }

    // epilogue 1: bias + relu, split back into LDS
    #pragma unroll
    for (int nc=0;nc<4;nc++){
      float bia = b1[nc*16+m];
      #pragma unroll
      for (int mc=0;mc<2;mc++)
        #pragma unroll
        for (int r=0;r<4;r++){
          float v = fmaxf(acc[mc][nc][r] + bia, 0.f);
          int row = mc*16 + q*4 + r, cl = nc*16 + m;
          short hb = f2bf_s(v);
          Sh[row*72+cl] = hb;
          Sl[row*72+cl] = f2bf_s(v - bf2f_s(hb));
        }
    }
    __syncthreads();

    // GEMM2
    short8 A2h[2][2], A2l[2][2];
    #pragma unroll
    for (int mc=0; mc<2; mc++)
      #pragma unroll
      for (int kc=0; kc<2; kc++){
        A2h[mc][kc] = *(const short8*)(Sh + (mc*16+m)*72 + kc*32 + q*8);
        A2l[mc][kc] = *(const short8*)(Sl + (mc*16+m)*72 + kc*32 + q*8);
      }
    floatx4 acc2[2][4];
    #pragma unroll
    for (int mc=0;mc<2;mc++)
      #pragma unroll
      for (int nc=0;nc<4;nc++) acc2[mc][nc] = (floatx4){0.f,0.f,0.f,0.f};
    #pragma unroll
    for (int nc=0;nc<4;nc++){
      #pragma unroll
      for (int kc=0;kc<2;kc++){
        short8 bh = *(const short8*)(w2h + (nc*16+m)*64 + kc*32 + q*8);
        short8 bl = *(const short8*)(w2l + (nc*16+m)*64 + kc*32 + q*8);
        #pragma unroll
        for (int mc=0;mc<2;mc++){
          acc2[mc][nc] = __builtin_amdgcn_mfma_f32_16x16x32_bf16(A2h[mc][kc], bh, acc2[mc][nc],0,0,0);
          acc2[mc][nc] = __builtin_amdgcn_mfma_f32_16x16x32_bf16(A2l[mc][kc], bh, acc2[mc][nc],0,0,0);
          acc2[mc][nc] = __builtin_amdgcn_mfma_f32_16x16x32_bf16(A2h[mc][kc], bl, acc2[mc][nc],0,0,0);
        }
      }
    }

    // epilogue 2: bias, store h2, BN stats
    #pragma unroll
    for (int nc=0;nc<4;nc++){
      float bia = b2[nc*16+m];
      float s = 0.f, s2 = 0.f;
      #pragma unroll
      for (int mc=0;mc<2;mc++)
        #pragma unroll
        for (int r=0;r<4;r++){
          float v = acc2[mc][nc][r] + bia;
          big[(((size_t)(nb + mc*16 + q*4 + r)) << 6) + nc*16 + m] = v;
          s += v; s2 = fmaf(v, v, s2);
        }
      s  += __shfl_xor(s, 16, 64);  s  += __shfl_xor(s, 32, 64);
      s2 += __shfl_xor(s2,16, 64);  s2 += __shfl_xor(s2,32, 64);
      if (q == 0){ red[0][wv][nc*16+m] = s; red[1][wv][nc*16+m] = s2; }
    }
    __syncthreads();
    if (tid < 128){
      int which = tid >> 6, c = tid & 63;
      float a = red[which][0][c]+red[which][1][c]+red[which][2][c]+red[which][3][c];
      unsafeAtomicAdd(stats + which*64 + c, a);
    }
}

// ------------------------------------------------------------------
// BN finalize (block 0) + zero stats for next layer + zero pooled
// ------------------------------------------------------------------
__global__ __launch_bounds__(64) void k_bnfin(float* __restrict__ stats,
                        const float* __restrict__ gamma,
                        const float* __restrict__ beta,
                        float* __restrict__ bnp,
                        float* __restrict__ pooled)
{
    if (blockIdx.x == 0) {
        int c = threadIdx.x;  // 64
        float mu  = stats[c]     * (1.0f/NN);
        float ex2 = stats[64+c]  * (1.0f/NN);
        float var = ex2 - mu*mu;
        float sc  = gamma[c] * rsqrtf(var + 1e-5f);
        bnp[c]     = sc;
        bnp[64+c]  = beta[c] - mu*sc;
        stats[c] = 0.f; stats[64+c] = 0.f;
    } else {
        int base = (blockIdx.x - 1)*256 + threadIdx.x;
        #pragma unroll
        for (int i = 0; i < 4; i++) pooled[base + i*64] = 0.f;
    }
}

// ------------------------------------------------------------------
// MFMA BN-apply + inner MLP + fused segment-pool.
// ------------------------------------------------------------------
__global__ __launch_bounds__(256) void k_bn_inner(
    const float* __restrict__ big, const float* __restrict__ bnp,
    const short* __restrict__ wih, const short* __restrict__ wil,
    const float* __restrict__ bi,
    bf16* __restrict__ xh,
    const int* __restrict__ gidx, float* __restrict__ pooled)
{
    __shared__ __align__(16) char buf[4][9472];
    int tid = threadIdx.x, wv = tid >> 6, lane = tid & 63;
    int q = lane >> 4, m = lane & 15;
    int nb = blockIdx.x*128 + wv*32;
    short* Sh = (short*)buf[wv];
    short* Sl = Sh + 2304;

    float sc = bnp[lane], sh = bnp[64 + lane];
    for (int rr = 0; rr < 32; rr++){
        float v = big[(((size_t)(nb+rr)) << 6) + lane];
        v = fmaxf(fmaf(v, sc, sh), 0.f);
        xh[(((size_t)(nb+rr)) << 6) + lane] = __float2bfloat16(v);
        short hb = f2bf_s(v);
        Sh[rr*72 + lane] = hb;
        Sl[rr*72 + lane] = f2bf_s(v - bf2f_s(hb));
    }
    __syncthreads();

    short8 A2h[2][2], A2l[2][2];
    #pragma unroll
    for (int mc=0; mc<2; mc++)
      #pragma unroll
      for (int kc=0; kc<2; kc++){
        A2h[mc][kc] = *(const short8*)(Sh + (mc*16+m)*72 + kc*32 + q*8);
        A2l[mc][kc] = *(const short8*)(Sl + (mc*16+m)*72 + kc*32 + q*8);
      }
    floatx4 acc[2][4];
    #pragma unroll
    for (int mc=0;mc<2;mc++)
      #pragma unroll
      for (int nc=0;nc<4;nc++) acc[mc][nc] = (floatx4){0.f,0.f,0.f,0.f};
    #pragma unroll
    for (int nc=0;nc<4;nc++){
      #pragma unroll
      for (int kc=0;kc<2;kc++){
        short8 bh = *(const short8*)(wih + (nc*16+m)*64 + kc*32 + q*8);
        short8 bl = *(const short8*)(wil + (nc*16+m)*64 + kc*32 + q*8);
        #pragma unroll
        for (int mc=0;mc<2;mc++){
          acc[mc][nc] = __builtin_amdgcn_mfma_f32_16x16x32_bf16(A2h[mc][kc], bh, acc[mc][nc],0,0,0);
          acc[mc][nc] = __builtin_amdgcn_mfma_f32_16x16x32_bf16(A2l[mc][kc], bh, acc[mc][nc],0,0,0);
          acc[mc][nc] = __builtin_amdgcn_mfma_f32_16x16x32_bf16(A2h[mc][kc], bl, acc[mc][nc],0,0,0);
        }
      }
    }
    __syncthreads();   // LDS reads done; safe to repurpose buf

    float* P = (float*)buf[wv];
    #pragma unroll
    for (int nc=0;nc<4;nc++){
      float bia = bi[nc*16+m];
      #pragma unroll
      for (int mc=0;mc<2;mc++)
        #pragma unroll
        for (int r=0;r<4;r++){
          float v = fmaxf(acc[mc][nc][r] + bia, 0.f);
          P[(mc*16 + q*4 + r)*66 + nc*16 + m] = v;
        }
    }
    __syncthreads();

    int gv = (lane < 32) ? gidx[nb + lane] : 0;
    int cur = __shfl(gv, 0, 64);
    float a = 0.f;
    for (int rr = 0; rr < 32; rr++){
        int g = __shfl(gv, rr, 64);
        if (g != cur){
            unsafeAtomicAdd(pooled + (size_t)cur*64 + lane, a);
            a = 0.f; cur = g;
        }
        a += P[rr*66 + lane];
    }
    unsafeAtomicAdd(pooled + (size_t)cur*64 + lane, a);
}

// ------------------------------------------------------------------
// Outer MLP: feats[:, coff:coff+64] = relu(pooled @ w + b)
// ------------------------------------------------------------------
__global__ __launch_bounds__(256) void k_outer(const float* __restrict__ pooled,
    const float* __restrict__ w, const float* __restrict__ b,
    float* __restrict__ feats, int coff)
{
    int g = blockIdx.x*256 + threadIdx.x;  // BG*64
    int bb = g >> 6, j = g & 63;
    const float* pr = pooled + bb*64;
    float a = b[j];
    for (int k = 0; k < 64; k++) a = fmaf(pr[k], w[k*64 + j], a);
    feats[bb*192 + coff + j] = fmaxf(a, 0.f);
}

// ------------------------------------------------------------------
// Tail: TG graphs per block, weights LDS-staged, NTN register-blocked
// ------------------------------------------------------------------
__global__ __launch_bounds__(256) void k_tail(
    const float* __restrict__ qf, const float* __restrict__ cf,
    const float* __restrict__ cw1, const float* __restrict__ cb1,
    const float* __restrict__ cw2, const float* __restrict__ cb2,
    const float* __restrict__ sw1, const float* __restrict__ sb1,
    const float* __restrict__ sw2, const float* __restrict__ sb2,
    const float* __restrict__ nw,  const float* __restrict__ nwb,
    const float* __restrict__ nb,
    const float* __restrict__ mw1, const float* __restrict__ mb1,
    const float* __restrict__ mw2, const float* __restrict__ mb2,
    const float* __restrict__ alpha, const float* __restrict__ beta,
    float* __restrict__ out)
{
    __shared__ float cws[192*96];
    __shared__ float diff[TG][192];
    __shared__ float e1s[TG][64], e2s[TG][64];
    __shared__ float h1s[TG][96], h2s[TG][96];
    __shared__ float s1s[TG][16], s2s[TG][16], srep[TG][16];
    __shared__ float red[16][16][TG];

    int t = threadIdx.x;
    int b0 = blockIdx.x * TG;

    for (int i = t; i < 192*96; i += 256) cws[i] = cw1[i];
    for (int i = t; i < TG*192; i += 256) {
        int b = i / 192, f = i % 192;
        float qv = qf[(b0+b)*192 + f], cv = cf[(b0+b)*192 + f];
        float d = qv - cv;
        diff[b][f] = __expf(-d*d);
        if (f >= 128) { e1s[b][f-128] = qv; e2s[b][f-128] = cv; }
    }
    __syncthreads();

    {
        int b = t >> 5, o = (t & 31) * 3;
        float a0 = cb1[o], a1 = cb1[o+1], a2 = cb1[o+2];
        for (int f = 0; f < 192; f++) {
            float d = diff[b][f];
            const float* w = cws + f*96 + o;
            a0 = fmaf(d, w[0], a0);
            a1 = fmaf(d, w[1], a1);
            a2 = fmaf(d, w[2], a2);
        }
        h1s[b][o] = fmaxf(a0, 0.f);
        h1s[b][o+1] = fmaxf(a1, 0.f);
        h1s[b][o+2] = fmaxf(a2, 0.f);
    }
    __syncthreads();
    for (int i = t; i < 96*96; i += 256) cws[i] = cw2[i];
    __syncthreads();
    {
        int b = t >> 5, o = (t & 31) * 3;
        float a0 = cb2[o], a1 = cb2[o+1], a2 = cb2[o+2];
        for (int f = 0; f < 96; f++) {
            float d = h1s[b][f];
            const float* w = cws + f*96 + o;
            a0 = fmaf(d, w[0], a0);
            a1 = fmaf(d, w[1], a1);
            a2 = fmaf(d, w[2], a2);
        }
        h2s[b][o] = tanhf(a0);
        h2s[b][o+1] = tanhf(a1);
        h2s[b][o+2] = tanhf(a2);
    }
    __syncthreads();
    if (t < TG*16) {
        int b = t >> 4, o = t & 15;
        float a = sb1[o];
        for (int f = 0; f < 96; f++) a = fmaf(h2s[b][f], sw1[f*16+o], a);
        s1s[b][o] = fmaxf(a, 0.f);
    }

    {
        int tt = t & 15, gq = t >> 4;
        int g0 = gq * 4;
        int lane = t & 63;
        float e1v[TG];
        #pragma unroll
        for (int b = 0; b < TG; b++) e1v[b] = e1s[b][lane];
        float v0[TG], v1[TG], v2[TG], v3[TG];
        #pragma unroll
        for (int b = 0; b < TG; b++) { v0[b]=0.f; v1[b]=0.f; v2[b]=0.f; v3[b]=0.f; }
        for (int f = 0; f < 64; f++) {
            const float* wp = nw + ((size_t)f*64 + g0)*16 + tt;
            float w0 = wp[0], w1 = wp[16], w2 = wp[32], w3 = wp[48];
            #pragma unroll
            for (int b = 0; b < TG; b++) {
                float e = __shfl(e1v[b], f, 64);
                v0[b] = fmaf(e, w0, v0[b]);
                v1[b] = fmaf(e, w1, v1[b]);
                v2[b] = fmaf(e, w2, v2[b]);
                v3[b] = fmaf(e, w3, v3[b]);
            }
        }
        #pragma unroll
        for (int b = 0; b < TG; b++) {
            float p = v0[b]*e2s[b][g0] + v1[b]*e2s[b][g0+1]
                    + v2[b]*e2s[b][g0+2] + v3[b]*e2s[b][g0+3];
            red[gq][tt][b] = p;
        }
    }
    __syncthreads();
    if (t < TG*16) {
        int b = t >> 4, tt = t & 15;
        float scv = 0.f;
        #pragma unroll
        for (int gq = 0; gq < 16; gq++) scv += red[gq][tt][b];
        float blk = nb[tt];
        for (int f = 0; f < 64; f++) blk = fmaf(e1s[b][f], nwb[tt*128 + f], blk);
        for (int f = 0; f < 64; f++) blk = fmaf(e2s[b][f], nwb[tt*128 + 64 + f], blk);
        srep[b][tt] = fmaxf(scv + blk, 0.f);
    }
    __syncthreads();
    if (t < TG*16) {
        int b = t >> 4, o = t & 15;
        float a = mb1[o];
        #pragma unroll
        for (int f = 0; f < 16; f++) a = fmaf(srep[b][f], mw1[f*16+o], a);
        s2s[b][o] = fmaxf(a, 0.f);
    }
    __syncthreads();
    if (t < TG) {
        float sco = sb2[0], sm = mb2[0];
        #pragma unroll
        for (int f = 0; f < 16; f++) {
            sco = fmaf(s1s[t][f], sw2[f], sco);
            sm  = fmaf(s2s[t][f], mw2[f], sm);
        }
        float score = 1.f / (1.f + __expf(-sco));
        float sim   = 1.f / (1.f + __expf(-sm));
        out[b0 + t] = alpha[0]*score + beta[0]*sim;
    }
}

// ------------------------------------------------------------------
extern "C" void kernel_launch(void* const* d_in, const int* in_sizes, int n_in,
                              void* d_out, int out_size, void* d_ws, size_t ws_size,
                              hipStream_t stream)
{
    const float* qx  = (const float*)d_in[0];
    const float* cx  = (const float*)d_in[1];
    const int*   qei = (const int*)d_in[2];
    const int*   cei = (const int*)d_in[3];
    const int*   qgi = (const int*)d_in[4];
    const int*   cgi = (const int*)d_in[5];
    const float* Wgw1 = (const float*)d_in[6];
    const float* Wgb1 = (const float*)d_in[7];
    const float* Wgw2 = (const float*)d_in[8];
    const float* Wgb2 = (const float*)d_in[9];
    const float* Wgam = (const float*)d_in[10];
    const float* Wbet = (const float*)d_in[11];
    const float* Weps = (const float*)d_in[12];
    const float* Wiw  = (const float*)d_in[13];
    const float* Wib  = (const float*)d_in[14];
    const float* Wow  = (const float*)d_in[15];
    const float* Wob  = (const float*)d_in[16];
    const float* Wcw1 = (const float*)d_in[17];
    const float* Wcb1 = (const float*)d_in[18];
    const float* Wcw2 = (const float*)d_in[19];
    const float* Wcb2 = (const float*)d_in[20];
    const float* Wsw1 = (const float*)d_in[21];
    const float* Wsb1 = (const float*)d_in[22];
    const float* Wsw2 = (const float*)d_in[23];
    const float* Wsb2 = (const float*)d_in[24];
    const float* Wnw  = (const float*)d_in[25];
    const float* Wnwb = (const float*)d_in[26];
    const float* Wnb  = (const float*)d_in[27];
    const float* Wmw1 = (const float*)d_in[28];
    const float* Wmb1 = (const float*)d_in[29];
    const float* Wmw2 = (const float*)d_in[30];
    const float* Wmb2 = (const float*)d_in[31];
    const float* Wal  = (const float*)d_in[32];
    const float* Wbe  = (const float*)d_in[33];

    float* F      = (float*)d_ws;
    float* big    = F;                       // N*64
    float* stats  = F + 8388608;             // 128
    float* bnp    = stats + 128;             // 128
    float* pooled = bnp + 128;               // BG*64
    float* qf     = pooled + 65536;          // BG*192
    float* cf     = qf + 196608;             // BG*192
    int*   qoff   = (int*)(cf + 196608);     // BG+1
    int*   coff   = qoff + (BG + 1);         // BG+1
    int*   rowptr = coff + (BG + 1);         // NN+1
    int*   cnt    = rowptr + (NN + 1);       // NN (histogram)
    int*   col    = cnt + NN;                // NEDGE
    int*   bsum   = col + NEDGE;             // 128
    int*   boff   = bsum + 128;              // 128
    bf16*  xh     = (bf16*)(boff + 128);     // N*64 bf16
    int*   rank   = (int*)big;               // NEDGE (aliases big; dead during CSR build)
    uintptr_t wtb = (uintptr_t)(xh + (size_t)NN*64);
    wtb = (wtb + 63) & ~((uintptr_t)63);
    short* w1h = (short*)wtb;                // 3*4096 each
    short* w1l = w1h + 3*4096;
    short* w2h = w1l + 3*4096;
    short* w2l = w2h + 3*4096;
    short* wih = w2l + 3*4096;
    short* wil = wih + 3*4096;

    k_wprep<<<144, 256, 0, stream>>>(Wgw1, Wgw2, Wiw, w1h, w1l, w2h, w2l, wih, wil);

    for (int side = 0; side < 2; side++) {
        const float* x0 = side ? cx  : qx;
        const int* ei   = side ? cei : qei;
        const int* gi   = side ? cgi : qgi;
        int* off        = side ? coff : qoff;
        float* feats    = side ? cf  : qf;

        k_offsets<<<5, 256, 0, stream>>>(gi, off);

        k_zero<<<NN/256, 256, 0, stream>>>(cnt);
        k_hist<<<NEDGE/256, 256, 0, stream>>>(ei, cnt, rank);
        k_scan1<<<128, 256, 0, stream>>>(cnt, rowptr, bsum);
        k_scan2<<<1, 128, 0, stream>>>(bsum, boff, rowptr);
        k_scan3<<<NN/256, 256, 0, stream>>>(rowptr, boff);
        k_fill<<<NEDGE/256, 256, 0, stream>>>(ei, rowptr, rank, col);

        k_cvt<<<NN*64/256, 256, 0, stream>>>(x0, xh, stats);

        for (int l = 0; l < LAYERS; l++) {
            k_agg_gin<<<NN/128, 256, 0, stream>>>(xh, rowptr, col, Weps + l,
                                                  w1h + l*4096, w1l + l*4096, Wgb1 + l*64,
                                                  w2h + l*4096, w2l + l*4096, Wgb2 + l*64,
                                                  big, stats);
            k_bnfin<<<257, 64, 0, stream>>>(stats, Wgam + l*64, Wbet + l*64, bnp, pooled);
            k_bn_inner<<<NN/128, 256, 0, stream>>>(big, bnp,
                                                   wih + l*4096, wil + l*4096,
                                                   Wib + l*64, xh, gi, pooled);
            k_outer<<<BG*64/256, 256, 0, stream>>>(pooled, Wow + l*4096, Wob + l*64,
                                                   feats, l*64);
        }
    }

    k_tail<<<BG/TG, 256, 0, stream>>>(qf, cf, Wcw1, Wcb1, Wcw2, Wcb2,
                                      Wsw1, Wsb1, Wsw2, Wsb2,
                                      Wnw, Wnwb, Wnb, Wmw1, Wmb1, Wmw2, Wmb2,
                                      Wal, Wbe, (float*)d_out);
}

// Round 10
// 922.625 us; speedup vs baseline: 2.7142x; 1.0583x over previous
//
#include <hip/hip_runtime.h>
#include <hip/hip_bf16.h>

typedef __hip_bfloat16 bf16;
typedef __attribute__((ext_vector_type(8))) short short8;
typedef __attribute__((ext_vector_type(4))) float floatx4;

#define NN     131072
#define NEDGE  1048576
#define BG     1024
#define LAYERS 3
#define TG     8      // graphs per tail block

// bf16 split helpers (RNE)
__device__ __forceinline__ short f2bf_s(float f){
    union { float f; unsigned u; } x; x.f = f;
    unsigned r = x.u + 0x7fffu + ((x.u >> 16) & 1u);
    return (short)(r >> 16);
}
__device__ __forceinline__ float bf2f_s(short s){
    union { unsigned u; float f; } x; x.u = ((unsigned)(unsigned short)s) << 16;
    return x.f;
}
__device__ __forceinline__ void acc4(const unsigned short* p,
                                     float& a0, float& a1, float& a2, float& a3){
    ushort4 u = *(const ushort4*)p;
    a0 += bf2f_s((short)u.x); a1 += bf2f_s((short)u.y);
    a2 += bf2f_s((short)u.z); a3 += bf2f_s((short)u.w);
}

// ------------------------------------------------------------------
// CSR build (deterministic fill via rank captured in k_hist).
// k_zero also carries the folded outer MLP of the PREVIOUS side's
// last layer (pooled_prev != nullptr on side 1 only).
// ------------------------------------------------------------------
__global__ __launch_bounds__(256) void k_zero(int* __restrict__ cnt,
    const float* __restrict__ pooled_prev, const float* __restrict__ owp,
    const float* __restrict__ obp, float* __restrict__ feats_prev)
{
    int i = blockIdx.x*256 + threadIdx.x;
    if (i < NN) cnt[i] = 0;
    if (pooled_prev && blockIdx.x < 256) {
        int bb = i >> 6, j = i & 63;
        const float* pr = pooled_prev + bb*64;
        float a = obp[j];
        for (int k = 0; k < 64; k++) a = fmaf(pr[k], owp[k*64 + j], a);
        feats_prev[bb*192 + 128 + j] = fmaxf(a, 0.f);
    }
}

__global__ __launch_bounds__(256) void k_hist(const int* __restrict__ ei,
                                              int* __restrict__ cnt,
                                              int* __restrict__ rank)
{
    int e = blockIdx.x*256 + threadIdx.x;
    rank[e] = atomicAdd(cnt + ei[NEDGE + e], 1);
}

__global__ __launch_bounds__(256) void k_scan1(const int* __restrict__ cnt,
    int* __restrict__ rowptr, int* __restrict__ bsum)
{
    __shared__ int sd[256];
    int t = threadIdx.x;
    int base = blockIdx.x*1024 + t*4;
    int c0 = cnt[base], c1 = cnt[base+1], c2 = cnt[base+2], c3 = cnt[base+3];
    int tsum = c0 + c1 + c2 + c3;
    sd[t] = tsum;
    __syncthreads();
    for (int off = 1; off < 256; off <<= 1) {
        int v = (t >= off) ? sd[t-off] : 0;
        __syncthreads();
        sd[t] += v;
        __syncthreads();
    }
    int excl = sd[t] - tsum;
    rowptr[base]   = excl;
    rowptr[base+1] = excl + c0;
    rowptr[base+2] = excl + c0 + c1;
    rowptr[base+3] = excl + c0 + c1 + c2;
    if (t == 255) bsum[blockIdx.x] = sd[255];
}

__global__ __launch_bounds__(128) void k_scan2(const int* __restrict__ bsum,
    int* __restrict__ boff, int* __restrict__ rowptr)
{
    __shared__ int sd[128];
    int t = threadIdx.x;
    int v0 = bsum[t];
    sd[t] = v0;
    __syncthreads();
    for (int off = 1; off < 128; off <<= 1) {
        int v = (t >= off) ? sd[t-off] : 0;
        __syncthreads();
        sd[t] += v;
        __syncthreads();
    }
    boff[t] = sd[t] - v0;
    if (t == 0) rowptr[NN] = NEDGE;
}

__global__ __launch_bounds__(256) void k_scan3(int* __restrict__ rowptr,
    const int* __restrict__ boff)
{
    int i = blockIdx.x*256 + threadIdx.x;
    rowptr[i] += boff[i >> 10];
}

__global__ __launch_bounds__(256) void k_fill(const int* __restrict__ ei,
    const int* __restrict__ rowptr, const int* __restrict__ rank,
    int* __restrict__ col)
{
    int e = blockIdx.x*256 + threadIdx.x;
    int s = ei[e];
    int d = ei[NEDGE + e];
    col[rowptr[d] + rank[e]] = s;
}

// ------------------------------------------------------------------
// fp32 -> bf16 shadow of node features (vectorized) + zero stats3/pooled3
// ------------------------------------------------------------------
__global__ __launch_bounds__(256) void k_cvt(const float* __restrict__ x,
                                             bf16* __restrict__ xh,
                                             float* __restrict__ zbuf)
{
    int i = blockIdx.x*256 + threadIdx.x;   // 8192 blocks -> NN*64/4 threads
    float4 v = ((const float4*)x)[i];
    short4 o;
    o.x = f2bf_s(v.x); o.y = f2bf_s(v.y);
    o.z = f2bf_s(v.z); o.w = f2bf_s(v.w);
    ((short4*)xh)[i] = o;
    if (i < 3*128 + 3*BG*64) zbuf[i] = 0.f;
}

// ------------------------------------------------------------------
// Weight prep (once/launch): Wt[n][k] = W[k][n], split bf16 hi/lo.
// ------------------------------------------------------------------
__global__ __launch_bounds__(256) void k_wprep(
    const float* __restrict__ gw1, const float* __restrict__ gw2,
    const float* __restrict__ iw,
    short* __restrict__ w1h, short* __restrict__ w1l,
    short* __restrict__ w2h, short* __restrict__ w2l,
    short* __restrict__ wih, short* __restrict__ wil)
{
    int i = blockIdx.x*256 + threadIdx.x;
    if (i >= 3*LAYERS*4096) return;
    int msel = i / (LAYERS*4096);
    int rem  = i % (LAYERS*4096);
    int l = rem >> 12, idx = rem & 4095;
    int n = idx >> 6, k = idx & 63;
    const float* src = (msel==0) ? gw1 : (msel==1) ? gw2 : iw;
    float v = src[l*4096 + k*64 + n];
    short hi = f2bf_s(v);
    short lo = f2bf_s(v - bf2f_s(hi));
    short* dh = (msel==0) ? w1h : (msel==1) ? w2h : wih;
    short* dl = (msel==0) ? w1l : (msel==1) ? w2l : wil;
    dh[rem] = hi;
    dl[rem] = lo;
}

// ------------------------------------------------------------------
// FUSED aggregate + GIN MLP (+ folded outer MLP of previous layer on
// blocks 0-255 when pooled_prev != nullptr).
// ------------------------------------------------------------------
__global__ __launch_bounds__(256) void k_agg_gin(
    const bf16* __restrict__ xh,
    const int* __restrict__ rowptr, const int* __restrict__ col,
    const float* __restrict__ epsp,
    const short* __restrict__ w1h, const short* __restrict__ w1l,
    const float* __restrict__ b1,
    const short* __restrict__ w2h, const short* __restrict__ w2l,
    const float* __restrict__ b2,
    float* __restrict__ big, float* __restrict__ stats,
    const float* __restrict__ pooled_prev, const float* __restrict__ owp,
    const float* __restrict__ obp, float* __restrict__ feats, int coffp)
{
    __shared__ __align__(16) char buf[4][9472];
    __shared__ float red[2][4][64];
    int tid = threadIdx.x, wv = tid >> 6, lane = tid & 63;
    int q = lane >> 4, m = lane & 15;
    int nb = blockIdx.x*128 + wv*32;
    short* Sh = (short*)buf[wv];
    short* Sl = Sh + 2304;      // 32*72
    float ep = 1.0f + *epsp;

    // folded outer MLP of previous layer
    if (pooled_prev && blockIdx.x < 256) {
        int g = blockIdx.x*256 + tid;
        int bb = g >> 6, j = g & 63;
        const float* pr = pooled_prev + bb*64;
        float a = obp[j];
        for (int k = 0; k < 64; k++) a = fmaf(pr[k], owp[k*64 + j], a);
        feats[bb*192 + coffp + j] = fmaxf(a, 0.f);
    }

    // ---- Phase 1: group-per-node gather ----
    int gv = rowptr[nb + (lane < 33 ? lane : 32)];
    int fo = m * 4;              // ushort feature offset (8 B per lane)
    const unsigned short* xt = (const unsigned short*)xh;

    for (int i = 0; i < 8; i++) {
        int row = i*4 + q;
        int rs = __shfl(gv, row, 64);
        int re = __shfl(gv, row+1, 64);
        float a0=0.f,a1=0.f,a2=0.f,a3=0.f;
        float e0=0.f,e1=0.f,e2=0.f,e3=0.f;
        float g0=0.f,g1=0.f,g2=0.f,g3=0.f;
        float h0=0.f,h1=0.f,h2=0.f,h3=0.f;
        int r = rs;
        for (; r + 4 <= re; r += 4) {
            int ca = col[r], cb = col[r+1], cc = col[r+2], cd = col[r+3];
            acc4(xt + (((size_t)ca) << 6) + fo, a0,a1,a2,a3);
            acc4(xt + (((size_t)cb) << 6) + fo, e0,e1,e2,e3);
            acc4(xt + (((size_t)cc) << 6) + fo, g0,g1,g2,g3);
            acc4(xt + (((size_t)cd) << 6) + fo, h0,h1,h2,h3);
        }
        for (; r < re; r++)
            acc4(xt + (((size_t)col[r]) << 6) + fo, a0,a1,a2,a3);
        a0 += e0 + g0 + h0;
        a1 += e1 + g1 + h1;
        a2 += e2 + g2 + h2;
        a3 += e3 + g3 + h3;
        ushort4 sv = *(const ushort4*)(xt + (((size_t)(nb+row)) << 6) + fo);
        a0 = fmaf(ep, bf2f_s((short)sv.x), a0);
        a1 = fmaf(ep, bf2f_s((short)sv.y), a1);
        a2 = fmaf(ep, bf2f_s((short)sv.z), a2);
        a3 = fmaf(ep, bf2f_s((short)sv.w), a3);
        short4 hh, ll;
        hh.x = f2bf_s(a0); ll.x = f2bf_s(a0 - bf2f_s(hh.x));
        hh.y = f2bf_s(a1); ll.y = f2bf_s(a1 - bf2f_s(hh.y));
        hh.z = f2bf_s(a2); ll.z = f2bf_s(a2 - bf2f_s(hh.z));
        hh.w = f2bf_s(a3); ll.w = f2bf_s(a3 - bf2f_s(hh.w));
        *(short4*)(Sh + row*72 + fo) = hh;
        *(short4*)(Sl + row*72 + fo) = ll;
    }
    __syncthreads();

    // ---- Phase 2: GEMM1 (A from LDS) ----
    short8 Ah[2][2], Al[2][2];
    #pragma unroll
    for (int mc=0; mc<2; mc++)
      #pragma unroll
      for (int kc=0; kc<2; kc++){
        Ah[mc][kc] = *(const short8*)(Sh + (mc*16+m)*72 + kc*32 + q*8);
        Al[mc][kc] = *(const short8*)(Sl + (mc*16+m)*72 + kc*32 + q*8);
      }
    floatx4 acc[2][4];
    #pragma unroll
    for (int mc=0;mc<2;mc++)
      #pragma unroll
      for (int nc=0;nc<4;nc++) acc[mc][nc] = (floatx4){0.f,0.f,0.f,0.f};
    #pragma unroll
    for (int nc=0;nc<4;nc++){
      #pragma unroll
      for (int kc=0;kc<2;kc++){
        short8 bh = *(const short8*)(w1h + (nc*16+m)*64 + kc*32 + q*8);
        short8 bl = *(const short8*)(w1l + (nc*16+m)*64 + kc*32 + q*8);
        #pragma unroll
        for (int mc=0;mc<2;mc++){
          acc[mc][nc] = __builtin_amdgcn_mfma_f32_16x16x32_bf16(Ah[mc][kc], bh, acc[mc][nc],0,0,0);
          acc[mc][nc] = __builtin_amdgcn_mfma_f32_16x16x32_bf16(Al[mc][kc], bh, acc[mc][nc],0,0,0);
          acc[mc][nc] = __builtin_amdgcn_mfma_f32_16x16x32_bf16(Ah[mc][kc], bl, acc[mc][nc],0,0,0);
        }
      }
    }

    // epilogue 1: bias + relu, split back into LDS
    #pragma unroll
    for (int nc=0;nc<4;nc++){
      float bia = b1[nc*16+m];
      #pragma unroll
      for (int mc=0;mc<2;mc++)
        #pragma unroll
        for (int r=0;r<4;r++){
          float v = fmaxf(acc[mc][nc][r] + bia, 0.f);
          int row = mc*16 + q*4 + r, cl = nc*16 + m;
          short hb = f2bf_s(v);
          Sh[row*72+cl] = hb;
          Sl[row*72+cl] = f2bf_s(v - bf2f_s(hb));
        }
    }
    __syncthreads();

    // GEMM2
    short8 A2h[2][2], A2l[2][2];
    #pragma unroll
    for (int mc=0; mc<2; mc++)
      #pragma unroll
      for (int kc=0; kc<2; kc++){
        A2h[mc][kc] = *(const short8*)(Sh + (mc*16+m)*72 + kc*32 + q*8);
        A2l[mc][kc] = *(const short8*)(Sl + (mc*16+m)*72 + kc*32 + q*8);
      }
    floatx4 acc2[2][4];
    #pragma unroll
    for (int mc=0;mc<2;mc++)
      #pragma unroll
      for (int nc=0;nc<4;nc++) acc2[mc][nc] = (floatx4){0.f,0.f,0.f,0.f};
    #pragma unroll
    for (int nc=0;nc<4;nc++){
      #pragma unroll
      for (int kc=0;kc<2;kc++){
        short8 bh = *(const short8*)(w2h + (nc*16+m)*64 + kc*32 + q*8);
        short8 bl = *(const short8*)(w2l + (nc*16+m)*64 + kc*32 + q*8);
        #pragma unroll
        for (int mc=0;mc<2;mc++){
          acc2[mc][nc] = __builtin_amdgcn_mfma_f32_16x16x32_bf16(A2h[mc][kc], bh, acc2[mc][nc],0,0,0);
          acc2[mc][nc] = __builtin_amdgcn_mfma_f32_16x16x32_bf16(A2l[mc][kc], bh, acc2[mc][nc],0,0,0);
          acc2[mc][nc] = __builtin_amdgcn_mfma_f32_16x16x32_bf16(A2h[mc][kc], bl, acc2[mc][nc],0,0,0);
        }
      }
    }

    // epilogue 2: bias, store h2, BN stats
    #pragma unroll
    for (int nc=0;nc<4;nc++){
      float bia = b2[nc*16+m];
      float s = 0.f, s2 = 0.f;
      #pragma unroll
      for (int mc=0;mc<2;mc++)
        #pragma unroll
        for (int r=0;r<4;r++){
          float v = acc2[mc][nc][r] + bia;
          big[(((size_t)(nb + mc*16 + q*4 + r)) << 6) + nc*16 + m] = v;
          s += v; s2 = fmaf(v, v, s2);
        }
      s  += __shfl_xor(s, 16, 64);  s  += __shfl_xor(s, 32, 64);
      s2 += __shfl_xor(s2,16, 64);  s2 += __shfl_xor(s2,32, 64);
      if (q == 0){ red[0][wv][nc*16+m] = s; red[1][wv][nc*16+m] = s2; }
    }
    __syncthreads();
    if (tid < 128){
      int which = tid >> 6, c = tid & 63;
      float a = red[which][0][c]+red[which][1][c]+red[which][2][c]+red[which][3][c];
      unsafeAtomicAdd(stats + which*64 + c, a);
    }
}

// ------------------------------------------------------------------
// MFMA BN-apply (params inline from stats) + inner MLP + fused pool.
// ------------------------------------------------------------------
__global__ __launch_bounds__(256) void k_bn_inner(
    const float* __restrict__ big, const float* __restrict__ stats,
    const float* __restrict__ gam, const float* __restrict__ bet,
    const short* __restrict__ wih, const short* __restrict__ wil,
    const float* __restrict__ bi,
    bf16* __restrict__ xh,
    const int* __restrict__ gidx, float* __restrict__ pooled)
{
    __shared__ __align__(16) char buf[4][9472];
    int tid = threadIdx.x, wv = tid >> 6, lane = tid & 63;
    int q = lane >> 4, m = lane & 15;
    int nb = blockIdx.x*128 + wv*32;
    short* Sh = (short*)buf[wv];
    short* Sl = Sh + 2304;

    // BN params inline (stats complete: previous dispatch)
    float mu  = stats[lane]    * (1.0f/NN);
    float ex2 = stats[64+lane] * (1.0f/NN);
    float var = ex2 - mu*mu;
    float sc  = gam[lane] * rsqrtf(var + 1e-5f);
    float sh  = bet[lane] - mu*sc;

    for (int rr = 0; rr < 32; rr++){
        float v = big[(((size_t)(nb+rr)) << 6) + lane];
        v = fmaxf(fmaf(v, sc, sh), 0.f);
        xh[(((size_t)(nb+rr)) << 6) + lane] = __float2bfloat16(v);
        short hb = f2bf_s(v);
        Sh[rr*72 + lane] = hb;
        Sl[rr*72 + lane] = f2bf_s(v - bf2f_s(hb));
    }
    __syncthreads();

    short8 A2h[2][2], A2l[2][2];
    #pragma unroll
    for (int mc=0; mc<2; mc++)
      #pragma unroll
      for (int kc=0; kc<2; kc++){
        A2h[mc][kc] = *(const short8*)(Sh + (mc*16+m)*72 + kc*32 + q*8);
        A2l[mc][kc] = *(const short8*)(Sl + (mc*16+m)*72 + kc*32 + q*8);
      }
    floatx4 acc[2][4];
    #pragma unroll
    for (int mc=0;mc<2;mc++)
      #pragma unroll
      for (int nc=0;nc<4;nc++) acc[mc][nc] = (floatx4){0.f,0.f,0.f,0.f};
    #pragma unroll
    for (int nc=0;nc<4;nc++){
      #pragma unroll
      for (int kc=0;kc<2;kc++){
        short8 bh = *(const short8*)(wih + (nc*16+m)*64 + kc*32 + q*8);
        short8 bl = *(const short8*)(wil + (nc*16+m)*64 + kc*32 + q*8);
        #pragma unroll
        for (int mc=0;mc<2;mc++){
          acc[mc][nc] = __builtin_amdgcn_mfma_f32_16x16x32_bf16(A2h[mc][kc], bh, acc[mc][nc],0,0,0);
          acc[mc][nc] = __builtin_amdgcn_mfma_f32_16x16x32_bf16(A2l[mc][kc], bh, acc[mc][nc],0,0,0);
          acc[mc][nc] = __builtin_amdgcn_mfma_f32_16x16x32_bf16(A2h[mc][kc], bl, acc[mc][nc],0,0,0);
        }
      }
    }
    __syncthreads();   // LDS reads done; safe to repurpose buf

    float* P = (float*)buf[wv];
    #pragma unroll
    for (int nc=0;nc<4;nc++){
      float bia = bi[nc*16+m];
      #pragma unroll
      for (int mc=0;mc<2;mc++)
        #pragma unroll
        for (int r=0;r<4;r++){
          float v = fmaxf(acc[mc][nc][r] + bia, 0.f);
          P[(mc*16 + q*4 + r)*66 + nc*16 + m] = v;
        }
    }
    __syncthreads();

    int gv = (lane < 32) ? gidx[nb + lane] : 0;
    int cur = __shfl(gv, 0, 64);
    float a = 0.f;
    for (int rr = 0; rr < 32; rr++){
        int g = __shfl(gv, rr, 64);
        if (g != cur){
            unsafeAtomicAdd(pooled + (size_t)cur*64 + lane, a);
            a = 0.f; cur = g;
        }
        a += P[rr*66 + lane];
    }
    unsafeAtomicAdd(pooled + (size_t)cur*64 + lane, a);
}

// ------------------------------------------------------------------
// Tail: TG graphs per block; corpus layer-2 outer computed inline.
// ------------------------------------------------------------------
__global__ __launch_bounds__(256) void k_tail(
    const float* __restrict__ qf, const float* __restrict__ cf,
    const float* __restrict__ pooled_c2,
    const float* __restrict__ ow2, const float* __restrict__ ob2,
    const float* __restrict__ cw1, const float* __restrict__ cb1,
    const float* __restrict__ cw2, const float* __restrict__ cb2,
    const float* __restrict__ sw1, const float* __restrict__ sb1,
    const float* __restrict__ sw2, const float* __restrict__ sb2,
    const float* __restrict__ nw,  const float* __restrict__ nwb,
    const float* __restrict__ nb,
    const float* __restrict__ mw1, const float* __restrict__ mb1,
    const float* __restrict__ mw2, const float* __restrict__ mb2,
    const float* __restrict__ alpha, const float* __restrict__ beta,
    float* __restrict__ out)
{
    __shared__ float cws[192*96];
    __shared__ float diff[TG][192];
    __shared__ float e1s[TG][64], e2s[TG][64];
    __shared__ float h1s[TG][96], h2s[TG][96];
    __shared__ float s1s[TG][16], s2s[TG][16], srep[TG][16];
    __shared__ float red[16][16][TG];

    int t = threadIdx.x;
    int b0 = blockIdx.x * TG;

    // inline corpus outer (layer 2): e2s = relu(pooled_c2 @ ow2 + ob2)
    {
        int b = t >> 5, o = (t & 31) * 2;
        const float* pr = pooled_c2 + (size_t)(b0 + b)*64;
        float a0 = ob2[o], a1 = ob2[o+1];
        for (int k = 0; k < 64; k++) {
            float p = pr[k];
            a0 = fmaf(p, ow2[k*64 + o], a0);
            a1 = fmaf(p, ow2[k*64 + o + 1], a1);
        }
        e2s[b][o]   = fmaxf(a0, 0.f);
        e2s[b][o+1] = fmaxf(a1, 0.f);
    }
    for (int i = t; i < 192*96; i += 256) cws[i] = cw1[i];
    __syncthreads();

    for (int i = t; i < TG*192; i += 256) {
        int b = i / 192, f = i % 192;
        float qv = qf[(b0+b)*192 + f];
        float cv = (f < 128) ? cf[(b0+b)*192 + f] : e2s[b][f-128];
        float d = qv - cv;
        diff[b][f] = __expf(-d*d);
        if (f >= 128) e1s[b][f-128] = qv;
    }
    __syncthreads();

    {
        int b = t >> 5, o = (t & 31) * 3;
        float a0 = cb1[o], a1 = cb1[o+1], a2 = cb1[o+2];
        for (int f = 0; f < 192; f++) {
            float d = diff[b][f];
            const float* w = cws + f*96 + o;
            a0 = fmaf(d, w[0], a0);
            a1 = fmaf(d, w[1], a1);
            a2 = fmaf(d, w[2], a2);
        }
        h1s[b][o] = fmaxf(a0, 0.f);
        h1s[b][o+1] = fmaxf(a1, 0.f);
        h1s[b][o+2] = fmaxf(a2, 0.f);
    }
    __syncthreads();
    for (int i = t; i < 96*96; i += 256) cws[i] = cw2[i];
    __syncthreads();
    {
        int b = t >> 5, o = (t & 31) * 3;
        float a0 = cb2[o], a1 = cb2[o+1], a2 = cb2[o+2];
        for (int f = 0; f < 96; f++) {
            float d = h1s[b][f];
            const float* w = cws + f*96 + o;
            a0 = fmaf(d, w[0], a0);
            a1 = fmaf(d, w[1], a1);
            a2 = fmaf(d, w[2], a2);
        }
        h2s[b][o] = tanhf(a0);
        h2s[b][o+1] = tanhf(a1);
        h2s[b][o+2] = tanhf(a2);
    }
    __syncthreads();
    if (t < TG*16) {
        int b = t >> 4, o = t & 15;
        float a = sb1[o];
        for (int f = 0; f < 96; f++) a = fmaf(h2s[b][f], sw1[f*16+o], a);
        s1s[b][o] = fmaxf(a, 0.f);
    }

    {
        int tt = t & 15, gq = t >> 4;
        int g0 = gq * 4;
        int lane = t & 63;
        float e1v[TG];
        #pragma unroll
        for (int b = 0; b < TG; b++) e1v[b] = e1s[b][lane];
        float v0[TG], v1[TG], v2[TG], v3[TG];
        #pragma unroll
        for (int b = 0; b < TG; b++) { v0[b]=0.f; v1[b]=0.f; v2[b]=0.f; v3[b]=0.f; }
        for (int f = 0; f < 64; f++) {
            const float* wp = nw + ((size_t)f*64 + g0)*16 + tt;
            float w0 = wp[0], w1 = wp[16], w2 = wp[32], w3 = wp[48];
            #pragma unroll
            for (int b = 0; b < TG; b++) {
                float e = __shfl(e1v[b], f, 64);
                v0[b] = fmaf(e, w0, v0[b]);
                v1[b] = fmaf(e, w1, v1[b]);
                v2[b] = fmaf(e, w2, v2[b]);
                v3[b] = fmaf(e, w3, v3[b]);
            }
        }
        #pragma unroll
        for (int b = 0; b < TG; b++) {
            float p = v0[b]*e2s[b][g0] + v1[b]*e2s[b][g0+1]
                    + v2[b]*e2s[b][g0+2] + v3[b]*e2s[b][g0+3];
            red[gq][tt][b] = p;
        }
    }
    __syncthreads();
    if (t < TG*16) {
        int b = t >> 4, tt = t & 15;
        float scv = 0.f;
        #pragma unroll
        for (int gq = 0; gq < 16; gq++) scv += red[gq][tt][b];
        float blk = nb[tt];
        for (int f = 0; f < 64; f++) blk = fmaf(e1s[b][f], nwb[tt*128 + f], blk);
        for (int f = 0; f < 64; f++) blk = fmaf(e2s[b][f], nwb[tt*128 + 64 + f], blk);
        srep[b][tt] = fmaxf(scv + blk, 0.f);
    }
    __syncthreads();
    if (t < TG*16) {
        int b = t >> 4, o = t & 15;
        float a = mb1[o];
        #pragma unroll
        for (int f = 0; f < 16; f++) a = fmaf(srep[b][f], mw1[f*16+o], a);
        s2s[b][o] = fmaxf(a, 0.f);
    }
    __syncthreads();
    if (t < TG) {
        float sco = sb2[0], sm = mb2[0];
        #pragma unroll
        for (int f = 0; f < 16; f++) {
            sco = fmaf(s1s[t][f], sw2[f], sco);
            sm  = fmaf(s2s[t][f], mw2[f], sm);
        }
        float score = 1.f / (1.f + __expf(-sco));
        float sim   = 1.f / (1.f + __expf(-sm));
        out[b0 + t] = alpha[0]*score + beta[0]*sim;
    }
}

// ------------------------------------------------------------------
extern "C" void kernel_launch(void* const* d_in, const int* in_sizes, int n_in,
                              void* d_out, int out_size, void* d_ws, size_t ws_size,
                              hipStream_t stream)
{
    const float* qx  = (const float*)d_in[0];
    const float* cx  = (const float*)d_in[1];
    const int*   qei = (const int*)d_in[2];
    const int*   cei = (const int*)d_in[3];
    const int*   qgi = (const int*)d_in[4];
    const int*   cgi = (const int*)d_in[5];
    const float* Wgw1 = (const float*)d_in[6];
    const float* Wgb1 = (const float*)d_in[7];
    const float* Wgw2 = (const float*)d_in[8];
    const float* Wgb2 = (const float*)d_in[9];
    const float* Wgam = (const float*)d_in[10];
    const float* Wbet = (const float*)d_in[11];
    const float* Weps = (const float*)d_in[12];
    const float* Wiw  = (const float*)d_in[13];
    const float* Wib  = (const float*)d_in[14];
    const float* Wow  = (const float*)d_in[15];
    const float* Wob  = (const float*)d_in[16];
    const float* Wcw1 = (const float*)d_in[17];
    const float* Wcb1 = (const float*)d_in[18];
    const float* Wcw2 = (const float*)d_in[19];
    const float* Wcb2 = (const float*)d_in[20];
    const float* Wsw1 = (const float*)d_in[21];
    const float* Wsb1 = (const float*)d_in[22];
    const float* Wsw2 = (const float*)d_in[23];
    const float* Wsb2 = (const float*)d_in[24];
    const float* Wnw  = (const float*)d_in[25];
    const float* Wnwb = (const float*)d_in[26];
    const float* Wnb  = (const float*)d_in[27];
    const float* Wmw1 = (const float*)d_in[28];
    const float* Wmb1 = (const float*)d_in[29];
    const float* Wmw2 = (const float*)d_in[30];
    const float* Wmb2 = (const float*)d_in[31];
    const float* Wal  = (const float*)d_in[32];
    const float* Wbe  = (const float*)d_in[33];

    float* F      = (float*)d_ws;
    float* big    = F;                        // N*64 (h2; rank aliases)
    float* zbuf   = F + 8388608;              // stats3(384) + pooled3(196608)
    float* stats3 = zbuf;
    float* pooled3= zbuf + 384;
    float* qf     = pooled3 + 3*BG*64;        // BG*192
    float* cf     = qf + 196608;              // BG*192
    int*   rowptr = (int*)(cf + 196608);      // NN+1
    int*   cnt    = rowptr + (NN + 1);        // NN (histogram)
    int*   col    = cnt + NN;                 // NEDGE
    int*   bsum   = col + NEDGE;              // 128
    int*   boff   = bsum + 128;               // 128
    bf16*  xh     = (bf16*)(boff + 128);      // N*64 bf16
    int*   rank   = (int*)big;                // NEDGE (dead during CSR build)
    uintptr_t wtb = (uintptr_t)(xh + (size_t)NN*64);
    wtb = (wtb + 63) & ~((uintptr_t)63);
    short* w1h = (short*)wtb;                 // 3*4096 each
    short* w1l = w1h + 3*4096;
    short* w2h = w1l + 3*4096;
    short* w2l = w2h + 3*4096;
    short* wih = w2l + 3*4096;
    short* wil = wih + 3*4096;

    k_wprep<<<144, 256, 0, stream>>>(Wgw1, Wgw2, Wiw, w1h, w1l, w2h, w2l, wih, wil);

    for (int side = 0; side < 2; side++) {
        const float* x0 = side ? cx  : qx;
        const int* ei   = side ? cei : qei;
        const int* gi   = side ? cgi : qgi;
        float* feats    = side ? cf  : qf;

        // side 1's k_zero also performs outer(l=2) for side 0 (qf cols 128..191)
        if (side == 0)
            k_zero<<<NN/256, 256, 0, stream>>>(cnt, nullptr, nullptr, nullptr, nullptr);
        else
            k_zero<<<NN/256, 256, 0, stream>>>(cnt, pooled3 + 2*BG*64,
                                               Wow + 2*4096, Wob + 2*64, qf);
        k_hist<<<NEDGE/256, 256, 0, stream>>>(ei, cnt, rank);
        k_scan1<<<128, 256, 0, stream>>>(cnt, rowptr, bsum);
        k_scan2<<<1, 128, 0, stream>>>(bsum, boff, rowptr);
        k_scan3<<<NN/256, 256, 0, stream>>>(rowptr, boff);
        k_fill<<<NEDGE/256, 256, 0, stream>>>(ei, rowptr, rank, col);

        k_cvt<<<NN*64/1024, 256, 0, stream>>>(x0, xh, zbuf);

        for (int l = 0; l < LAYERS; l++) {
            const float* pprev = (l == 0) ? nullptr : pooled3 + (size_t)(l-1)*BG*64;
            const float* owp   = (l == 0) ? nullptr : Wow + (l-1)*4096;
            const float* obp   = (l == 0) ? nullptr : Wob + (l-1)*64;
            k_agg_gin<<<NN/128, 256, 0, stream>>>(xh, rowptr, col, Weps + l,
                                                  w1h + l*4096, w1l + l*4096, Wgb1 + l*64,
                                                  w2h + l*4096, w2l + l*4096, Wgb2 + l*64,
                                                  big, stats3 + l*128,
                                                  pprev, owp, obp, feats, (l-1)*64);
            k_bn_inner<<<NN/128, 256, 0, stream>>>(big, stats3 + l*128,
                                                   Wgam + l*64, Wbet + l*64,
                                                   wih + l*4096, wil + l*4096,
                                                   Wib + l*64, xh, gi,
                                                   pooled3 + (size_t)l*BG*64);
        }
    }

    k_tail<<<BG/TG, 256, 0, stream>>>(qf, cf, pooled3 + 2*BG*64,
                                      Wow + 2*4096, Wob + 2*64,
                                      Wcw1, Wcb1, Wcw2, Wcb2,
                                      Wsw1, Wsb1, Wsw2, Wsb2,
                                      Wnw, Wnwb, Wnb, Wmw1, Wmb1, Wmw2, Wmb2,
                                      Wal, Wbe, (float*)d_out);
}